// Round 5
// baseline (1160.762 us; speedup 1.0000x reference)
//
#include <hip/hip_runtime.h>

// Problem constants (Bert4KGModel): B=4, T=S=512, D=1024, H=16, dh=64, F=4096, L=2
#define BB  4
#define TT  512
#define DD  1024
#define HH  16
#define DHH 64
#define FF  4096

typedef unsigned short u16;
typedef __attribute__((ext_vector_type(8))) short bfrag8;   // 8 bf16 (4 VGPRs)
typedef __attribute__((ext_vector_type(4))) float facc4;    // 4 f32 acc

__device__ __forceinline__ u16 f2bf(float f){
  unsigned u = __float_as_uint(f);
  unsigned r = u + 0x7fffu + ((u >> 16) & 1u);   // RNE
  return (u16)(r >> 16);
}
__device__ __forceinline__ float bf2f(u16 h){
  return __uint_as_float(((unsigned)h) << 16);
}

// async global->LDS, 16B per lane; LDS dest is wave-uniform base + lane*16
__device__ __forceinline__ void gload16(const u16* g, u16* l){
  __builtin_amdgcn_global_load_lds(
      (const __attribute__((address_space(1))) void*)g,
      (__attribute__((address_space(3))) void*)l, 16, 0, 0);
}

// counted vmcnt wait (literal immediates only)
template<int N> __device__ __forceinline__ void vwait(){
  static_assert(N==0 || N==4 || N==6 || N==8 || N==12 || N==16, "bad vmcnt literal");
  if constexpr (N==0)  asm volatile("s_waitcnt vmcnt(0)" ::: "memory");
  else if constexpr (N==4)  asm volatile("s_waitcnt vmcnt(4)" ::: "memory");
  else if constexpr (N==6)  asm volatile("s_waitcnt vmcnt(6)" ::: "memory");
  else if constexpr (N==8)  asm volatile("s_waitcnt vmcnt(8)" ::: "memory");
  else if constexpr (N==12) asm volatile("s_waitcnt vmcnt(12)" ::: "memory");
  else if constexpr (N==16) asm volatile("s_waitcnt vmcnt(16)" ::: "memory");
}

// ---------------------------------------------------------------------------
// Weight transpose + f32->bf16 with generalized z-mapping
// ---------------------------------------------------------------------------
__global__ __launch_bounds__(256) void transpose_w_kernel(
    const float* __restrict__ W, u16* __restrict__ Wt, int R, int C,
    long szs1, long szs2, long dzs1, long dzs2, int zdiv)
{
  __shared__ float tile[32][33];
  const int tx = threadIdx.x & 31, ty = threadIdx.x >> 5;   // 32 x 8
  const int z = blockIdx.z;
  const long so = (long)(z / zdiv) * szs1 + (long)(z % zdiv) * szs2;
  const long dzo = (long)(z / zdiv) * dzs1 + (long)(z % zdiv) * dzs2;
  const int c0 = blockIdx.x << 5, r0 = blockIdx.y << 5;
  #pragma unroll
  for (int i = 0; i < 4; ++i)
    tile[ty + i*8][tx] = W[so + (long)(r0 + ty + i*8)*C + c0 + tx];
  __syncthreads();
  #pragma unroll
  for (int i = 0; i < 4; ++i)
    Wt[dzo + (long)(c0 + ty + i*8)*R + r0 + tx] = f2bf(tile[tx][ty + i*8]);
}

// ---------------------------------------------------------------------------
// 4 buffers f32 -> bf16 in one launch
// ---------------------------------------------------------------------------
__global__ __launch_bounds__(256) void f32_to_bf16_4(
    const float* __restrict__ a0, const float* __restrict__ a1,
    const float* __restrict__ a2, const float* __restrict__ a3,
    u16* __restrict__ o0, u16* __restrict__ o1,
    u16* __restrict__ o2, u16* __restrict__ o3, int n4)
{
  const float* s; u16* d;
  switch (blockIdx.y){
    case 0: s = a0; d = o0; break;
    case 1: s = a1; d = o1; break;
    case 2: s = a2; d = o2; break;
    default: s = a3; d = o3; break;
  }
  int i = blockIdx.x * 256 + threadIdx.x;
  if (i >= n4) return;
  float4 v = ((const float4*)s)[i];
  ushort4 o;
  o.x = f2bf(v.x); o.y = f2bf(v.y); o.z = f2bf(v.z); o.w = f2bf(v.w);
  ((ushort4*)d)[i] = o;
}

// ---------------------------------------------------------------------------
// Embedding gather
// ---------------------------------------------------------------------------
__global__ __launch_bounds__(256) void embed_kernel(
    const float* __restrict__ emb, const int* __restrict__ pvec,
    const float* __restrict__ pos, float* __restrict__ out)
{
  const int row = blockIdx.x;
  const int i = threadIdx.x;
  const int idx = pvec[row];
  const int t = row & (TT - 1);
  float4 e = ((const float4*)(emb + (long)idx * DD))[i];
  float4 p = ((const float4*)(pos + (long)t * DD))[i];
  float4 o;
  o.x = e.x * 32.0f + p.x; o.y = e.y * 32.0f + p.y;
  o.z = e.z * 32.0f + p.z; o.w = e.w * 32.0f + p.w;
  ((float4*)(out + (long)row * DD))[i] = o;
}

// ---------------------------------------------------------------------------
// LayerNorm(a [+ res]) -> yf (f32, optional) and yb (bf16)
// ---------------------------------------------------------------------------
__global__ __launch_bounds__(256) void ln_kernel(
    const float* __restrict__ a, const float* __restrict__ res,
    float* __restrict__ yf, u16* __restrict__ yb)
{
  const int row = blockIdx.x;
  const int i = threadIdx.x;
  const int lane = i & 63, wid = i >> 6;
  float4 x = ((const float4*)(a + (long)row * DD))[i];
  if (res){
    float4 r4 = ((const float4*)(res + (long)row * DD))[i];
    x.x += r4.x; x.y += r4.y; x.z += r4.z; x.w += r4.w;
  }
  float s = x.x + x.y + x.z + x.w;
  #pragma unroll
  for (int o = 32; o; o >>= 1) s += __shfl_xor(s, o);
  __shared__ float red[4];
  if (lane == 0) red[wid] = s;
  __syncthreads();
  const float mean = (red[0] + red[1] + red[2] + red[3]) * (1.0f / DD);
  __syncthreads();
  const float dx = x.x - mean, dy = x.y - mean, dz = x.z - mean, dw = x.w - mean;
  float q = dx*dx + dy*dy + dz*dz + dw*dw;
  #pragma unroll
  for (int o = 32; o; o >>= 1) q += __shfl_xor(q, o);
  if (lane == 0) red[wid] = q;
  __syncthreads();
  const float var = (red[0] + red[1] + red[2] + red[3]) * (1.0f / DD);
  const float rstd = rsqrtf(var + 1e-5f);
  float4 y; y.x = dx*rstd; y.y = dy*rstd; y.z = dz*rstd; y.w = dw*rstd;
  if (yf) ((float4*)(yf + (long)row * DD))[i] = y;
  ushort4 o4; o4.x = f2bf(y.x); o4.y = f2bf(y.y); o4.z = f2bf(y.z); o4.w = f2bf(y.w);
  ((ushort4*)(yb + (long)row * DD))[i] = o4;
}

// ---------------------------------------------------------------------------
// Flash attention: one block per (q-tile 64, b*h). 4 waves x 16 q-rows.
// 3-deep counted-vmcnt K/V staging; online softmax; P via swizzled LDS.
// ---------------------------------------------------------------------------
template<bool CAUSAL>
__global__ __launch_bounds__(256, 2) void flash_kernel(
    const u16* __restrict__ Q, const u16* __restrict__ Kt,
    const u16* __restrict__ Vt, const int* __restrict__ cmask, int mode,
    u16* __restrict__ O)
{
  __shared__ __align__(16) u16 Ks[3][64*64];
  __shared__ __align__(16) u16 Vs[3][64*64];
  __shared__ __align__(16) u16 Ps[4*16*64];
  __shared__ float biasS[512];

  // XCD swizzle: all 8 q-tiles of one head land on one XCD (K/V L2 reuse)
  const int fid = blockIdx.y * 8 + blockIdx.x;          // 0..511
  const int lid = (fid & 7) * 64 + (fid >> 3);
  const int qt = lid & 7;
  const int bh = lid >> 3;
  const int b = bh >> 4, h = bh & 15;

  const int tid = threadIdx.x, lane = tid & 63, wid = tid >> 6;
  const int fr = lane & 15, kg = lane >> 4;

  if (!CAUSAL){
    #pragma unroll
    for (int r = 0; r < 2; ++r){
      const int c = r * 256 + tid;
      biasS[c] = (cmask[b * 512 + c] != mode) ? 0.0f : -1e20f;
    }
  }

  const long base = (long)bh * (512 * 64);
  const u16* qrow = Q + base + (long)(qt*64 + wid*16 + fr) * 64;
  const bfrag8 aq0 = *(const bfrag8*)(qrow + kg*8);
  const bfrag8 aq1 = *(const bfrag8*)(qrow + 32 + kg*8);

  const int srow = tid >> 3;                         // 0..31
  const int gcol = ((tid & 7) ^ (srow & 7)) * 8;     // pre-swizzled source chunk

  auto stageKV = [&](int buf, int kt){
    u16* Kd = Ks[buf] + wid * 512;
    u16* Vd = Vs[buf] + wid * 512;
    #pragma unroll
    for (int p = 0; p < 2; ++p)
      gload16(Kt + base + (long)(kt*64 + p*32 + srow) * 64 + gcol, Kd + p*2048);
    #pragma unroll
    for (int p = 0; p < 2; ++p)
      gload16(Vt + base + (long)(p*32 + srow) * 512 + kt*64 + gcol, Vd + p*2048);
  };

  float mrow[4], lrow[4];
  #pragma unroll
  for (int r = 0; r < 4; ++r){ mrow[r] = -3e38f; lrow[r] = 0.0f; }
  facc4 accO[4] = {};
  const facc4 z4 = {0.0f, 0.0f, 0.0f, 0.0f};

  const int NT = CAUSAL ? (qt + 1) : 8;   // causal: skip fully-masked tiles
  stageKV(0, 0);
  if (NT > 1) stageKV(1, 1);
  if (NT > 2) stageKV(2, 2);
  if (NT > 2) vwait<8>();
  else if (NT > 1) vwait<4>();
  else vwait<0>();
  __builtin_amdgcn_s_barrier();

  u16* Pw = Ps + wid * 1024;
  int cur = 0;

  for (int kt = 0; kt < NT; ++kt){
    bfrag8 bk[4][2], bv[4][2];
    #pragma unroll
    for (int j = 0; j < 4; ++j)
      #pragma unroll
      for (int c2 = 0; c2 < 2; ++c2){
        const int po = (((c2*4 + kg) ^ (fr & 7)) * 8);
        bk[j][c2] = *(const bfrag8*)&Ks[cur][(j*16 + fr)*64 + po];
        bv[j][c2] = *(const bfrag8*)&Vs[cur][(j*16 + fr)*64 + po];
      }
    __builtin_amdgcn_sched_barrier(0);
    __builtin_amdgcn_s_barrier();                 // all waves read buf[cur]
    if (kt + 3 < NT){ stageKV(cur, kt + 3); vwait<8>(); }
    else if (kt + 2 < NT) vwait<4>();
    else if (kt + 1 < NT) vwait<0>();
    __builtin_amdgcn_s_barrier();                 // buf[kt+1] ready for every wave

    // QK^T (rows = q, cols = kpos)
    facc4 sc[4];
    __builtin_amdgcn_s_setprio(1);
    #pragma unroll
    for (int j = 0; j < 4; ++j){
      sc[j] = __builtin_amdgcn_mfma_f32_16x16x32_bf16(aq0, bk[j][0], z4, 0, 0, 0);
      sc[j] = __builtin_amdgcn_mfma_f32_16x16x32_bf16(aq1, bk[j][1], sc[j], 0, 0, 0);
    }
    __builtin_amdgcn_s_setprio(0);
    // mask
    if (CAUSAL){
      const int rowb = qt*64 + wid*16 + kg*4;
      #pragma unroll
      for (int j = 0; j < 4; ++j){
        const int col = kt*64 + j*16 + fr;
        #pragma unroll
        for (int r = 0; r < 4; ++r)
          if (col > rowb + r) sc[j][r] = -1e20f;
      }
    } else {
      #pragma unroll
      for (int j = 0; j < 4; ++j){
        const float bval = biasS[kt*64 + j*16 + fr];
        #pragma unroll
        for (int r = 0; r < 4; ++r) sc[j][r] += bval;
      }
    }
    // online softmax (per-lane rows kg*4+rr; reduce across fr lanes)
    float tmax[4];
    #pragma unroll
    for (int r = 0; r < 4; ++r)
      tmax[r] = fmaxf(fmaxf(sc[0][r], sc[1][r]), fmaxf(sc[2][r], sc[3][r]));
    #pragma unroll
    for (int o = 1; o < 16; o <<= 1)
      #pragma unroll
      for (int r = 0; r < 4; ++r)
        tmax[r] = fmaxf(tmax[r], __shfl_xor(tmax[r], o));
    float fac[4];
    #pragma unroll
    for (int r = 0; r < 4; ++r){
      const float mn = fmaxf(mrow[r], tmax[r]);
      fac[r] = __expf(mrow[r] - mn);
      mrow[r] = mn;
    }
    float tsum[4] = {0.0f, 0.0f, 0.0f, 0.0f};
    #pragma unroll
    for (int j = 0; j < 4; ++j)
      #pragma unroll
      for (int r = 0; r < 4; ++r){
        const float p = __expf(sc[j][r] - mrow[r]);
        sc[j][r] = p; tsum[r] += p;
      }
    #pragma unroll
    for (int o = 1; o < 16; o <<= 1)
      #pragma unroll
      for (int r = 0; r < 4; ++r) tsum[r] += __shfl_xor(tsum[r], o);
    #pragma unroll
    for (int r = 0; r < 4; ++r) lrow[r] = lrow[r]*fac[r] + tsum[r];
    #pragma unroll
    for (int f = 0; f < 4; ++f)
      #pragma unroll
      for (int r = 0; r < 4; ++r) accO[f][r] *= fac[r];

    // P -> wave-private LDS (chunk-swizzled), read back as A-frags
    #pragma unroll
    for (int j = 0; j < 4; ++j)
      #pragma unroll
      for (int r = 0; r < 4; ++r){
        const int row = kg*4 + r;
        const int col = j*16 + fr;
        Pw[row*64 + (((col >> 3) ^ (row & 7)) * 8) + (col & 7)] = f2bf(sc[j][r]);
      }
    bfrag8 ap[2];
    #pragma unroll
    for (int c2 = 0; c2 < 2; ++c2)
      ap[c2] = *(const bfrag8*)&Pw[fr*64 + (((c2*4 + kg) ^ (fr & 7)) * 8)];
    __builtin_amdgcn_s_setprio(1);
    #pragma unroll
    for (int f = 0; f < 4; ++f){
      accO[f] = __builtin_amdgcn_mfma_f32_16x16x32_bf16(ap[0], bv[f][0], accO[f], 0, 0, 0);
      accO[f] = __builtin_amdgcn_mfma_f32_16x16x32_bf16(ap[1], bv[f][1], accO[f], 0, 0, 0);
    }
    __builtin_amdgcn_s_setprio(0);
    cur = (cur == 2) ? 0 : cur + 1;
  }

  // epilogue: divide by row sum, write [b*512+t][1024] at col h*64
  #pragma unroll
  for (int f = 0; f < 4; ++f)
    #pragma unroll
    for (int r = 0; r < 4; ++r){
      const int row = qt*64 + wid*16 + kg*4 + r;
      const int col = h*64 + f*16 + fr;
      O[(long)(b*512 + row) * 1024 + col] = f2bf(accO[f][r] / lrow[r]);
    }
}

// ---------------------------------------------------------------------------
// bf16 MFMA GEMM, BK=64, NBUF-deep counted-vmcnt pipeline, XCD swizzle.
// MODE_F32: bias2 = optional residual matrix (added after bias/alpha/relu).
// MODE_KV: hardcoded 16-batch (ci, l, k/v) mapping, A = contiguous kvb[4].
// ---------------------------------------------------------------------------
#define MODE_F32  0
#define MODE_BF16 1
#define MODE_QKV  3
#define MODE_KV   4
#define MODE_Q    5

__device__ __forceinline__ long qk_off(int gm, int gn){   // [b,h,t,d]
  return (((long)(gm >> 9) * HH + (gn >> 6)) * TT + (gm & (TT-1))) * DHH + (gn & (DHH-1));
}
__device__ __forceinline__ long vt_off(int gm, int gn){   // [b,h,d,s]
  return (((long)(gm >> 9) * HH + (gn >> 6)) * DHH + (gn & (DHH-1))) * TT + (gm & (TT-1));
}

template<int BM, int BN, int MODE>
__global__ __launch_bounds__(256, 2) void gemm_k(
    const u16* __restrict__ A, const u16* __restrict__ B,
    const float* __restrict__ bias0, const float* __restrict__ bias1,
    const float* __restrict__ bias2,
    float* __restrict__ Cf, u16* __restrict__ Cb0,
    u16* __restrict__ Cb1, u16* __restrict__ Cb2,
    int K, int lda, int ldb, int ldc,
    long zsA, long zsB1, long zsB2, int zdivB,
    long czs1, long czs2, int zdivC, long bzs,
    int relu, float alpha)
{
  constexpr int BK = 64;
  constexpr int NBUF = (BM == 64) ? 3 : 2;              // 3-deep for small tiles
  constexpr int ASZ = BM * BK, BSZ = BN * BK;           // u16 per buffer
  __shared__ __align__(16) u16 As[NBUF * ASZ];
  __shared__ __align__(16) u16 Bs[NBUF * BSZ];

  // XCD-aware bijective block swizzle (all grids are %8 == 0)
  const int gx = gridDim.x, gy = gridDim.y;
  const int nwg = gx * gy * gridDim.z;
  const int fid = (blockIdx.z * gy + blockIdx.y) * gx + blockIdx.x;
  const int cpx = nwg >> 3;
  const int lid = (fid & 7) * cpx + (fid >> 3);
  const int bx = lid % gx;
  const int rem = lid / gx;
  const int by = rem % gy;
  const int z  = rem / gy;

  const u16* Ab;
  const u16* Bb;
  long cbase;
  constexpr long NBA = (long)2048 * 1024;      // one kv / KVc block (u16 elems)
  constexpr long D2C = (long)DD * DD;
  if constexpr (MODE == MODE_KV){
    const int ci = z >> 2, ll = (z >> 1) & 1, isv = z & 1;
    Ab = A + (long)ci * NBA;
    Bb = B + (long)(ll*8 + ci*2 + isv) * D2C;
    cbase = (long)(ll*8 + ci*2 + isv) * NBA;
  } else {
    Ab = A + (long)z * zsA;
    Bb = B + (long)(z / zdivB) * zsB1 + (long)(z % zdivB) * zsB2;
    cbase = (long)(z / zdivC) * czs1 + (long)(z % zdivC) * czs2;
  }
  const int tid = threadIdx.x, lane = tid & 63, wid = tid >> 6;
  const int m0 = by * BM, n0 = bx * BN;
  constexpr int WGN = (BN >= 128) ? 2 : 1, WGM = 4 / WGN;
  constexpr int TMW = BM / WGM, TNW = BN / WGN;
  constexpr int FM = TMW / 16, FN = TNW / 16;
  const int wm = (wid / WGN) * TMW, wn = (wid % WGN) * TNW;
  const int fr = lane & 15, kg = lane >> 4;
  facc4 acc[FM][FN] = {};

  // staging: pass = 32 rows (4KB); thread t -> row t>>3, phys chunk t&7;
  // global chunk pre-swizzled: LDS[r][c] = G[r][c^(r&7)]
  const int srow = tid >> 3;
  const int gcol = (((tid & 7) ^ (srow & 7)) * 8);
  constexpr int AP = BM / 32, BP = BN / 32;
  constexpr int LPS = AP + BP;                     // VMEM instrs per stage per wave

  auto stage = [&](int buf, int k0){
    u16* Ad = As + buf * ASZ + wid * 512;
    u16* Bd = Bs + buf * BSZ + wid * 512;
    #pragma unroll
    for (int p = 0; p < AP; ++p)
      gload16(Ab + (long)(m0 + p*32 + srow) * lda + (k0 + gcol), Ad + p*2048);
    #pragma unroll
    for (int p = 0; p < BP; ++p)
      gload16(Bb + (long)(n0 + p*32 + srow) * ldb + (k0 + gcol), Bd + p*2048);
  };

  const int nsteps = K / BK;                       // always >= 16 here
  stage(0, 0);
  stage(1, BK);
  if constexpr (NBUF == 3){ stage(2, 2*BK); vwait<2*LPS>(); }
  else vwait<LPS>();
  __builtin_amdgcn_s_barrier();

  int cur = 0;
  for (int s = 0; s < nsteps; ++s){
    const u16* Ar = As + cur * ASZ;
    const u16* Br = Bs + cur * BSZ;
    bfrag8 af[FM][2], bfv[FN][2];
    #pragma unroll
    for (int i = 0; i < FM; ++i)
      #pragma unroll
      for (int c2 = 0; c2 < 2; ++c2)
        af[i][c2] = *(const bfrag8*)&Ar[(wm + i*16 + fr) * 64 + (((c2*4 + kg) ^ (fr & 7)) * 8)];
    #pragma unroll
    for (int j = 0; j < FN; ++j)
      #pragma unroll
      for (int c2 = 0; c2 < 2; ++c2)
        bfv[j][c2] = *(const bfrag8*)&Br[(wn + j*16 + fr) * 64 + (((c2*4 + kg) ^ (fr & 7)) * 8)];
    __builtin_amdgcn_sched_barrier(0);
    __builtin_amdgcn_s_barrier();                 // all waves done reading buf[cur]
    if constexpr (NBUF == 3){
      if (s + 3 < nsteps){ stage(cur, (s + 3) * BK); vwait<2*LPS>(); }
      else if (s + 2 < nsteps) vwait<LPS>();
      else if (s + 1 < nsteps) vwait<0>();
    } else {
      if (s + 2 < nsteps){ stage(cur, (s + 2) * BK); vwait<LPS>(); }
      else if (s + 1 < nsteps) vwait<0>();
    }
    __builtin_amdgcn_s_barrier();                 // buf[s+1] landed for every wave
    __builtin_amdgcn_s_setprio(1);
    #pragma unroll
    for (int i = 0; i < FM; ++i)
      #pragma unroll
      for (int j = 0; j < FN; ++j){
        acc[i][j] = __builtin_amdgcn_mfma_f32_16x16x32_bf16(af[i][0], bfv[j][0], acc[i][j], 0, 0, 0);
        acc[i][j] = __builtin_amdgcn_mfma_f32_16x16x32_bf16(af[i][1], bfv[j][1], acc[i][j], 0, 0, 0);
      }
    __builtin_amdgcn_s_setprio(0);
    cur = (cur == NBUF - 1) ? 0 : cur + 1;
  }

  // Epilogue. C/D frag layout: col = fr, row = kg*4 + rr.
  #pragma unroll
  for (int i = 0; i < FM; ++i){
    #pragma unroll
    for (int j = 0; j < FN; ++j){
      const int gn = n0 + wn + j*16 + fr;
      #pragma unroll
      for (int rr = 0; rr < 4; ++rr){
        const int gm = m0 + wm + i*16 + kg*4 + rr;
        float v = acc[i][j][rr];
        if constexpr (MODE == MODE_F32){
          v = (v + (bias0 ? bias0[gn] : 0.0f)) * alpha;
          if (relu) v = fmaxf(v, 0.0f);
          const long off = cbase + (long)gm * ldc + gn;
          if (bias2) v += bias2[off];             // fused residual
          Cf[off] = v;
        } else if constexpr (MODE == MODE_BF16){
          v = (v + (bias0 ? bias0[gn] : 0.0f)) * alpha;
          if (relu) v = fmaxf(v, 0.0f);
          Cb0[cbase + (long)gm * ldc + gn] = f2bf(v);
        } else if constexpr (MODE == MODE_QKV){
          const int sect = gn >> 10, nn = gn & (DD - 1);
          if (sect == 0)      Cb0[qk_off(gm, nn)] = f2bf((v + bias0[nn]) * alpha);
          else if (sect == 1) Cb1[qk_off(gm, nn)] = f2bf(v + bias1[nn]);
          else                Cb2[vt_off(gm, nn)] = f2bf(v + bias2[nn]);
        } else if constexpr (MODE == MODE_Q){
          Cb0[qk_off(gm, gn)] = f2bf((v + bias0[gn]) * alpha);
        } else {  // MODE_KV: z -> (ci, l, k/v)
          const int ci = z >> 2, ll = (z >> 1) & 1, isv = z & 1;
          const float* bp = (isv ? bias1 : bias0) + (long)(ll*5 + ci + 1) * DD;
          const float vb = v + bp[gn];
          if (isv) Cb0[cbase + vt_off(gm, gn)] = f2bf(vb);
          else     Cb0[cbase + qk_off(gm, gn)] = f2bf(vb);
        }
      }
    }
  }
}

// ---------------------------------------------------------------------------
extern "C" void kernel_launch(void* const* d_in, const int* in_sizes, int n_in,
                              void* d_out, int out_size, void* d_ws, size_t ws_size,
                              hipStream_t stream)
{
  (void)in_sizes; (void)n_in; (void)out_size; (void)ws_size;
  const float* emb   = (const float*)d_in[0];
  const int*   pvec  = (const int*)d_in[1];
  const float* g_enc = (const float*)d_in[2];
  const float* g_con = (const float*)d_in[3];
  const float* g_db  = (const float*)d_in[4];
  const float* g_usr = (const float*)d_in[5];
  const int*   cmask = (const int*)d_in[6];
  const float* pose  = (const float*)d_in[7];
  const float* Wq = (const float*)d_in[8];
  const float* bq = (const float*)d_in[9];
  const float* Wk = (const float*)d_in[10];
  const float* bk = (const float*)d_in[11];
  const float* Wv = (const float*)d_in[12];
  const float* bv = (const float*)d_in[13];
  const float* Wo = (const float*)d_in[14];
  const float* bo = (const float*)d_in[15];
  const float* W1 = (const float*)d_in[16];
  const float* b1 = (const float*)d_in[17];
  const float* W2 = (const float*)d_in[18];
  const float* b2 = (const float*)d_in[19];
  float* out = (float*)d_out;

  const size_t NTOK = (size_t)BB * TT;   // 2048
  const long D2 = (long)DD * DD;

  char* wp = (char*)d_ws;
  auto alloc = [&](size_t bytes) -> char* {
    char* p = wp;
    wp += (bytes + 255) & ~(size_t)255;
    return p;
  };
  u16*   WqkvS = (u16*)  alloc(sizeof(u16) * 2 * 3 * D2);
  u16*   WkvC  = (u16*)  alloc(sizeof(u16) * 2 * 4 * 2 * D2);
  u16*   WqC   = (u16*)  alloc(sizeof(u16) * 2 * 4 * D2);
  u16*   WoT   = (u16*)  alloc(sizeof(u16) * 10 * D2);
  u16*   W1T   = (u16*)  alloc(sizeof(u16) * 2 * DD * FF);
  u16*   W2T   = (u16*)  alloc(sizeof(u16) * 2 * DD * FF);
  // kvb0..3 MUST stay contiguous (4 MB each, 256B-aligned): MODE_KV indexes
  // them as one [4][NTOK][DD] array.
  u16*   kvb0  = (u16*)  alloc(sizeof(u16) * NTOK * DD);
  u16*   kvb1  = (u16*)  alloc(sizeof(u16) * NTOK * DD);
  u16*   kvb2  = (u16*)  alloc(sizeof(u16) * NTOK * DD);
  u16*   kvb3  = (u16*)  alloc(sizeof(u16) * NTOK * DD);
  u16*   KVc   = (u16*)  alloc(sizeof(u16) * 16 * NTOK * DD);
  float* xf    = (float*)alloc(sizeof(float) * NTOK * DD);
  u16*   xb    = (u16*)  alloc(sizeof(u16) * NTOK * DD);
  u16*   Qb    = (u16*)  alloc(sizeof(u16) * NTOK * DD);
  u16*   Kb    = (u16*)  alloc(sizeof(u16) * NTOK * DD);
  u16*   Vtb   = (u16*)  alloc(sizeof(u16) * NTOK * DD);
  u16*   attnb = (u16*)  alloc(sizeof(u16) * NTOK * DD);
  float* obuf  = (float*)alloc(sizeof(float) * NTOK * DD);
  u16*   hb    = (u16*)  alloc(sizeof(u16) * NTOK * FF);

  // ---- weight prep ----
  const dim3 tg(32, 32, 2);
  transpose_w_kernel<<<tg, 256, 0, stream>>>(Wq, WqkvS,          DD, DD, 5*D2, 0, 3*D2, 0, 1);
  transpose_w_kernel<<<tg, 256, 0, stream>>>(Wk, WqkvS + D2,     DD, DD, 5*D2, 0, 3*D2, 0, 1);
  transpose_w_kernel<<<tg, 256, 0, stream>>>(Wv, WqkvS + 2*D2,   DD, DD, 5*D2, 0, 3*D2, 0, 1);
  transpose_w_kernel<<<dim3(32,32,8), 256, 0, stream>>>(Wk + D2, WkvC,      DD, DD, 5*D2, D2, 8*D2, 2*D2, 4);
  transpose_w_kernel<<<dim3(32,32,8), 256, 0, stream>>>(Wv + D2, WkvC + D2, DD, DD, 5*D2, D2, 8*D2, 2*D2, 4);
  transpose_w_kernel<<<dim3(32,32,8), 256, 0, stream>>>(Wq + D2, WqC,       DD, DD, 5*D2, D2, 4*D2, D2,   4);
  transpose_w_kernel<<<dim3(32,32,10),256, 0, stream>>>(Wo, WoT,            DD, DD, D2, 0, D2, 0, 1);
  transpose_w_kernel<<<dim3(128,32,2),256, 0, stream>>>(W1, W1T, DD, FF, (long)DD*FF, 0, (long)DD*FF, 0, 1);
  transpose_w_kernel<<<dim3(32,128,2),256, 0, stream>>>(W2, W2T, FF, DD, (long)DD*FF, 0, (long)DD*FF, 0, 1);

  const int n4 = (int)(NTOK * DD / 4);
  f32_to_bf16_4<<<dim3(n4/256, 4, 1), 256, 0, stream>>>(
      g_db, g_con, g_usr, g_enc, kvb0, kvb1, kvb2, kvb3, n4);

  embed_kernel<<<(int)NTOK, 256, 0, stream>>>(emb, pvec, pose, obuf);
  ln_kernel<<<(int)NTOK, 256, 0, stream>>>(obuf, nullptr, xf, xb);

  // ---- all cross-attention K/V in ONE 2048-block launch ----
  const long NB = (long)NTOK * DD;
  gemm_k<128,128,MODE_KV><<<dim3(8,16,16), 256, 0, stream>>>(
    kvb0, WkvC, bk, bv, nullptr,
    nullptr, KVc, nullptr, nullptr,
    DD, DD, DD, 0,
    0, 0, 0, 1, 0, 0, 1, 0,
    0, 1.0f);

  const int modeTab[5] = {-1, 2, 1, 3, 0};

  for (int l = 0; l < 2; ++l){
    for (int i = 0; i < 5; ++i){
      const u16 *Kp, *Vp;
      if (i == 0){
        gemm_k<64,128,MODE_QKV><<<dim3(24,32,1), 256, 0, stream>>>(
          xb, WqkvS + (long)l*3*D2,
          bq + (size_t)l*5*DD, bk + (size_t)l*5*DD, bv + (size_t)l*5*DD,
          nullptr, Qb, Kb, Vtb,
          DD, DD, DD, 0,
          0, 0, 0, 1, 0, 0, 1, 0,
          0, 0.125f);
        Kp = Kb; Vp = Vtb;
      } else {
        const int ci = i - 1;
        gemm_k<64,128,MODE_Q><<<dim3(8,32,1), 256, 0, stream>>>(
          xb, WqC + (long)(l*4 + ci)*D2,
          bq + (size_t)(l*5 + i)*DD, nullptr, nullptr,
          nullptr, Qb, nullptr, nullptr,
          DD, DD, DD, 0,
          0, 0, 0, 1, 0, 0, 1, 0,
          0, 0.125f);
        Kp = KVc + ((long)l*8 + ci*2)*NB;
        Vp = Kp + NB;
      }
      // fused attention (QK^T + masked softmax + PV)
      if (i == 0)
        flash_kernel<true><<<dim3(8,64), 256, 0, stream>>>(
            Qb, Kp, Vp, cmask, 0, attnb);
      else
        flash_kernel<false><<<dim3(8,64), 256, 0, stream>>>(
            Qb, Kp, Vp, cmask, modeTab[i], attnb);
      // O-projection + fused residual (f32 out)
      gemm_k<64,128,MODE_F32><<<dim3(8,32,1), 256, 0, stream>>>(
        attnb, WoT + (long)(l*5 + i)*D2,
        bo + (size_t)(l*5 + i)*DD, nullptr, xf,
        obuf, nullptr, nullptr, nullptr,
        DD, DD, DD, DD,
        0, 0, 0, 1, 0, 0, 1, 0,
        0, 1.0f);
      ln_kernel<<<(int)NTOK, 256, 0, stream>>>(obuf, nullptr, xf, xb);
    }
    // FFN
    gemm_k<128,128,MODE_BF16><<<dim3(32,16,1), 256, 0, stream>>>(
      xb, W1T + (size_t)l*DD*FF,
      b1 + (size_t)l*FF, nullptr, nullptr,
      nullptr, hb, nullptr, nullptr,
      DD, DD, DD, FF,
      0, 0, 0, 1, 0, 0, 1, 0,
      1, 1.0f);
    gemm_k<64,128,MODE_F32><<<dim3(8,32,1), 256, 0, stream>>>(
      hb, W2T + (size_t)l*DD*FF,
      b2 + (size_t)l*DD, nullptr, xf,
      obuf, nullptr, nullptr, nullptr,
      FF, FF, FF, DD,
      0, 0, 0, 1, 0, 0, 1, 0,
      0, 1.0f);
    float* yf = (l == 1) ? out : xf;
    ln_kernel<<<(int)NTOK, 256, 0, stream>>>(obuf, nullptr, yf, xb);
  }
}

// Round 6
// 1152.166 us; speedup vs baseline: 1.0075x; 1.0075x over previous
//
#include <hip/hip_runtime.h>

// Problem constants (Bert4KGModel): B=4, T=S=512, D=1024, H=16, dh=64, F=4096, L=2
#define BB  4
#define TT  512
#define DD  1024
#define HH  16
#define DHH 64
#define FF  4096

typedef unsigned short u16;
typedef __attribute__((ext_vector_type(8))) short bfrag8;   // 8 bf16 (4 VGPRs)
typedef __attribute__((ext_vector_type(4))) float facc4;    // 4 f32 acc

__device__ __forceinline__ u16 f2bf(float f){
  unsigned u = __float_as_uint(f);
  unsigned r = u + 0x7fffu + ((u >> 16) & 1u);   // RNE
  return (u16)(r >> 16);
}
__device__ __forceinline__ float bf2f(u16 h){
  return __uint_as_float(((unsigned)h) << 16);
}

// async global->LDS, 16B per lane; LDS dest is wave-uniform base + lane*16
__device__ __forceinline__ void gload16(const u16* g, u16* l){
  __builtin_amdgcn_global_load_lds(
      (const __attribute__((address_space(1))) void*)g,
      (__attribute__((address_space(3))) void*)l, 16, 0, 0);
}

// counted vmcnt wait (literal immediates only)
template<int N> __device__ __forceinline__ void vwait(){
  static_assert(N==0 || N==4 || N==6 || N==8, "bad vmcnt literal");
  if constexpr (N==0)  asm volatile("s_waitcnt vmcnt(0)" ::: "memory");
  else if constexpr (N==4)  asm volatile("s_waitcnt vmcnt(4)" ::: "memory");
  else if constexpr (N==6)  asm volatile("s_waitcnt vmcnt(6)" ::: "memory");
  else if constexpr (N==8)  asm volatile("s_waitcnt vmcnt(8)" ::: "memory");
}

// ---------------------------------------------------------------------------
// Weight transpose + f32->bf16 with generalized z-mapping
// ---------------------------------------------------------------------------
__global__ __launch_bounds__(256) void transpose_w_kernel(
    const float* __restrict__ W, u16* __restrict__ Wt, int R, int C,
    long szs1, long szs2, long dzs1, long dzs2, int zdiv)
{
  __shared__ float tile[32][33];
  const int tx = threadIdx.x & 31, ty = threadIdx.x >> 5;   // 32 x 8
  const int z = blockIdx.z;
  const long so = (long)(z / zdiv) * szs1 + (long)(z % zdiv) * szs2;
  const long dzo = (long)(z / zdiv) * dzs1 + (long)(z % zdiv) * dzs2;
  const int c0 = blockIdx.x << 5, r0 = blockIdx.y << 5;
  #pragma unroll
  for (int i = 0; i < 4; ++i)
    tile[ty + i*8][tx] = W[so + (long)(r0 + ty + i*8)*C + c0 + tx];
  __syncthreads();
  #pragma unroll
  for (int i = 0; i < 4; ++i)
    Wt[dzo + (long)(c0 + ty + i*8)*R + r0 + tx] = f2bf(tile[tx][ty + i*8]);
}

// ---------------------------------------------------------------------------
// 4 buffers f32 -> bf16 in one launch
// ---------------------------------------------------------------------------
__global__ __launch_bounds__(256) void f32_to_bf16_4(
    const float* __restrict__ a0, const float* __restrict__ a1,
    const float* __restrict__ a2, const float* __restrict__ a3,
    u16* __restrict__ o0, u16* __restrict__ o1,
    u16* __restrict__ o2, u16* __restrict__ o3, int n4)
{
  const float* s; u16* d;
  switch (blockIdx.y){
    case 0: s = a0; d = o0; break;
    case 1: s = a1; d = o1; break;
    case 2: s = a2; d = o2; break;
    default: s = a3; d = o3; break;
  }
  int i = blockIdx.x * 256 + threadIdx.x;
  if (i >= n4) return;
  float4 v = ((const float4*)s)[i];
  ushort4 o;
  o.x = f2bf(v.x); o.y = f2bf(v.y); o.z = f2bf(v.z); o.w = f2bf(v.w);
  ((ushort4*)d)[i] = o;
}

// ---------------------------------------------------------------------------
// Embedding gather
// ---------------------------------------------------------------------------
__global__ __launch_bounds__(256) void embed_kernel(
    const float* __restrict__ emb, const int* __restrict__ pvec,
    const float* __restrict__ pos, float* __restrict__ out)
{
  const int row = blockIdx.x;
  const int i = threadIdx.x;
  const int idx = pvec[row];
  const int t = row & (TT - 1);
  float4 e = ((const float4*)(emb + (long)idx * DD))[i];
  float4 p = ((const float4*)(pos + (long)t * DD))[i];
  float4 o;
  o.x = e.x * 32.0f + p.x; o.y = e.y * 32.0f + p.y;
  o.z = e.z * 32.0f + p.z; o.w = e.w * 32.0f + p.w;
  ((float4*)(out + (long)row * DD))[i] = o;
}

// ---------------------------------------------------------------------------
// LayerNorm(a) -> yf (f32, optional) and yb (bf16)
// ---------------------------------------------------------------------------
__global__ __launch_bounds__(256) void ln_kernel(
    const float* __restrict__ a, const float* __restrict__ res,
    float* __restrict__ yf, u16* __restrict__ yb)
{
  const int row = blockIdx.x;
  const int i = threadIdx.x;
  const int lane = i & 63, wid = i >> 6;
  float4 x = ((const float4*)(a + (long)row * DD))[i];
  if (res){
    float4 r4 = ((const float4*)(res + (long)row * DD))[i];
    x.x += r4.x; x.y += r4.y; x.z += r4.z; x.w += r4.w;
  }
  float s = x.x + x.y + x.z + x.w;
  #pragma unroll
  for (int o = 32; o; o >>= 1) s += __shfl_xor(s, o);
  __shared__ float red[4];
  if (lane == 0) red[wid] = s;
  __syncthreads();
  const float mean = (red[0] + red[1] + red[2] + red[3]) * (1.0f / DD);
  __syncthreads();
  const float dx = x.x - mean, dy = x.y - mean, dz = x.z - mean, dw = x.w - mean;
  float q = dx*dx + dy*dy + dz*dz + dw*dw;
  #pragma unroll
  for (int o = 32; o; o >>= 1) q += __shfl_xor(q, o);
  if (lane == 0) red[wid] = q;
  __syncthreads();
  const float var = (red[0] + red[1] + red[2] + red[3]) * (1.0f / DD);
  const float rstd = rsqrtf(var + 1e-5f);
  float4 y; y.x = dx*rstd; y.y = dy*rstd; y.z = dz*rstd; y.w = dw*rstd;
  if (yf) ((float4*)(yf + (long)row * DD))[i] = y;
  ushort4 o4; o4.x = f2bf(y.x); o4.y = f2bf(y.y); o4.z = f2bf(y.z); o4.w = f2bf(y.w);
  ((ushort4*)(yb + (long)row * DD))[i] = o4;
}

// ---------------------------------------------------------------------------
// Flash attention: one block per (q-tile 64, b*h). 4 waves x 16 q-rows.
// 2-deep counted-vmcnt K/V staging (41KB LDS -> 3 blocks/CU); setprio on MFMA.
// ---------------------------------------------------------------------------
template<bool CAUSAL>
__global__ __launch_bounds__(256, 2) void flash_kernel(
    const u16* __restrict__ Q, const u16* __restrict__ Kt,
    const u16* __restrict__ Vt, const int* __restrict__ cmask, int mode,
    u16* __restrict__ O)
{
  __shared__ __align__(16) u16 Ks[2][64*64];
  __shared__ __align__(16) u16 Vs[2][64*64];
  __shared__ __align__(16) u16 Ps[4*16*64];
  __shared__ float biasS[512];

  // XCD swizzle: all 8 q-tiles of one head land on one XCD (K/V L2 reuse)
  const int fid = blockIdx.y * 8 + blockIdx.x;          // 0..511
  const int lid = (fid & 7) * 64 + (fid >> 3);
  const int qt = lid & 7;
  const int bh = lid >> 3;
  const int b = bh >> 4, h = bh & 15;

  const int tid = threadIdx.x, lane = tid & 63, wid = tid >> 6;
  const int fr = lane & 15, kg = lane >> 4;

  if (!CAUSAL){
    #pragma unroll
    for (int r = 0; r < 2; ++r){
      const int c = r * 256 + tid;
      biasS[c] = (cmask[b * 512 + c] != mode) ? 0.0f : -1e20f;
    }
  }

  const long base = (long)bh * (512 * 64);
  const u16* qrow = Q + base + (long)(qt*64 + wid*16 + fr) * 64;
  const bfrag8 aq0 = *(const bfrag8*)(qrow + kg*8);
  const bfrag8 aq1 = *(const bfrag8*)(qrow + 32 + kg*8);

  const int srow = tid >> 3;                         // 0..31
  const int gcol = ((tid & 7) ^ (srow & 7)) * 8;     // pre-swizzled source chunk

  auto stageKV = [&](int buf, int kt){
    u16* Kd = Ks[buf] + wid * 512;
    u16* Vd = Vs[buf] + wid * 512;
    #pragma unroll
    for (int p = 0; p < 2; ++p)
      gload16(Kt + base + (long)(kt*64 + p*32 + srow) * 64 + gcol, Kd + p*2048);
    #pragma unroll
    for (int p = 0; p < 2; ++p)
      gload16(Vt + base + (long)(p*32 + srow) * 512 + kt*64 + gcol, Vd + p*2048);
  };

  float mrow[4], lrow[4];
  #pragma unroll
  for (int r = 0; r < 4; ++r){ mrow[r] = -3e38f; lrow[r] = 0.0f; }
  facc4 accO[4] = {};
  const facc4 z4 = {0.0f, 0.0f, 0.0f, 0.0f};

  const int NT = CAUSAL ? (qt + 1) : 8;   // causal: skip fully-masked tiles
  stageKV(0, 0);
  if (NT > 1){ stageKV(1, 1); vwait<4>(); }
  else vwait<0>();
  __builtin_amdgcn_s_barrier();

  u16* Pw = Ps + wid * 1024;

  for (int kt = 0; kt < NT; ++kt){
    const int cur = kt & 1;
    bfrag8 bk[4][2], bv[4][2];
    #pragma unroll
    for (int j = 0; j < 4; ++j)
      #pragma unroll
      for (int c2 = 0; c2 < 2; ++c2){
        const int po = (((c2*4 + kg) ^ (fr & 7)) * 8);
        bk[j][c2] = *(const bfrag8*)&Ks[cur][(j*16 + fr)*64 + po];
        bv[j][c2] = *(const bfrag8*)&Vs[cur][(j*16 + fr)*64 + po];
      }
    __builtin_amdgcn_sched_barrier(0);
    __builtin_amdgcn_s_barrier();                 // all waves read buf[cur]
    if (kt + 2 < NT){ stageKV(cur, kt + 2); vwait<4>(); }
    else vwait<0>();                              // stage(kt+1) landed
    __builtin_amdgcn_s_barrier();                 // ...for every wave

    // QK^T (rows = q, cols = kpos)
    facc4 sc[4];
    __builtin_amdgcn_s_setprio(1);
    #pragma unroll
    for (int j = 0; j < 4; ++j){
      sc[j] = __builtin_amdgcn_mfma_f32_16x16x32_bf16(aq0, bk[j][0], z4, 0, 0, 0);
      sc[j] = __builtin_amdgcn_mfma_f32_16x16x32_bf16(aq1, bk[j][1], sc[j], 0, 0, 0);
    }
    __builtin_amdgcn_s_setprio(0);
    // mask
    if (CAUSAL){
      const int rowb = qt*64 + wid*16 + kg*4;
      #pragma unroll
      for (int j = 0; j < 4; ++j){
        const int col = kt*64 + j*16 + fr;
        #pragma unroll
        for (int r = 0; r < 4; ++r)
          if (col > rowb + r) sc[j][r] = -1e20f;
      }
    } else {
      #pragma unroll
      for (int j = 0; j < 4; ++j){
        const float bval = biasS[kt*64 + j*16 + fr];
        #pragma unroll
        for (int r = 0; r < 4; ++r) sc[j][r] += bval;
      }
    }
    // online softmax (per-lane rows kg*4+rr; reduce across fr lanes)
    float tmax[4];
    #pragma unroll
    for (int r = 0; r < 4; ++r)
      tmax[r] = fmaxf(fmaxf(sc[0][r], sc[1][r]), fmaxf(sc[2][r], sc[3][r]));
    #pragma unroll
    for (int o = 1; o < 16; o <<= 1)
      #pragma unroll
      for (int r = 0; r < 4; ++r)
        tmax[r] = fmaxf(tmax[r], __shfl_xor(tmax[r], o));
    float fac[4];
    #pragma unroll
    for (int r = 0; r < 4; ++r){
      const float mn = fmaxf(mrow[r], tmax[r]);
      fac[r] = __expf(mrow[r] - mn);
      mrow[r] = mn;
    }
    float tsum[4] = {0.0f, 0.0f, 0.0f, 0.0f};
    #pragma unroll
    for (int j = 0; j < 4; ++j)
      #pragma unroll
      for (int r = 0; r < 4; ++r){
        const float p = __expf(sc[j][r] - mrow[r]);
        sc[j][r] = p; tsum[r] += p;
      }
    #pragma unroll
    for (int o = 1; o < 16; o <<= 1)
      #pragma unroll
      for (int r = 0; r < 4; ++r) tsum[r] += __shfl_xor(tsum[r], o);
    #pragma unroll
    for (int r = 0; r < 4; ++r) lrow[r] = lrow[r]*fac[r] + tsum[r];
    #pragma unroll
    for (int f = 0; f < 4; ++f)
      #pragma unroll
      for (int r = 0; r < 4; ++r) accO[f][r] *= fac[r];

    // P -> wave-private LDS (chunk-swizzled), read back as A-frags
    #pragma unroll
    for (int j = 0; j < 4; ++j)
      #pragma unroll
      for (int r = 0; r < 4; ++r){
        const int row = kg*4 + r;
        const int col = j*16 + fr;
        Pw[row*64 + (((col >> 3) ^ (row & 7)) * 8) + (col & 7)] = f2bf(sc[j][r]);
      }
    bfrag8 ap[2];
    #pragma unroll
    for (int c2 = 0; c2 < 2; ++c2)
      ap[c2] = *(const bfrag8*)&Pw[fr*64 + (((c2*4 + kg) ^ (fr & 7)) * 8)];
    __builtin_amdgcn_s_setprio(1);
    #pragma unroll
    for (int f = 0; f < 4; ++f){
      accO[f] = __builtin_amdgcn_mfma_f32_16x16x32_bf16(ap[0], bv[f][0], accO[f], 0, 0, 0);
      accO[f] = __builtin_amdgcn_mfma_f32_16x16x32_bf16(ap[1], bv[f][1], accO[f], 0, 0, 0);
    }
    __builtin_amdgcn_s_setprio(0);
  }

  // epilogue: divide by row sum, write [b*512+t][1024] at col h*64
  #pragma unroll
  for (int f = 0; f < 4; ++f)
    #pragma unroll
    for (int r = 0; r < 4; ++r){
      const int row = qt*64 + wid*16 + kg*4 + r;
      const int col = h*64 + f*16 + fr;
      O[(long)(b*512 + row) * 1024 + col] = f2bf(accO[f][r] / lrow[r]);
    }
}

// ---------------------------------------------------------------------------
#define MODE_F32  0
#define MODE_BF16 1
#define MODE_QKV  3
#define MODE_KV   4
#define MODE_Q    5

__device__ __forceinline__ long qk_off(int gm, int gn){   // [b,h,t,d]
  return (((long)(gm >> 9) * HH + (gn >> 6)) * TT + (gm & (TT-1))) * DHH + (gn & (DHH-1));
}
__device__ __forceinline__ long vt_off(int gm, int gn){   // [b,h,d,s]
  return (((long)(gm >> 9) * HH + (gn >> 6)) * DHH + (gn & (DHH-1))) * TT + (gm & (TT-1));
}

// ---------------------------------------------------------------------------
// 512-thread 128x256 GEMM (8 waves, 64x64/wave -> 32 MFMA : 16 ds_read).
// 2-deep counted-vmcnt. MODE_KV: z -> (ci,l,k/v) batch; MODE_BF16: plain.
// ---------------------------------------------------------------------------
template<int MODE>
__global__ __launch_bounds__(512, 2) void gemm_k8(
    const u16* __restrict__ A, const u16* __restrict__ B,
    const float* __restrict__ bias0, const float* __restrict__ bias1,
    u16* __restrict__ Cb0, int K, int lda, int ldb, int ldc, int relu)
{
  constexpr int BM = 128, BN = 256, BK = 64;
  constexpr int ASZ = BM * BK, BSZ = BN * BK;           // u16 per buffer
  __shared__ __align__(16) u16 As[2 * ASZ];
  __shared__ __align__(16) u16 Bs[2 * BSZ];

  // XCD-aware bijective block swizzle
  const int gx = gridDim.x, gy = gridDim.y;
  const int nwg = gx * gy * gridDim.z;
  const int fid = (blockIdx.z * gy + blockIdx.y) * gx + blockIdx.x;
  const int cpx = nwg >> 3;
  const int lid = (fid & 7) * cpx + (fid >> 3);
  const int bx = lid % gx;
  const int rem = lid / gx;
  const int by = rem % gy;
  const int z  = rem / gy;

  const u16* Ab;
  const u16* Bb;
  long cbase;
  constexpr long NBA = (long)2048 * 1024;
  constexpr long D2C = (long)DD * DD;
  if constexpr (MODE == MODE_KV){
    const int ci = z >> 2, ll = (z >> 1) & 1, isv = z & 1;
    Ab = A + (long)ci * NBA;
    Bb = B + (long)(ll*8 + ci*2 + isv) * D2C;
    cbase = (long)(ll*8 + ci*2 + isv) * NBA;
  } else {
    Ab = A; Bb = B; cbase = 0;
  }
  const int tid = threadIdx.x, lane = tid & 63, wid = tid >> 6;
  const int m0 = by * BM, n0 = bx * BN;
  const int wm = (wid >> 2) * 64, wn = (wid & 3) * 64;   // 2M x 4N wave grid
  const int fr = lane & 15, kg = lane >> 4;
  facc4 acc[4][4] = {};

  // staging: pass = 64 rows (8KB); thread t -> row t>>3, phys chunk t&7
  const int srow = tid >> 3;                       // 0..63
  const int gcol = (((tid & 7) ^ (srow & 7)) * 8);
  constexpr int AP = BM / 64, BP = BN / 64;        // 2, 4
  constexpr int LPS = AP + BP;                     // 6 per wave

  auto stage = [&](int buf, int k0){
    u16* Ad = As + buf * ASZ + wid * 512;
    u16* Bd = Bs + buf * BSZ + wid * 512;
    #pragma unroll
    for (int p = 0; p < AP; ++p)
      gload16(Ab + (long)(m0 + p*64 + srow) * lda + (k0 + gcol), Ad + p*4096);
    #pragma unroll
    for (int p = 0; p < BP; ++p)
      gload16(Bb + (long)(n0 + p*64 + srow) * ldb + (k0 + gcol), Bd + p*4096);
  };

  const int nsteps = K / BK;
  stage(0, 0);
  stage(1, BK);
  vwait<LPS>();
  __builtin_amdgcn_s_barrier();

  for (int s = 0; s < nsteps; ++s){
    const int cur = s & 1;
    const u16* Ar = As + cur * ASZ;
    const u16* Br = Bs + cur * BSZ;
    bfrag8 af[4][2], bfv[4][2];
    #pragma unroll
    for (int i = 0; i < 4; ++i)
      #pragma unroll
      for (int c2 = 0; c2 < 2; ++c2)
        af[i][c2] = *(const bfrag8*)&Ar[(wm + i*16 + fr) * 64 + (((c2*4 + kg) ^ (fr & 7)) * 8)];
    #pragma unroll
    for (int j = 0; j < 4; ++j)
      #pragma unroll
      for (int c2 = 0; c2 < 2; ++c2)
        bfv[j][c2] = *(const bfrag8*)&Br[(wn + j*16 + fr) * 64 + (((c2*4 + kg) ^ (fr & 7)) * 8)];
    __builtin_amdgcn_sched_barrier(0);
    __builtin_amdgcn_s_barrier();                 // all waves done reading buf[cur]
    if (s + 2 < nsteps){ stage(cur, (s + 2) * BK); vwait<LPS>(); }
    else if (s + 1 < nsteps) vwait<0>();
    __builtin_amdgcn_s_barrier();
    #pragma unroll
    for (int i = 0; i < 4; ++i)
      #pragma unroll
      for (int j = 0; j < 4; ++j){
        acc[i][j] = __builtin_amdgcn_mfma_f32_16x16x32_bf16(af[i][0], bfv[j][0], acc[i][j], 0, 0, 0);
        acc[i][j] = __builtin_amdgcn_mfma_f32_16x16x32_bf16(af[i][1], bfv[j][1], acc[i][j], 0, 0, 0);
      }
  }

  #pragma unroll
  for (int i = 0; i < 4; ++i){
    #pragma unroll
    for (int j = 0; j < 4; ++j){
      const int gn = n0 + wn + j*16 + fr;
      #pragma unroll
      for (int rr = 0; rr < 4; ++rr){
        const int gm = m0 + wm + i*16 + kg*4 + rr;
        float v = acc[i][j][rr];
        if constexpr (MODE == MODE_KV){
          const int ci = z >> 2, ll = (z >> 1) & 1, isv = z & 1;
          const float* bp = (isv ? bias1 : bias0) + (long)(ll*5 + ci + 1) * DD;
          const float vb = v + bp[gn];
          if (isv) Cb0[cbase + vt_off(gm, gn)] = f2bf(vb);
          else     Cb0[cbase + qk_off(gm, gn)] = f2bf(vb);
        } else {
          v = v + (bias0 ? bias0[gn] : 0.0f);
          if (relu) v = fmaxf(v, 0.0f);
          Cb0[cbase + (long)gm * ldc + gn] = f2bf(v);
        }
      }
    }
  }
}

// ---------------------------------------------------------------------------
// 256-thread bf16 MFMA GEMM, BK=64, 2-deep counted-vmcnt, XCD swizzle.
// MODE_F32: bias2 = optional residual matrix.
// ---------------------------------------------------------------------------
template<int BM, int BN, int MODE>
__global__ __launch_bounds__(256, 2) void gemm_k(
    const u16* __restrict__ A, const u16* __restrict__ B,
    const float* __restrict__ bias0, const float* __restrict__ bias1,
    const float* __restrict__ bias2,
    float* __restrict__ Cf, u16* __restrict__ Cb0,
    u16* __restrict__ Cb1, u16* __restrict__ Cb2,
    int K, int lda, int ldb, int ldc,
    long zsA, long zsB1, long zsB2, int zdivB,
    long czs1, long czs2, int zdivC, long bzs,
    int relu, float alpha)
{
  constexpr int BK = 64;
  constexpr int ASZ = BM * BK, BSZ = BN * BK;
  __shared__ __align__(16) u16 As[2 * ASZ];
  __shared__ __align__(16) u16 Bs[2 * BSZ];

  const int gx = gridDim.x, gy = gridDim.y;
  const int nwg = gx * gy * gridDim.z;
  const int fid = (blockIdx.z * gy + blockIdx.y) * gx + blockIdx.x;
  const int cpx = nwg >> 3;
  const int lid = (fid & 7) * cpx + (fid >> 3);
  const int bx = lid % gx;
  const int rem = lid / gx;
  const int by = rem % gy;
  const int z  = rem / gy;

  const u16* Ab = A + (long)z * zsA;
  const u16* Bb = B + (long)(z / zdivB) * zsB1 + (long)(z % zdivB) * zsB2;
  const long cbase = (long)(z / zdivC) * czs1 + (long)(z % zdivC) * czs2;
  const int tid = threadIdx.x, lane = tid & 63, wid = tid >> 6;
  const int m0 = by * BM, n0 = bx * BN;
  constexpr int WGN = (BN >= 128) ? 2 : 1, WGM = 4 / WGN;
  constexpr int TMW = BM / WGM, TNW = BN / WGN;
  constexpr int FM = TMW / 16, FN = TNW / 16;
  const int wm = (wid / WGN) * TMW, wn = (wid % WGN) * TNW;
  const int fr = lane & 15, kg = lane >> 4;
  facc4 acc[FM][FN] = {};

  const int srow = tid >> 3;
  const int gcol = (((tid & 7) ^ (srow & 7)) * 8);
  constexpr int AP = BM / 32, BP = BN / 32;
  constexpr int LPS = AP + BP;

  auto stage = [&](int buf, int k0){
    u16* Ad = As + buf * ASZ + wid * 512;
    u16* Bd = Bs + buf * BSZ + wid * 512;
    #pragma unroll
    for (int p = 0; p < AP; ++p)
      gload16(Ab + (long)(m0 + p*32 + srow) * lda + (k0 + gcol), Ad + p*2048);
    #pragma unroll
    for (int p = 0; p < BP; ++p)
      gload16(Bb + (long)(n0 + p*32 + srow) * ldb + (k0 + gcol), Bd + p*2048);
  };

  const int nsteps = K / BK;
  stage(0, 0);
  if (nsteps > 1){ stage(1, BK); vwait<LPS>(); }
  else vwait<0>();
  __builtin_amdgcn_s_barrier();

  for (int s = 0; s < nsteps; ++s){
    const int cur = s & 1;
    const u16* Ar = As + cur * ASZ;
    const u16* Br = Bs + cur * BSZ;
    bfrag8 af[FM][2], bfv[FN][2];
    #pragma unroll
    for (int i = 0; i < FM; ++i)
      #pragma unroll
      for (int c2 = 0; c2 < 2; ++c2)
        af[i][c2] = *(const bfrag8*)&Ar[(wm + i*16 + fr) * 64 + (((c2*4 + kg) ^ (fr & 7)) * 8)];
    #pragma unroll
    for (int j = 0; j < FN; ++j)
      #pragma unroll
      for (int c2 = 0; c2 < 2; ++c2)
        bfv[j][c2] = *(const bfrag8*)&Br[(wn + j*16 + fr) * 64 + (((c2*4 + kg) ^ (fr & 7)) * 8)];
    __builtin_amdgcn_sched_barrier(0);
    __builtin_amdgcn_s_barrier();
    if (s + 2 < nsteps){ stage(cur, (s + 2) * BK); vwait<LPS>(); }
    else if (s + 1 < nsteps) vwait<0>();
    __builtin_amdgcn_s_barrier();
    #pragma unroll
    for (int i = 0; i < FM; ++i)
      #pragma unroll
      for (int j = 0; j < FN; ++j){
        acc[i][j] = __builtin_amdgcn_mfma_f32_16x16x32_bf16(af[i][0], bfv[j][0], acc[i][j], 0, 0, 0);
        acc[i][j] = __builtin_amdgcn_mfma_f32_16x16x32_bf16(af[i][1], bfv[j][1], acc[i][j], 0, 0, 0);
      }
  }

  #pragma unroll
  for (int i = 0; i < FM; ++i){
    #pragma unroll
    for (int j = 0; j < FN; ++j){
      const int gn = n0 + wn + j*16 + fr;
      #pragma unroll
      for (int rr = 0; rr < 4; ++rr){
        const int gm = m0 + wm + i*16 + kg*4 + rr;
        float v = acc[i][j][rr];
        if constexpr (MODE == MODE_F32){
          v = (v + (bias0 ? bias0[gn] : 0.0f)) * alpha;
          if (relu) v = fmaxf(v, 0.0f);
          const long off = cbase + (long)gm * ldc + gn;
          if (bias2) v += bias2[off];             // fused residual
          Cf[off] = v;
        } else if constexpr (MODE == MODE_BF16){
          v = (v + (bias0 ? bias0[gn] : 0.0f)) * alpha;
          if (relu) v = fmaxf(v, 0.0f);
          Cb0[cbase + (long)gm * ldc + gn] = f2bf(v);
        } else if constexpr (MODE == MODE_QKV){
          const int sect = gn >> 10, nn = gn & (DD - 1);
          if (sect == 0)      Cb0[qk_off(gm, nn)] = f2bf((v + bias0[nn]) * alpha);
          else if (sect == 1) Cb1[qk_off(gm, nn)] = f2bf(v + bias1[nn]);
          else                Cb2[vt_off(gm, nn)] = f2bf(v + bias2[nn]);
        } else if constexpr (MODE == MODE_Q){
          Cb0[qk_off(gm, gn)] = f2bf((v + bias0[gn]) * alpha);
        }
      }
    }
  }
}

// ---------------------------------------------------------------------------
extern "C" void kernel_launch(void* const* d_in, const int* in_sizes, int n_in,
                              void* d_out, int out_size, void* d_ws, size_t ws_size,
                              hipStream_t stream)
{
  (void)in_sizes; (void)n_in; (void)out_size; (void)ws_size;
  const float* emb   = (const float*)d_in[0];
  const int*   pvec  = (const int*)d_in[1];
  const float* g_enc = (const float*)d_in[2];
  const float* g_con = (const float*)d_in[3];
  const float* g_db  = (const float*)d_in[4];
  const float* g_usr = (const float*)d_in[5];
  const int*   cmask = (const int*)d_in[6];
  const float* pose  = (const float*)d_in[7];
  const float* Wq = (const float*)d_in[8];
  const float* bq = (const float*)d_in[9];
  const float* Wk = (const float*)d_in[10];
  const float* bk = (const float*)d_in[11];
  const float* Wv = (const float*)d_in[12];
  const float* bv = (const float*)d_in[13];
  const float* Wo = (const float*)d_in[14];
  const float* bo = (const float*)d_in[15];
  const float* W1 = (const float*)d_in[16];
  const float* b1 = (const float*)d_in[17];
  const float* W2 = (const float*)d_in[18];
  const float* b2 = (const float*)d_in[19];
  float* out = (float*)d_out;

  const size_t NTOK = (size_t)BB * TT;   // 2048
  const long D2 = (long)DD * DD;

  char* wp = (char*)d_ws;
  auto alloc = [&](size_t bytes) -> char* {
    char* p = wp;
    wp += (bytes + 255) & ~(size_t)255;
    return p;
  };
  u16*   WqkvS = (u16*)  alloc(sizeof(u16) * 2 * 3 * D2);
  u16*   WkvC  = (u16*)  alloc(sizeof(u16) * 2 * 4 * 2 * D2);
  u16*   WqC   = (u16*)  alloc(sizeof(u16) * 2 * 4 * D2);
  u16*   WoT   = (u16*)  alloc(sizeof(u16) * 10 * D2);
  u16*   W1T   = (u16*)  alloc(sizeof(u16) * 2 * DD * FF);
  u16*   W2T   = (u16*)  alloc(sizeof(u16) * 2 * DD * FF);
  // kvb0..3 MUST stay contiguous: MODE_KV indexes them as [4][NTOK][DD]
  u16*   kvb0  = (u16*)  alloc(sizeof(u16) * NTOK * DD);
  u16*   kvb1  = (u16*)  alloc(sizeof(u16) * NTOK * DD);
  u16*   kvb2  = (u16*)  alloc(sizeof(u16) * NTOK * DD);
  u16*   kvb3  = (u16*)  alloc(sizeof(u16) * NTOK * DD);
  u16*   KVc   = (u16*)  alloc(sizeof(u16) * 16 * NTOK * DD);
  float* xf    = (float*)alloc(sizeof(float) * NTOK * DD);
  u16*   xb    = (u16*)  alloc(sizeof(u16) * NTOK * DD);
  u16*   Qb    = (u16*)  alloc(sizeof(u16) * NTOK * DD);
  u16*   Kb    = (u16*)  alloc(sizeof(u16) * NTOK * DD);
  u16*   Vtb   = (u16*)  alloc(sizeof(u16) * NTOK * DD);
  u16*   attnb = (u16*)  alloc(sizeof(u16) * NTOK * DD);
  float* obuf  = (float*)alloc(sizeof(float) * NTOK * DD);
  u16*   hb    = (u16*)  alloc(sizeof(u16) * NTOK * FF);

  // ---- weight prep ----
  const dim3 tg(32, 32, 2);
  transpose_w_kernel<<<tg, 256, 0, stream>>>(Wq, WqkvS,          DD, DD, 5*D2, 0, 3*D2, 0, 1);
  transpose_w_kernel<<<tg, 256, 0, stream>>>(Wk, WqkvS + D2,     DD, DD, 5*D2, 0, 3*D2, 0, 1);
  transpose_w_kernel<<<tg, 256, 0, stream>>>(Wv, WqkvS + 2*D2,   DD, DD, 5*D2, 0, 3*D2, 0, 1);
  transpose_w_kernel<<<dim3(32,32,8), 256, 0, stream>>>(Wk + D2, WkvC,      DD, DD, 5*D2, D2, 8*D2, 2*D2, 4);
  transpose_w_kernel<<<dim3(32,32,8), 256, 0, stream>>>(Wv + D2, WkvC + D2, DD, DD, 5*D2, D2, 8*D2, 2*D2, 4);
  transpose_w_kernel<<<dim3(32,32,8), 256, 0, stream>>>(Wq + D2, WqC,       DD, DD, 5*D2, D2, 4*D2, D2,   4);
  transpose_w_kernel<<<dim3(32,32,10),256, 0, stream>>>(Wo, WoT,            DD, DD, D2, 0, D2, 0, 1);
  transpose_w_kernel<<<dim3(128,32,2),256, 0, stream>>>(W1, W1T, DD, FF, (long)DD*FF, 0, (long)DD*FF, 0, 1);
  transpose_w_kernel<<<dim3(32,128,2),256, 0, stream>>>(W2, W2T, FF, DD, (long)DD*FF, 0, (long)DD*FF, 0, 1);

  const int n4 = (int)(NTOK * DD / 4);
  f32_to_bf16_4<<<dim3(n4/256, 4, 1), 256, 0, stream>>>(
      g_db, g_con, g_usr, g_enc, kvb0, kvb1, kvb2, kvb3, n4);

  embed_kernel<<<(int)NTOK, 256, 0, stream>>>(emb, pvec, pose, obuf);
  ln_kernel<<<(int)NTOK, 256, 0, stream>>>(obuf, nullptr, xf, xb);

  // ---- all cross-attention K/V in ONE 1024-block 512-thread launch ----
  const long NB = (long)NTOK * DD;
  gemm_k8<MODE_KV><<<dim3(4,16,16), 512, 0, stream>>>(
    kvb0, WkvC, bk, bv, KVc, DD, DD, DD, 0, 0);

  const int modeTab[5] = {-1, 2, 1, 3, 0};

  for (int l = 0; l < 2; ++l){
    for (int i = 0; i < 5; ++i){
      const u16 *Kp, *Vp;
      if (i == 0){
        gemm_k<64,128,MODE_QKV><<<dim3(24,32,1), 256, 0, stream>>>(
          xb, WqkvS + (long)l*3*D2,
          bq + (size_t)l*5*DD, bk + (size_t)l*5*DD, bv + (size_t)l*5*DD,
          nullptr, Qb, Kb, Vtb,
          DD, DD, DD, 0,
          0, 0, 0, 1, 0, 0, 1, 0,
          0, 0.125f);
        Kp = Kb; Vp = Vtb;
      } else {
        const int ci = i - 1;
        gemm_k<64,128,MODE_Q><<<dim3(8,32,1), 256, 0, stream>>>(
          xb, WqC + (long)(l*4 + ci)*D2,
          bq + (size_t)(l*5 + i)*DD, nullptr, nullptr,
          nullptr, Qb, nullptr, nullptr,
          DD, DD, DD, 0,
          0, 0, 0, 1, 0, 0, 1, 0,
          0, 0.125f);
        Kp = KVc + ((long)l*8 + ci*2)*NB;
        Vp = Kp + NB;
      }
      // fused attention (QK^T + masked softmax + PV)
      if (i == 0)
        flash_kernel<true><<<dim3(8,64), 256, 0, stream>>>(
            Qb, Kp, Vp, cmask, 0, attnb);
      else
        flash_kernel<false><<<dim3(8,64), 256, 0, stream>>>(
            Qb, Kp, Vp, cmask, modeTab[i], attnb);
      // O-projection + fused residual (f32 out)
      gemm_k<64,128,MODE_F32><<<dim3(8,32,1), 256, 0, stream>>>(
        attnb, WoT + (long)(l*5 + i)*D2,
        bo + (size_t)(l*5 + i)*DD, nullptr, xf,
        obuf, nullptr, nullptr, nullptr,
        DD, DD, DD, DD,
        0, 0, 0, 1, 0, 0, 1, 0,
        0, 1.0f);
      ln_kernel<<<(int)NTOK, 256, 0, stream>>>(obuf, nullptr, xf, xb);
    }
    // FFN
    gemm_k8<MODE_BF16><<<dim3(16,16,1), 512, 0, stream>>>(
      xb, W1T + (size_t)l*DD*FF, b1 + (size_t)l*FF, nullptr,
      hb, DD, DD, DD, FF, 1);
    gemm_k<64,128,MODE_F32><<<dim3(8,32,1), 256, 0, stream>>>(
      hb, W2T + (size_t)l*DD*FF,
      b2 + (size_t)l*DD, nullptr, xf,
      obuf, nullptr, nullptr, nullptr,
      FF, FF, FF, DD,
      0, 0, 0, 1, 0, 0, 1, 0,
      0, 1.0f);
    float* yf = (l == 1) ? out : xf;
    ln_kernel<<<(int)NTOK, 256, 0, stream>>>(obuf, nullptr, yf, xb);
  }
}

// Round 7
// 1061.051 us; speedup vs baseline: 1.0940x; 1.0859x over previous
//
#include <hip/hip_runtime.h>

// Problem constants (Bert4KGModel): B=4, T=S=512, D=1024, H=16, dh=64, F=4096, L=2
#define BB  4
#define TT  512
#define DD  1024
#define HH  16
#define DHH 64
#define FF  4096

typedef unsigned short u16;
typedef __attribute__((ext_vector_type(8))) short bfrag8;   // 8 bf16 (4 VGPRs)
typedef __attribute__((ext_vector_type(4))) float facc4;    // 4 f32 acc

__device__ __forceinline__ u16 f2bf(float f){
  unsigned u = __float_as_uint(f);
  unsigned r = u + 0x7fffu + ((u >> 16) & 1u);   // RNE
  return (u16)(r >> 16);
}
__device__ __forceinline__ float bf2f(u16 h){
  return __uint_as_float(((unsigned)h) << 16);
}

// async global->LDS, 16B per lane; LDS dest is wave-uniform base + lane*16
__device__ __forceinline__ void gload16(const u16* g, u16* l){
  __builtin_amdgcn_global_load_lds(
      (const __attribute__((address_space(1))) void*)g,
      (__attribute__((address_space(3))) void*)l, 16, 0, 0);
}

// counted vmcnt wait (literal immediates only)
template<int N> __device__ __forceinline__ void vwait(){
  static_assert(N==0 || N==4 || N==6 || N==8, "bad vmcnt literal");
  if constexpr (N==0)  asm volatile("s_waitcnt vmcnt(0)" ::: "memory");
  else if constexpr (N==4)  asm volatile("s_waitcnt vmcnt(4)" ::: "memory");
  else if constexpr (N==6)  asm volatile("s_waitcnt vmcnt(6)" ::: "memory");
  else if constexpr (N==8)  asm volatile("s_waitcnt vmcnt(8)" ::: "memory");
}

// ---------------------------------------------------------------------------
// Weight transpose + f32->bf16 with generalized z-mapping
// ---------------------------------------------------------------------------
__global__ __launch_bounds__(256) void transpose_w_kernel(
    const float* __restrict__ W, u16* __restrict__ Wt, int R, int C,
    long szs1, long szs2, long dzs1, long dzs2, int zdiv)
{
  __shared__ float tile[32][33];
  const int tx = threadIdx.x & 31, ty = threadIdx.x >> 5;   // 32 x 8
  const int z = blockIdx.z;
  const long so = (long)(z / zdiv) * szs1 + (long)(z % zdiv) * szs2;
  const long dzo = (long)(z / zdiv) * dzs1 + (long)(z % zdiv) * dzs2;
  const int c0 = blockIdx.x << 5, r0 = blockIdx.y << 5;
  #pragma unroll
  for (int i = 0; i < 4; ++i)
    tile[ty + i*8][tx] = W[so + (long)(r0 + ty + i*8)*C + c0 + tx];
  __syncthreads();
  #pragma unroll
  for (int i = 0; i < 4; ++i)
    Wt[dzo + (long)(c0 + ty + i*8)*R + r0 + tx] = f2bf(tile[tx][ty + i*8]);
}

// ---------------------------------------------------------------------------
// 4 buffers f32 -> bf16 in one launch
// ---------------------------------------------------------------------------
__global__ __launch_bounds__(256) void f32_to_bf16_4(
    const float* __restrict__ a0, const float* __restrict__ a1,
    const float* __restrict__ a2, const float* __restrict__ a3,
    u16* __restrict__ o0, u16* __restrict__ o1,
    u16* __restrict__ o2, u16* __restrict__ o3, int n4)
{
  const float* s; u16* d;
  switch (blockIdx.y){
    case 0: s = a0; d = o0; break;
    case 1: s = a1; d = o1; break;
    case 2: s = a2; d = o2; break;
    default: s = a3; d = o3; break;
  }
  int i = blockIdx.x * 256 + threadIdx.x;
  if (i >= n4) return;
  float4 v = ((const float4*)s)[i];
  ushort4 o;
  o.x = f2bf(v.x); o.y = f2bf(v.y); o.z = f2bf(v.z); o.w = f2bf(v.w);
  ((ushort4*)d)[i] = o;
}

// ---------------------------------------------------------------------------
// Embedding gather
// ---------------------------------------------------------------------------
__global__ __launch_bounds__(256) void embed_kernel(
    const float* __restrict__ emb, const int* __restrict__ pvec,
    const float* __restrict__ pos, float* __restrict__ out)
{
  const int row = blockIdx.x;
  const int i = threadIdx.x;
  const int idx = pvec[row];
  const int t = row & (TT - 1);
  float4 e = ((const float4*)(emb + (long)idx * DD))[i];
  float4 p = ((const float4*)(pos + (long)t * DD))[i];
  float4 o;
  o.x = e.x * 32.0f + p.x; o.y = e.y * 32.0f + p.y;
  o.z = e.z * 32.0f + p.z; o.w = e.w * 32.0f + p.w;
  ((float4*)(out + (long)row * DD))[i] = o;
}

// ---------------------------------------------------------------------------
// LayerNorm(a [+ res]) -> yf (f32, optional) and yb (bf16)
// ---------------------------------------------------------------------------
__global__ __launch_bounds__(256) void ln_kernel(
    const float* __restrict__ a, const float* __restrict__ res,
    float* __restrict__ yf, u16* __restrict__ yb)
{
  const int row = blockIdx.x;
  const int i = threadIdx.x;
  const int lane = i & 63, wid = i >> 6;
  float4 x = ((const float4*)(a + (long)row * DD))[i];
  if (res){
    float4 r4 = ((const float4*)(res + (long)row * DD))[i];
    x.x += r4.x; x.y += r4.y; x.z += r4.z; x.w += r4.w;
  }
  float s = x.x + x.y + x.z + x.w;
  #pragma unroll
  for (int o = 32; o; o >>= 1) s += __shfl_xor(s, o);
  __shared__ float red[4];
  if (lane == 0) red[wid] = s;
  __syncthreads();
  const float mean = (red[0] + red[1] + red[2] + red[3]) * (1.0f / DD);
  __syncthreads();
  const float dx = x.x - mean, dy = x.y - mean, dz = x.z - mean, dw = x.w - mean;
  float q = dx*dx + dy*dy + dz*dz + dw*dw;
  #pragma unroll
  for (int o = 32; o; o >>= 1) q += __shfl_xor(q, o);
  if (lane == 0) red[wid] = q;
  __syncthreads();
  const float var = (red[0] + red[1] + red[2] + red[3]) * (1.0f / DD);
  const float rstd = rsqrtf(var + 1e-5f);
  float4 y; y.x = dx*rstd; y.y = dy*rstd; y.z = dz*rstd; y.w = dw*rstd;
  if (yf) ((float4*)(yf + (long)row * DD))[i] = y;
  ushort4 o4; o4.x = f2bf(y.x); o4.y = f2bf(y.y); o4.z = f2bf(y.z); o4.w = f2bf(y.w);
  ((ushort4*)(yb + (long)row * DD))[i] = o4;
}

// ---------------------------------------------------------------------------
// Flash attention: one block per (q-tile 64, b*h). 4 waves x 16 q-rows.
// 2-deep counted-vmcnt K/V staging (41KB LDS -> 3 blocks/CU); setprio on MFMA.
// ---------------------------------------------------------------------------
template<bool CAUSAL>
__global__ __launch_bounds__(256, 2) void flash_kernel(
    const u16* __restrict__ Q, const u16* __restrict__ Kt,
    const u16* __restrict__ Vt, const int* __restrict__ cmask, int mode,
    u16* __restrict__ O)
{
  __shared__ __align__(16) u16 Ks[2][64*64];
  __shared__ __align__(16) u16 Vs[2][64*64];
  __shared__ __align__(16) u16 Ps[4*16*64];
  __shared__ float biasS[512];

  // XCD swizzle: all 8 q-tiles of one head land on one XCD (K/V L2 reuse)
  const int fid = blockIdx.y * 8 + blockIdx.x;          // 0..511
  const int lid = (fid & 7) * 64 + (fid >> 3);
  const int qt = lid & 7;
  const int bh = lid >> 3;
  const int b = bh >> 4, h = bh & 15;

  const int tid = threadIdx.x, lane = tid & 63, wid = tid >> 6;
  const int fr = lane & 15, kg = lane >> 4;

  if (!CAUSAL){
    #pragma unroll
    for (int r = 0; r < 2; ++r){
      const int c = r * 256 + tid;
      biasS[c] = (cmask[b * 512 + c] != mode) ? 0.0f : -1e20f;
    }
  }

  const long base = (long)bh * (512 * 64);
  const u16* qrow = Q + base + (long)(qt*64 + wid*16 + fr) * 64;
  const bfrag8 aq0 = *(const bfrag8*)(qrow + kg*8);
  const bfrag8 aq1 = *(const bfrag8*)(qrow + 32 + kg*8);

  const int srow = tid >> 3;                         // 0..31
  const int gcol = ((tid & 7) ^ (srow & 7)) * 8;     // pre-swizzled source chunk

  auto stageKV = [&](int buf, int kt){
    u16* Kd = Ks[buf] + wid * 512;
    u16* Vd = Vs[buf] + wid * 512;
    #pragma unroll
    for (int p = 0; p < 2; ++p)
      gload16(Kt + base + (long)(kt*64 + p*32 + srow) * 64 + gcol, Kd + p*2048);
    #pragma unroll
    for (int p = 0; p < 2; ++p)
      gload16(Vt + base + (long)(p*32 + srow) * 512 + kt*64 + gcol, Vd + p*2048);
  };

  float mrow[4], lrow[4];
  #pragma unroll
  for (int r = 0; r < 4; ++r){ mrow[r] = -3e38f; lrow[r] = 0.0f; }
  facc4 accO[4] = {};
  const facc4 z4 = {0.0f, 0.0f, 0.0f, 0.0f};

  const int NT = CAUSAL ? (qt + 1) : 8;   // causal: skip fully-masked tiles
  stageKV(0, 0);
  if (NT > 1){ stageKV(1, 1); vwait<4>(); }
  else vwait<0>();
  __builtin_amdgcn_s_barrier();

  u16* Pw = Ps + wid * 1024;

  for (int kt = 0; kt < NT; ++kt){
    const int cur = kt & 1;
    bfrag8 bk[4][2], bv[4][2];
    #pragma unroll
    for (int j = 0; j < 4; ++j)
      #pragma unroll
      for (int c2 = 0; c2 < 2; ++c2){
        const int po = (((c2*4 + kg) ^ (fr & 7)) * 8);
        bk[j][c2] = *(const bfrag8*)&Ks[cur][(j*16 + fr)*64 + po];
        bv[j][c2] = *(const bfrag8*)&Vs[cur][(j*16 + fr)*64 + po];
      }
    __builtin_amdgcn_sched_barrier(0);
    __builtin_amdgcn_s_barrier();                 // all waves read buf[cur]
    if (kt + 2 < NT){ stageKV(cur, kt + 2); vwait<4>(); }
    else vwait<0>();                              // stage(kt+1) landed
    __builtin_amdgcn_s_barrier();                 // ...for every wave

    // QK^T (rows = q, cols = kpos)
    facc4 sc[4];
    __builtin_amdgcn_s_setprio(1);
    #pragma unroll
    for (int j = 0; j < 4; ++j){
      sc[j] = __builtin_amdgcn_mfma_f32_16x16x32_bf16(aq0, bk[j][0], z4, 0, 0, 0);
      sc[j] = __builtin_amdgcn_mfma_f32_16x16x32_bf16(aq1, bk[j][1], sc[j], 0, 0, 0);
    }
    __builtin_amdgcn_s_setprio(0);
    // mask
    if (CAUSAL){
      const int rowb = qt*64 + wid*16 + kg*4;
      #pragma unroll
      for (int j = 0; j < 4; ++j){
        const int col = kt*64 + j*16 + fr;
        #pragma unroll
        for (int r = 0; r < 4; ++r)
          if (col > rowb + r) sc[j][r] = -1e20f;
      }
    } else {
      #pragma unroll
      for (int j = 0; j < 4; ++j){
        const float bval = biasS[kt*64 + j*16 + fr];
        #pragma unroll
        for (int r = 0; r < 4; ++r) sc[j][r] += bval;
      }
    }
    // online softmax (per-lane rows kg*4+rr; reduce across fr lanes)
    float tmax[4];
    #pragma unroll
    for (int r = 0; r < 4; ++r)
      tmax[r] = fmaxf(fmaxf(sc[0][r], sc[1][r]), fmaxf(sc[2][r], sc[3][r]));
    #pragma unroll
    for (int o = 1; o < 16; o <<= 1)
      #pragma unroll
      for (int r = 0; r < 4; ++r)
        tmax[r] = fmaxf(tmax[r], __shfl_xor(tmax[r], o));
    float fac[4];
    #pragma unroll
    for (int r = 0; r < 4; ++r){
      const float mn = fmaxf(mrow[r], tmax[r]);
      fac[r] = __expf(mrow[r] - mn);
      mrow[r] = mn;
    }
    float tsum[4] = {0.0f, 0.0f, 0.0f, 0.0f};
    #pragma unroll
    for (int j = 0; j < 4; ++j)
      #pragma unroll
      for (int r = 0; r < 4; ++r){
        const float p = __expf(sc[j][r] - mrow[r]);
        sc[j][r] = p; tsum[r] += p;
      }
    #pragma unroll
    for (int o = 1; o < 16; o <<= 1)
      #pragma unroll
      for (int r = 0; r < 4; ++r) tsum[r] += __shfl_xor(tsum[r], o);
    #pragma unroll
    for (int r = 0; r < 4; ++r) lrow[r] = lrow[r]*fac[r] + tsum[r];
    #pragma unroll
    for (int f = 0; f < 4; ++f)
      #pragma unroll
      for (int r = 0; r < 4; ++r) accO[f][r] *= fac[r];

    // P -> wave-private LDS (chunk-swizzled), read back as A-frags
    #pragma unroll
    for (int j = 0; j < 4; ++j)
      #pragma unroll
      for (int r = 0; r < 4; ++r){
        const int row = kg*4 + r;
        const int col = j*16 + fr;
        Pw[row*64 + (((col >> 3) ^ (row & 7)) * 8) + (col & 7)] = f2bf(sc[j][r]);
      }
    bfrag8 ap[2];
    #pragma unroll
    for (int c2 = 0; c2 < 2; ++c2)
      ap[c2] = *(const bfrag8*)&Pw[fr*64 + (((c2*4 + kg) ^ (fr & 7)) * 8)];
    __builtin_amdgcn_s_setprio(1);
    #pragma unroll
    for (int f = 0; f < 4; ++f){
      accO[f] = __builtin_amdgcn_mfma_f32_16x16x32_bf16(ap[0], bv[f][0], accO[f], 0, 0, 0);
      accO[f] = __builtin_amdgcn_mfma_f32_16x16x32_bf16(ap[1], bv[f][1], accO[f], 0, 0, 0);
    }
    __builtin_amdgcn_s_setprio(0);
  }

  // epilogue: divide by row sum, write [b*512+t][1024] at col h*64
  #pragma unroll
  for (int f = 0; f < 4; ++f)
    #pragma unroll
    for (int r = 0; r < 4; ++r){
      const int row = qt*64 + wid*16 + kg*4 + r;
      const int col = h*64 + f*16 + fr;
      O[(long)(b*512 + row) * 1024 + col] = f2bf(accO[f][r] / lrow[r]);
    }
}

// ---------------------------------------------------------------------------
#define MODE_F32  0
#define MODE_BF16 1
#define MODE_QKV  3
#define MODE_KV   4
#define MODE_Q    5

__device__ __forceinline__ long qk_off(int gm, int gn){   // [b,h,t,d]
  return (((long)(gm >> 9) * HH + (gn >> 6)) * TT + (gm & (TT-1))) * DHH + (gn & (DHH-1));
}
__device__ __forceinline__ long vt_off(int gm, int gn){   // [b,h,d,s]
  return (((long)(gm >> 9) * HH + (gn >> 6)) * DHH + (gn & (DHH-1))) * TT + (gm & (TT-1));
}

// ---------------------------------------------------------------------------
// 256-thread bf16 MFMA GEMM, BK=64, 2-deep counted-vmcnt, XCD swizzle.
// Tiles: 64x64 (2x2 waves, 32KB LDS) or 64x128 (2x2N waves, 48KB LDS).
// MODE_F32: bias2 = optional residual matrix.
// MODE_KV: z -> (ci, l, k/v); A = contiguous kvb[4]; writes K/V^T layouts.
// ---------------------------------------------------------------------------
template<int BM, int BN, int MODE>
__global__ __launch_bounds__(256, 2) void gemm_k(
    const u16* __restrict__ A, const u16* __restrict__ B,
    const float* __restrict__ bias0, const float* __restrict__ bias1,
    const float* __restrict__ bias2,
    float* __restrict__ Cf, u16* __restrict__ Cb0,
    u16* __restrict__ Cb1, u16* __restrict__ Cb2,
    int K, int lda, int ldb, int ldc,
    long zsA, long zsB1, long zsB2, int zdivB,
    long czs1, long czs2, int zdivC, long bzs,
    int relu, float alpha)
{
  constexpr int BK = 64;
  constexpr int ASZ = BM * BK, BSZ = BN * BK;
  __shared__ __align__(16) u16 As[2 * ASZ];
  __shared__ __align__(16) u16 Bs[2 * BSZ];

  // XCD-aware bijective block swizzle (all grids are %8 == 0)
  const int gx = gridDim.x, gy = gridDim.y;
  const int nwg = gx * gy * gridDim.z;
  const int fid = (blockIdx.z * gy + blockIdx.y) * gx + blockIdx.x;
  const int cpx = nwg >> 3;
  const int lid = (fid & 7) * cpx + (fid >> 3);
  const int bx = lid % gx;
  const int rem = lid / gx;
  const int by = rem % gy;
  const int z  = rem / gy;

  const u16* Ab;
  const u16* Bb;
  long cbase;
  constexpr long NBA = (long)2048 * 1024;      // one kv / KVc block (u16 elems)
  constexpr long D2C = (long)DD * DD;
  if constexpr (MODE == MODE_KV){
    const int ci = z >> 2, ll = (z >> 1) & 1, isv = z & 1;
    Ab = A + (long)ci * NBA;
    Bb = B + (long)(ll*8 + ci*2 + isv) * D2C;
    cbase = (long)(ll*8 + ci*2 + isv) * NBA;
  } else {
    Ab = A + (long)z * zsA;
    Bb = B + (long)(z / zdivB) * zsB1 + (long)(z % zdivB) * zsB2;
    cbase = (long)(z / zdivC) * czs1 + (long)(z % zdivC) * czs2;
  }
  const int tid = threadIdx.x, lane = tid & 63, wid = tid >> 6;
  const int m0 = by * BM, n0 = bx * BN;
  constexpr int WGN = 2, WGM = 2;                      // 2x2 wave grid
  constexpr int TMW = BM / WGM, TNW = BN / WGN;
  constexpr int FM = TMW / 16, FN = TNW / 16;
  const int wm = (wid >> 1) * TMW, wn = (wid & 1) * TNW;
  const int fr = lane & 15, kg = lane >> 4;
  facc4 acc[FM][FN] = {};

  // staging: pass = 32 rows (4KB); thread t -> row t>>3, phys chunk t&7;
  // global chunk pre-swizzled: LDS[r][c] = G[r][c^(r&7)]
  const int srow = tid >> 3;
  const int gcol = (((tid & 7) ^ (srow & 7)) * 8);
  constexpr int AP = BM / 32, BP = BN / 32;
  constexpr int LPS = AP + BP;

  auto stage = [&](int buf, int k0){
    u16* Ad = As + buf * ASZ + wid * 512;
    u16* Bd = Bs + buf * BSZ + wid * 512;
    #pragma unroll
    for (int p = 0; p < AP; ++p)
      gload16(Ab + (long)(m0 + p*32 + srow) * lda + (k0 + gcol), Ad + p*2048);
    #pragma unroll
    for (int p = 0; p < BP; ++p)
      gload16(Bb + (long)(n0 + p*32 + srow) * ldb + (k0 + gcol), Bd + p*2048);
  };

  const int nsteps = K / BK;
  stage(0, 0);
  if (nsteps > 1){ stage(1, BK); vwait<LPS>(); }
  else vwait<0>();
  __builtin_amdgcn_s_barrier();

  for (int s = 0; s < nsteps; ++s){
    const int cur = s & 1;
    const u16* Ar = As + cur * ASZ;
    const u16* Br = Bs + cur * BSZ;
    bfrag8 af[FM][2], bfv[FN][2];
    #pragma unroll
    for (int i = 0; i < FM; ++i)
      #pragma unroll
      for (int c2 = 0; c2 < 2; ++c2)
        af[i][c2] = *(const bfrag8*)&Ar[(wm + i*16 + fr) * 64 + (((c2*4 + kg) ^ (fr & 7)) * 8)];
    #pragma unroll
    for (int j = 0; j < FN; ++j)
      #pragma unroll
      for (int c2 = 0; c2 < 2; ++c2)
        bfv[j][c2] = *(const bfrag8*)&Br[(wn + j*16 + fr) * 64 + (((c2*4 + kg) ^ (fr & 7)) * 8)];
    __builtin_amdgcn_sched_barrier(0);
    __builtin_amdgcn_s_barrier();                 // all waves done reading buf[cur]
    if (s + 2 < nsteps){ stage(cur, (s + 2) * BK); vwait<LPS>(); }
    else if (s + 1 < nsteps) vwait<0>();
    __builtin_amdgcn_s_barrier();                 // buf[s+1] landed for every wave
    #pragma unroll
    for (int i = 0; i < FM; ++i)
      #pragma unroll
      for (int j = 0; j < FN; ++j){
        acc[i][j] = __builtin_amdgcn_mfma_f32_16x16x32_bf16(af[i][0], bfv[j][0], acc[i][j], 0, 0, 0);
        acc[i][j] = __builtin_amdgcn_mfma_f32_16x16x32_bf16(af[i][1], bfv[j][1], acc[i][j], 0, 0, 0);
      }
  }

  // Epilogue. C/D frag layout: col = fr, row = kg*4 + rr.
  #pragma unroll
  for (int i = 0; i < FM; ++i){
    #pragma unroll
    for (int j = 0; j < FN; ++j){
      const int gn = n0 + wn + j*16 + fr;
      #pragma unroll
      for (int rr = 0; rr < 4; ++rr){
        const int gm = m0 + wm + i*16 + kg*4 + rr;
        float v = acc[i][j][rr];
        if constexpr (MODE == MODE_F32){
          v = (v + (bias0 ? bias0[gn] : 0.0f)) * alpha;
          if (relu) v = fmaxf(v, 0.0f);
          const long off = cbase + (long)gm * ldc + gn;
          if (bias2) v += bias2[off];             // fused residual
          Cf[off] = v;
        } else if constexpr (MODE == MODE_BF16){
          v = (v + (bias0 ? bias0[gn] : 0.0f)) * alpha;
          if (relu) v = fmaxf(v, 0.0f);
          Cb0[cbase + (long)gm * ldc + gn] = f2bf(v);
        } else if constexpr (MODE == MODE_QKV){
          const int sect = gn >> 10, nn = gn & (DD - 1);
          if (sect == 0)      Cb0[qk_off(gm, nn)] = f2bf((v + bias0[nn]) * alpha);
          else if (sect == 1) Cb1[qk_off(gm, nn)] = f2bf(v + bias1[nn]);
          else                Cb2[vt_off(gm, nn)] = f2bf(v + bias2[nn]);
        } else if constexpr (MODE == MODE_Q){
          Cb0[qk_off(gm, gn)] = f2bf((v + bias0[gn]) * alpha);
        } else {  // MODE_KV: z -> (ci, l, k/v)
          const int ci = z >> 2, ll = (z >> 1) & 1, isv = z & 1;
          const float* bp = (isv ? bias1 : bias0) + (long)(ll*5 + ci + 1) * DD;
          const float vb = v + bp[gn];
          if (isv) Cb0[cbase + vt_off(gm, gn)] = f2bf(vb);
          else     Cb0[cbase + qk_off(gm, gn)] = f2bf(vb);
        }
      }
    }
  }
}

// ---------------------------------------------------------------------------
extern "C" void kernel_launch(void* const* d_in, const int* in_sizes, int n_in,
                              void* d_out, int out_size, void* d_ws, size_t ws_size,
                              hipStream_t stream)
{
  (void)in_sizes; (void)n_in; (void)out_size; (void)ws_size;
  const float* emb   = (const float*)d_in[0];
  const int*   pvec  = (const int*)d_in[1];
  const float* g_enc = (const float*)d_in[2];
  const float* g_con = (const float*)d_in[3];
  const float* g_db  = (const float*)d_in[4];
  const float* g_usr = (const float*)d_in[5];
  const int*   cmask = (const int*)d_in[6];
  const float* pose  = (const float*)d_in[7];
  const float* Wq = (const float*)d_in[8];
  const float* bq = (const float*)d_in[9];
  const float* Wk = (const float*)d_in[10];
  const float* bk = (const float*)d_in[11];
  const float* Wv = (const float*)d_in[12];
  const float* bv = (const float*)d_in[13];
  const float* Wo = (const float*)d_in[14];
  const float* bo = (const float*)d_in[15];
  const float* W1 = (const float*)d_in[16];
  const float* b1 = (const float*)d_in[17];
  const float* W2 = (const float*)d_in[18];
  const float* b2 = (const float*)d_in[19];
  float* out = (float*)d_out;

  const size_t NTOK = (size_t)BB * TT;   // 2048
  const long D2 = (long)DD * DD;

  char* wp = (char*)d_ws;
  auto alloc = [&](size_t bytes) -> char* {
    char* p = wp;
    wp += (bytes + 255) & ~(size_t)255;
    return p;
  };
  u16*   WqkvS = (u16*)  alloc(sizeof(u16) * 2 * 3 * D2);
  u16*   WkvC  = (u16*)  alloc(sizeof(u16) * 2 * 4 * 2 * D2);
  u16*   WqC   = (u16*)  alloc(sizeof(u16) * 2 * 4 * D2);
  u16*   WoT   = (u16*)  alloc(sizeof(u16) * 10 * D2);
  u16*   W1T   = (u16*)  alloc(sizeof(u16) * 2 * DD * FF);
  u16*   W2T   = (u16*)  alloc(sizeof(u16) * 2 * DD * FF);
  // kvb0..3 MUST stay contiguous: MODE_KV indexes them as [4][NTOK][DD]
  u16*   kvb0  = (u16*)  alloc(sizeof(u16) * NTOK * DD);
  u16*   kvb1  = (u16*)  alloc(sizeof(u16) * NTOK * DD);
  u16*   kvb2  = (u16*)  alloc(sizeof(u16) * NTOK * DD);
  u16*   kvb3  = (u16*)  alloc(sizeof(u16) * NTOK * DD);
  u16*   KVc   = (u16*)  alloc(sizeof(u16) * 16 * NTOK * DD);
  float* xf    = (float*)alloc(sizeof(float) * NTOK * DD);
  u16*   xb    = (u16*)  alloc(sizeof(u16) * NTOK * DD);
  u16*   Qb    = (u16*)  alloc(sizeof(u16) * NTOK * DD);
  u16*   Kb    = (u16*)  alloc(sizeof(u16) * NTOK * DD);
  u16*   Vtb   = (u16*)  alloc(sizeof(u16) * NTOK * DD);
  u16*   attnb = (u16*)  alloc(sizeof(u16) * NTOK * DD);
  float* obuf  = (float*)alloc(sizeof(float) * NTOK * DD);
  u16*   hb    = (u16*)  alloc(sizeof(u16) * NTOK * FF);

  // ---- weight prep ----
  const dim3 tg(32, 32, 2);
  transpose_w_kernel<<<tg, 256, 0, stream>>>(Wq, WqkvS,          DD, DD, 5*D2, 0, 3*D2, 0, 1);
  transpose_w_kernel<<<tg, 256, 0, stream>>>(Wk, WqkvS + D2,     DD, DD, 5*D2, 0, 3*D2, 0, 1);
  transpose_w_kernel<<<tg, 256, 0, stream>>>(Wv, WqkvS + 2*D2,   DD, DD, 5*D2, 0, 3*D2, 0, 1);
  transpose_w_kernel<<<dim3(32,32,8), 256, 0, stream>>>(Wk + D2, WkvC,      DD, DD, 5*D2, D2, 8*D2, 2*D2, 4);
  transpose_w_kernel<<<dim3(32,32,8), 256, 0, stream>>>(Wv + D2, WkvC + D2, DD, DD, 5*D2, D2, 8*D2, 2*D2, 4);
  transpose_w_kernel<<<dim3(32,32,8), 256, 0, stream>>>(Wq + D2, WqC,       DD, DD, 5*D2, D2, 4*D2, D2,   4);
  transpose_w_kernel<<<dim3(32,32,10),256, 0, stream>>>(Wo, WoT,            DD, DD, D2, 0, D2, 0, 1);
  transpose_w_kernel<<<dim3(128,32,2),256, 0, stream>>>(W1, W1T, DD, FF, (long)DD*FF, 0, (long)DD*FF, 0, 1);
  transpose_w_kernel<<<dim3(32,128,2),256, 0, stream>>>(W2, W2T, FF, DD, (long)DD*FF, 0, (long)DD*FF, 0, 1);

  const int n4 = (int)(NTOK * DD / 4);
  f32_to_bf16_4<<<dim3(n4/256, 4, 1), 256, 0, stream>>>(
      g_db, g_con, g_usr, g_enc, kvb0, kvb1, kvb2, kvb3, n4);

  embed_kernel<<<(int)NTOK, 256, 0, stream>>>(emb, pvec, pose, obuf);
  ln_kernel<<<(int)NTOK, 256, 0, stream>>>(obuf, nullptr, xf, xb);

  // ---- all cross-attention K/V in ONE 4096-block launch (16 z-batches) ----
  const long NB = (long)NTOK * DD;
  gemm_k<64,128,MODE_KV><<<dim3(8,32,16), 256, 0, stream>>>(
    kvb0, WkvC, bk, bv, nullptr,
    nullptr, KVc, nullptr, nullptr,
    DD, DD, DD, 0,
    0, 0, 0, 1, 0, 0, 1, 0,
    0, 1.0f);

  const int modeTab[5] = {-1, 2, 1, 3, 0};

  for (int l = 0; l < 2; ++l){
    for (int i = 0; i < 5; ++i){
      const u16 *Kp, *Vp;
      if (i == 0){
        gemm_k<64,128,MODE_QKV><<<dim3(24,32,1), 256, 0, stream>>>(
          xb, WqkvS + (long)l*3*D2,
          bq + (size_t)l*5*DD, bk + (size_t)l*5*DD, bv + (size_t)l*5*DD,
          nullptr, Qb, Kb, Vtb,
          DD, DD, DD, 0,
          0, 0, 0, 1, 0, 0, 1, 0,
          0, 0.125f);
        Kp = Kb; Vp = Vtb;
      } else {
        const int ci = i - 1;
        gemm_k<64,64,MODE_Q><<<dim3(16,32,1), 256, 0, stream>>>(
          xb, WqC + (long)(l*4 + ci)*D2,
          bq + (size_t)(l*5 + i)*DD, nullptr, nullptr,
          nullptr, Qb, nullptr, nullptr,
          DD, DD, DD, 0,
          0, 0, 0, 1, 0, 0, 1, 0,
          0, 0.125f);
        Kp = KVc + ((long)l*8 + ci*2)*NB;
        Vp = Kp + NB;
      }
      // fused attention (QK^T + masked softmax + PV)
      if (i == 0)
        flash_kernel<true><<<dim3(8,64), 256, 0, stream>>>(
            Qb, Kp, Vp, cmask, 0, attnb);
      else
        flash_kernel<false><<<dim3(8,64), 256, 0, stream>>>(
            Qb, Kp, Vp, cmask, modeTab[i], attnb);
      // O-projection + fused residual (f32 out)
      gemm_k<64,64,MODE_F32><<<dim3(16,32,1), 256, 0, stream>>>(
        attnb, WoT + (long)(l*5 + i)*D2,
        bo + (size_t)(l*5 + i)*DD, nullptr, xf,
        obuf, nullptr, nullptr, nullptr,
        DD, DD, DD, DD,
        0, 0, 0, 1, 0, 0, 1, 0,
        0, 1.0f);
      ln_kernel<<<(int)NTOK, 256, 0, stream>>>(obuf, nullptr, xf, xb);
    }
    // FFN
    gemm_k<64,128,MODE_BF16><<<dim3(32,32,1), 256, 0, stream>>>(
      xb, W1T + (size_t)l*DD*FF,
      b1 + (size_t)l*FF, nullptr, nullptr,
      nullptr, hb, nullptr, nullptr,
      DD, DD, DD, FF,
      0, 0, 0, 1, 0, 0, 1, 0,
      1, 1.0f);
    gemm_k<64,64,MODE_F32><<<dim3(16,32,1), 256, 0, stream>>>(
      hb, W2T + (size_t)l*DD*FF,
      b2 + (size_t)l*DD, nullptr, xf,
      obuf, nullptr, nullptr, nullptr,
      FF, FF, FF, DD,
      0, 0, 0, 1, 0, 0, 1, 0,
      0, 1.0f);
    float* yf = (l == 1) ? out : xf;
    ln_kernel<<<(int)NTOK, 256, 0, stream>>>(obuf, nullptr, yf, xb);
  }
}

// Round 8
// 1004.645 us; speedup vs baseline: 1.1554x; 1.0561x over previous
//
#include <hip/hip_runtime.h>

// Problem constants (Bert4KGModel): B=4, T=S=512, D=1024, H=16, dh=64, F=4096, L=2
#define BB  4
#define TT  512
#define DD  1024
#define HH  16
#define DHH 64
#define FF  4096

typedef unsigned short u16;
typedef __attribute__((ext_vector_type(8))) short bfrag8;   // 8 bf16 (4 VGPRs)
typedef __attribute__((ext_vector_type(4))) float facc4;    // 4 f32 acc

__device__ __forceinline__ u16 f2bf(float f){
  unsigned u = __float_as_uint(f);
  unsigned r = u + 0x7fffu + ((u >> 16) & 1u);   // RNE
  return (u16)(r >> 16);
}
__device__ __forceinline__ float bf2f(u16 h){
  return __uint_as_float(((unsigned)h) << 16);
}

// async global->LDS, 16B per lane; LDS dest is wave-uniform base + lane*16
__device__ __forceinline__ void gload16(const u16* g, u16* l){
  __builtin_amdgcn_global_load_lds(
      (const __attribute__((address_space(1))) void*)g,
      (__attribute__((address_space(3))) void*)l, 16, 0, 0);
}

// counted vmcnt wait (literal immediates only)
template<int N> __device__ __forceinline__ void vwait(){
  static_assert(N==0 || N==4 || N==6 || N==8, "bad vmcnt literal");
  if constexpr (N==0)  asm volatile("s_waitcnt vmcnt(0)" ::: "memory");
  else if constexpr (N==4)  asm volatile("s_waitcnt vmcnt(4)" ::: "memory");
  else if constexpr (N==6)  asm volatile("s_waitcnt vmcnt(6)" ::: "memory");
  else if constexpr (N==8)  asm volatile("s_waitcnt vmcnt(8)" ::: "memory");
}

// ---------------------------------------------------------------------------
// ALL weight transposes (f32 -> bf16, [R][C] -> [C][R]) in ONE launch.
// Compile-time job table; dst offsets are fixed positions in the workspace
// arena (must match kernel_launch alloc order: WqkvS,WkvC,WqC,WoT,W1T,W2T).
// ---------------------------------------------------------------------------
__global__ __launch_bounds__(256) void transpose_all(
    const float* __restrict__ Wq, const float* __restrict__ Wk,
    const float* __restrict__ Wv, const float* __restrict__ Wo,
    const float* __restrict__ W1, const float* __restrict__ W2,
    u16* __restrict__ dst0)
{
  constexpr long D2 = (long)DD * DD, DF = (long)DD * FF;
  constexpr long O_WqkvS = 0, O_WkvC = 6*D2, O_WqC = 22*D2, O_WoT = 30*D2,
                 O_W1T = 40*D2, O_W2T = 40*D2 + 2*DF;
  const int bid = blockIdx.x;
  const float* src; long soff, doff; int R, C, rem;
  if (bid < 6144){                        // self Wq/Wk/Wv (z=2 each)
    const int j = bid / 2048; rem = bid % 2048;
    src = (j==0) ? Wq : (j==1) ? Wk : Wv;
    const int jz = rem / 1024; rem = rem % 1024;
    soff = (long)jz * 5 * D2;
    doff = O_WqkvS + (long)j * D2 + (long)jz * 3 * D2;
    R = DD; C = DD;
  } else if (bid < 30720){                // cross K/V/Q (z=8 each)
    const int j = (bid - 6144) / 8192; rem = (bid - 6144) % 8192;
    src = (j==0) ? Wk : (j==1) ? Wv : Wq;
    const int jz = rem / 1024; rem = rem % 1024;
    const int ll = jz >> 2, ci = jz & 3;
    soff = D2 + (long)ll * 5 * D2 + (long)ci * D2;
    if (j == 0)      doff = O_WkvC + (long)ll*8*D2 + (long)ci*2*D2;
    else if (j == 1) doff = O_WkvC + D2 + (long)ll*8*D2 + (long)ci*2*D2;
    else             doff = O_WqC + (long)ll*4*D2 + (long)ci*D2;
    R = DD; C = DD;
  } else if (bid < 40960){                // Wo (z=10)
    rem = bid - 30720;
    const int jz = rem / 1024; rem = rem % 1024;
    src = Wo; soff = (long)jz * D2; doff = O_WoT + (long)jz * D2;
    R = DD; C = DD;
  } else if (bid < 49152){                // W1 [1024][4096] (z=2)
    rem = bid - 40960;
    const int jz = rem / 4096; rem = rem % 4096;
    src = W1; soff = (long)jz * DF; doff = O_W1T + (long)jz * DF;
    R = DD; C = FF;
  } else {                                // W2 [4096][1024] (z=2)
    rem = bid - 49152;
    const int jz = rem / 4096; rem = rem % 4096;
    src = W2; soff = (long)jz * DF; doff = O_W2T + (long)jz * DF;
    R = FF; C = DD;
  }
  const int ctiles = C / 32;
  const int c0 = (rem % ctiles) * 32;
  const int r0 = (rem / ctiles) * 32;
  __shared__ float tile[32][33];
  const int tx = threadIdx.x & 31, ty = threadIdx.x >> 5;
  #pragma unroll
  for (int i = 0; i < 4; ++i)
    tile[ty + i*8][tx] = src[soff + (long)(r0 + ty + i*8)*C + c0 + tx];
  __syncthreads();
  #pragma unroll
  for (int i = 0; i < 4; ++i)
    dst0[doff + (long)(c0 + ty + i*8)*R + r0 + tx] = f2bf(tile[tx][ty + i*8]);
}

// ---------------------------------------------------------------------------
// 4 buffers f32 -> bf16 in one launch
// ---------------------------------------------------------------------------
__global__ __launch_bounds__(256) void f32_to_bf16_4(
    const float* __restrict__ a0, const float* __restrict__ a1,
    const float* __restrict__ a2, const float* __restrict__ a3,
    u16* __restrict__ o0, u16* __restrict__ o1,
    u16* __restrict__ o2, u16* __restrict__ o3, int n4)
{
  const float* s; u16* d;
  switch (blockIdx.y){
    case 0: s = a0; d = o0; break;
    case 1: s = a1; d = o1; break;
    case 2: s = a2; d = o2; break;
    default: s = a3; d = o3; break;
  }
  int i = blockIdx.x * 256 + threadIdx.x;
  if (i >= n4) return;
  float4 v = ((const float4*)s)[i];
  ushort4 o;
  o.x = f2bf(v.x); o.y = f2bf(v.y); o.z = f2bf(v.z); o.w = f2bf(v.w);
  ((ushort4*)d)[i] = o;
}

// ---------------------------------------------------------------------------
// Fused embedding gather + LayerNorm: one block per token row.
// x = emb[idx]*32 + pos[t];  y = LN(x) -> yf (f32) and yb (bf16)
// ---------------------------------------------------------------------------
__global__ __launch_bounds__(256) void embed_ln_kernel(
    const float* __restrict__ emb, const int* __restrict__ pvec,
    const float* __restrict__ pos, float* __restrict__ yf, u16* __restrict__ yb)
{
  const int row = blockIdx.x;
  const int i = threadIdx.x;
  const int lane = i & 63, wid = i >> 6;
  const int idx = pvec[row];
  const int t = row & (TT - 1);
  float4 e = ((const float4*)(emb + (long)idx * DD))[i];
  float4 p = ((const float4*)(pos + (long)t * DD))[i];
  float4 x;
  x.x = e.x * 32.0f + p.x; x.y = e.y * 32.0f + p.y;
  x.z = e.z * 32.0f + p.z; x.w = e.w * 32.0f + p.w;
  float s = x.x + x.y + x.z + x.w;
  #pragma unroll
  for (int o = 32; o; o >>= 1) s += __shfl_xor(s, o);
  __shared__ float red[4];
  if (lane == 0) red[wid] = s;
  __syncthreads();
  const float mean = (red[0] + red[1] + red[2] + red[3]) * (1.0f / DD);
  __syncthreads();
  const float dx = x.x - mean, dy = x.y - mean, dz = x.z - mean, dw = x.w - mean;
  float q = dx*dx + dy*dy + dz*dz + dw*dw;
  #pragma unroll
  for (int o = 32; o; o >>= 1) q += __shfl_xor(q, o);
  if (lane == 0) red[wid] = q;
  __syncthreads();
  const float var = (red[0] + red[1] + red[2] + red[3]) * (1.0f / DD);
  const float rstd = rsqrtf(var + 1e-5f);
  float4 y; y.x = dx*rstd; y.y = dy*rstd; y.z = dz*rstd; y.w = dw*rstd;
  ((float4*)(yf + (long)row * DD))[i] = y;
  ushort4 o4; o4.x = f2bf(y.x); o4.y = f2bf(y.y); o4.z = f2bf(y.z); o4.w = f2bf(y.w);
  ((ushort4*)(yb + (long)row * DD))[i] = o4;
}

// ---------------------------------------------------------------------------
// LayerNorm(a [+ res]) -> yf (f32, optional) and yb (bf16, optional)
// ---------------------------------------------------------------------------
__global__ __launch_bounds__(256) void ln_kernel(
    const float* __restrict__ a, const float* __restrict__ res,
    float* __restrict__ yf, u16* __restrict__ yb)
{
  const int row = blockIdx.x;
  const int i = threadIdx.x;
  const int lane = i & 63, wid = i >> 6;
  float4 x = ((const float4*)(a + (long)row * DD))[i];
  if (res){
    float4 r4 = ((const float4*)(res + (long)row * DD))[i];
    x.x += r4.x; x.y += r4.y; x.z += r4.z; x.w += r4.w;
  }
  float s = x.x + x.y + x.z + x.w;
  #pragma unroll
  for (int o = 32; o; o >>= 1) s += __shfl_xor(s, o);
  __shared__ float red[4];
  if (lane == 0) red[wid] = s;
  __syncthreads();
  const float mean = (red[0] + red[1] + red[2] + red[3]) * (1.0f / DD);
  __syncthreads();
  const float dx = x.x - mean, dy = x.y - mean, dz = x.z - mean, dw = x.w - mean;
  float q = dx*dx + dy*dy + dz*dz + dw*dw;
  #pragma unroll
  for (int o = 32; o; o >>= 1) q += __shfl_xor(q, o);
  if (lane == 0) red[wid] = q;
  __syncthreads();
  const float var = (red[0] + red[1] + red[2] + red[3]) * (1.0f / DD);
  const float rstd = rsqrtf(var + 1e-5f);
  float4 y; y.x = dx*rstd; y.y = dy*rstd; y.z = dz*rstd; y.w = dw*rstd;
  if (yf) ((float4*)(yf + (long)row * DD))[i] = y;
  if (yb){
    ushort4 o4; o4.x = f2bf(y.x); o4.y = f2bf(y.y); o4.z = f2bf(y.z); o4.w = f2bf(y.w);
    ((ushort4*)(yb + (long)row * DD))[i] = o4;
  }
}

// ---------------------------------------------------------------------------
// Flash attention: one block per (q-tile 64, b*h). 4 waves x 16 q-rows.
// 2-deep counted-vmcnt K/V staging (41KB LDS); setprio on MFMA.
// ---------------------------------------------------------------------------
template<bool CAUSAL>
__global__ __launch_bounds__(256, 2) void flash_kernel(
    const u16* __restrict__ Q, const u16* __restrict__ Kt,
    const u16* __restrict__ Vt, const int* __restrict__ cmask, int mode,
    u16* __restrict__ O)
{
  __shared__ __align__(16) u16 Ks[2][64*64];
  __shared__ __align__(16) u16 Vs[2][64*64];
  __shared__ __align__(16) u16 Ps[4*16*64];
  __shared__ float biasS[512];

  // XCD swizzle: all 8 q-tiles of one head land on one XCD (K/V L2 reuse)
  const int fid = blockIdx.y * 8 + blockIdx.x;          // 0..511
  const int lid = (fid & 7) * 64 + (fid >> 3);
  const int qt = lid & 7;
  const int bh = lid >> 3;
  const int b = bh >> 4, h = bh & 15;

  const int tid = threadIdx.x, lane = tid & 63, wid = tid >> 6;
  const int fr = lane & 15, kg = lane >> 4;

  if (!CAUSAL){
    #pragma unroll
    for (int r = 0; r < 2; ++r){
      const int c = r * 256 + tid;
      biasS[c] = (cmask[b * 512 + c] != mode) ? 0.0f : -1e20f;
    }
  }

  const long base = (long)bh * (512 * 64);
  const u16* qrow = Q + base + (long)(qt*64 + wid*16 + fr) * 64;
  const bfrag8 aq0 = *(const bfrag8*)(qrow + kg*8);
  const bfrag8 aq1 = *(const bfrag8*)(qrow + 32 + kg*8);

  const int srow = tid >> 3;                         // 0..31
  const int gcol = ((tid & 7) ^ (srow & 7)) * 8;     // pre-swizzled source chunk

  auto stageKV = [&](int buf, int kt){
    u16* Kd = Ks[buf] + wid * 512;
    u16* Vd = Vs[buf] + wid * 512;
    #pragma unroll
    for (int p = 0; p < 2; ++p)
      gload16(Kt + base + (long)(kt*64 + p*32 + srow) * 64 + gcol, Kd + p*2048);
    #pragma unroll
    for (int p = 0; p < 2; ++p)
      gload16(Vt + base + (long)(p*32 + srow) * 512 + kt*64 + gcol, Vd + p*2048);
  };

  float mrow[4], lrow[4];
  #pragma unroll
  for (int r = 0; r < 4; ++r){ mrow[r] = -3e38f; lrow[r] = 0.0f; }
  facc4 accO[4] = {};
  const facc4 z4 = {0.0f, 0.0f, 0.0f, 0.0f};

  const int NT = CAUSAL ? (qt + 1) : 8;   // causal: skip fully-masked tiles
  stageKV(0, 0);
  if (NT > 1){ stageKV(1, 1); vwait<4>(); }
  else vwait<0>();
  __builtin_amdgcn_s_barrier();

  u16* Pw = Ps + wid * 1024;

  for (int kt = 0; kt < NT; ++kt){
    const int cur = kt & 1;
    bfrag8 bk[4][2], bv[4][2];
    #pragma unroll
    for (int j = 0; j < 4; ++j)
      #pragma unroll
      for (int c2 = 0; c2 < 2; ++c2){
        const int po = (((c2*4 + kg) ^ (fr & 7)) * 8);
        bk[j][c2] = *(const bfrag8*)&Ks[cur][(j*16 + fr)*64 + po];
        bv[j][c2] = *(const bfrag8*)&Vs[cur][(j*16 + fr)*64 + po];
      }
    __builtin_amdgcn_sched_barrier(0);
    __builtin_amdgcn_s_barrier();                 // all waves read buf[cur]
    if (kt + 2 < NT){ stageKV(cur, kt + 2); vwait<4>(); }
    else vwait<0>();                              // stage(kt+1) landed
    __builtin_amdgcn_s_barrier();                 // ...for every wave

    // QK^T (rows = q, cols = kpos)
    facc4 sc[4];
    __builtin_amdgcn_s_setprio(1);
    #pragma unroll
    for (int j = 0; j < 4; ++j){
      sc[j] = __builtin_amdgcn_mfma_f32_16x16x32_bf16(aq0, bk[j][0], z4, 0, 0, 0);
      sc[j] = __builtin_amdgcn_mfma_f32_16x16x32_bf16(aq1, bk[j][1], sc[j], 0, 0, 0);
    }
    __builtin_amdgcn_s_setprio(0);
    // mask
    if (CAUSAL){
      const int rowb = qt*64 + wid*16 + kg*4;
      #pragma unroll
      for (int j = 0; j < 4; ++j){
        const int col = kt*64 + j*16 + fr;
        #pragma unroll
        for (int r = 0; r < 4; ++r)
          if (col > rowb + r) sc[j][r] = -1e20f;
      }
    } else {
      #pragma unroll
      for (int j = 0; j < 4; ++j){
        const float bval = biasS[kt*64 + j*16 + fr];
        #pragma unroll
        for (int r = 0; r < 4; ++r) sc[j][r] += bval;
      }
    }
    // online softmax (per-lane rows kg*4+rr; reduce across fr lanes)
    float tmax[4];
    #pragma unroll
    for (int r = 0; r < 4; ++r)
      tmax[r] = fmaxf(fmaxf(sc[0][r], sc[1][r]), fmaxf(sc[2][r], sc[3][r]));
    #pragma unroll
    for (int o = 1; o < 16; o <<= 1)
      #pragma unroll
      for (int r = 0; r < 4; ++r)
        tmax[r] = fmaxf(tmax[r], __shfl_xor(tmax[r], o));
    float fac[4];
    #pragma unroll
    for (int r = 0; r < 4; ++r){
      const float mn = fmaxf(mrow[r], tmax[r]);
      fac[r] = __expf(mrow[r] - mn);
      mrow[r] = mn;
    }
    float tsum[4] = {0.0f, 0.0f, 0.0f, 0.0f};
    #pragma unroll
    for (int j = 0; j < 4; ++j)
      #pragma unroll
      for (int r = 0; r < 4; ++r){
        const float p = __expf(sc[j][r] - mrow[r]);
        sc[j][r] = p; tsum[r] += p;
      }
    #pragma unroll
    for (int o = 1; o < 16; o <<= 1)
      #pragma unroll
      for (int r = 0; r < 4; ++r) tsum[r] += __shfl_xor(tsum[r], o);
    #pragma unroll
    for (int r = 0; r < 4; ++r) lrow[r] = lrow[r]*fac[r] + tsum[r];
    #pragma unroll
    for (int f = 0; f < 4; ++f)
      #pragma unroll
      for (int r = 0; r < 4; ++r) accO[f][r] *= fac[r];

    // P -> wave-private LDS (chunk-swizzled), read back as A-frags
    #pragma unroll
    for (int j = 0; j < 4; ++j)
      #pragma unroll
      for (int r = 0; r < 4; ++r){
        const int row = kg*4 + r;
        const int col = j*16 + fr;
        Pw[row*64 + (((col >> 3) ^ (row & 7)) * 8) + (col & 7)] = f2bf(sc[j][r]);
      }
    bfrag8 ap[2];
    #pragma unroll
    for (int c2 = 0; c2 < 2; ++c2)
      ap[c2] = *(const bfrag8*)&Pw[fr*64 + (((c2*4 + kg) ^ (fr & 7)) * 8)];
    __builtin_amdgcn_s_setprio(1);
    #pragma unroll
    for (int f = 0; f < 4; ++f){
      accO[f] = __builtin_amdgcn_mfma_f32_16x16x32_bf16(ap[0], bv[f][0], accO[f], 0, 0, 0);
      accO[f] = __builtin_amdgcn_mfma_f32_16x16x32_bf16(ap[1], bv[f][1], accO[f], 0, 0, 0);
    }
    __builtin_amdgcn_s_setprio(0);
  }

  // epilogue: divide by row sum, write [b*512+t][1024] at col h*64
  #pragma unroll
  for (int f = 0; f < 4; ++f)
    #pragma unroll
    for (int r = 0; r < 4; ++r){
      const int row = qt*64 + wid*16 + kg*4 + r;
      const int col = h*64 + f*16 + fr;
      O[(long)(b*512 + row) * 1024 + col] = f2bf(accO[f][r] / lrow[r]);
    }
}

// ---------------------------------------------------------------------------
#define MODE_F32  0
#define MODE_BF16 1
#define MODE_QKV  3
#define MODE_KV   4
#define MODE_Q    5

__device__ __forceinline__ long qk_off(int gm, int gn){   // [b,h,t,d]
  return (((long)(gm >> 9) * HH + (gn >> 6)) * TT + (gm & (TT-1))) * DHH + (gn & (DHH-1));
}
__device__ __forceinline__ long vt_off(int gm, int gn){   // [b,h,d,s]
  return (((long)(gm >> 9) * HH + (gn >> 6)) * DHH + (gn & (DHH-1))) * TT + (gm & (TT-1));
}

// ---------------------------------------------------------------------------
// 256-thread bf16 MFMA GEMM, BK=64, 2-deep counted-vmcnt, XCD swizzle.
// 2x2 wave grid. V^T outputs (MODE_KV isv / MODE_QKV n0>=2048) go through an
// LDS transpose bounce -> fully coalesced 16B stores (was a 2B/1KB scatter).
// ---------------------------------------------------------------------------
template<int BM, int BN, int MODE>
__global__ __launch_bounds__(256, 2) void gemm_k(
    const u16* __restrict__ A, const u16* __restrict__ B,
    const float* __restrict__ bias0, const float* __restrict__ bias1,
    const float* __restrict__ bias2,
    float* __restrict__ Cf, u16* __restrict__ Cb0,
    u16* __restrict__ Cb1, u16* __restrict__ Cb2,
    int K, int lda, int ldb, int ldc,
    long zsA, long zsB1, long zsB2, int zdivB,
    long czs1, long czs2, int zdivC, long bzs,
    int relu, float alpha)
{
  constexpr int BK = 64;
  constexpr int ASZ = BM * BK, BSZ = BN * BK;
  __shared__ __align__(16) u16 As[2 * ASZ];
  __shared__ __align__(16) u16 Bs[2 * BSZ];

  // XCD-aware bijective block swizzle (all grids are %8 == 0)
  const int gx = gridDim.x, gy = gridDim.y;
  const int nwg = gx * gy * gridDim.z;
  const int fid = (blockIdx.z * gy + blockIdx.y) * gx + blockIdx.x;
  const int cpx = nwg >> 3;
  const int lid = (fid & 7) * cpx + (fid >> 3);
  const int bx = lid % gx;
  const int rem = lid / gx;
  const int by = rem % gy;
  const int z  = rem / gy;

  const u16* Ab;
  const u16* Bb;
  long cbase;
  constexpr long NBA = (long)2048 * 1024;      // one kv / KVc block (u16 elems)
  constexpr long D2C = (long)DD * DD;
  if constexpr (MODE == MODE_KV){
    const int ci = z >> 2, ll = (z >> 1) & 1, isv = z & 1;
    Ab = A + (long)ci * NBA;
    Bb = B + (long)(ll*8 + ci*2 + isv) * D2C;
    cbase = (long)(ll*8 + ci*2 + isv) * NBA;
  } else {
    Ab = A + (long)z * zsA;
    Bb = B + (long)(z / zdivB) * zsB1 + (long)(z % zdivB) * zsB2;
    cbase = (long)(z / zdivC) * czs1 + (long)(z % zdivC) * czs2;
  }
  const int tid = threadIdx.x, lane = tid & 63, wid = tid >> 6;
  const int m0 = by * BM, n0 = bx * BN;
  constexpr int TMW = BM / 2, TNW = BN / 2;           // 2x2 wave grid
  constexpr int FM = TMW / 16, FN = TNW / 16;
  const int wm = (wid >> 1) * TMW, wn = (wid & 1) * TNW;
  const int fr = lane & 15, kg = lane >> 4;
  facc4 acc[FM][FN] = {};

  // staging: pass = 32 rows (4KB); thread t -> row t>>3, phys chunk t&7;
  // global chunk pre-swizzled: LDS[r][c] = G[r][c^(r&7)]
  const int srow = tid >> 3;
  const int gcol = (((tid & 7) ^ (srow & 7)) * 8);
  constexpr int AP = BM / 32, BP = BN / 32;
  constexpr int LPS = AP + BP;

  auto stage = [&](int buf, int k0){
    u16* Ad = As + buf * ASZ + wid * 512;
    u16* Bd = Bs + buf * BSZ + wid * 512;
    #pragma unroll
    for (int p = 0; p < AP; ++p)
      gload16(Ab + (long)(m0 + p*32 + srow) * lda + (k0 + gcol), Ad + p*2048);
    #pragma unroll
    for (int p = 0; p < BP; ++p)
      gload16(Bb + (long)(n0 + p*32 + srow) * ldb + (k0 + gcol), Bd + p*2048);
  };

  const int nsteps = K / BK;
  stage(0, 0);
  if (nsteps > 1){ stage(1, BK); vwait<LPS>(); }
  else vwait<0>();
  __builtin_amdgcn_s_barrier();

  for (int s = 0; s < nsteps; ++s){
    const int cur = s & 1;
    const u16* Ar = As + cur * ASZ;
    const u16* Br = Bs + cur * BSZ;
    bfrag8 af[FM][2], bfv[FN][2];
    #pragma unroll
    for (int i = 0; i < FM; ++i)
      #pragma unroll
      for (int c2 = 0; c2 < 2; ++c2)
        af[i][c2] = *(const bfrag8*)&Ar[(wm + i*16 + fr) * 64 + (((c2*4 + kg) ^ (fr & 7)) * 8)];
    #pragma unroll
    for (int j = 0; j < FN; ++j)
      #pragma unroll
      for (int c2 = 0; c2 < 2; ++c2)
        bfv[j][c2] = *(const bfrag8*)&Br[(wn + j*16 + fr) * 64 + (((c2*4 + kg) ^ (fr & 7)) * 8)];
    __builtin_amdgcn_sched_barrier(0);
    __builtin_amdgcn_s_barrier();                 // all waves done reading buf[cur]
    if (s + 2 < nsteps){ stage(cur, (s + 2) * BK); vwait<LPS>(); }
    else if (s + 1 < nsteps) vwait<0>();
    __builtin_amdgcn_s_barrier();                 // buf[s+1] landed for every wave
    #pragma unroll
    for (int i = 0; i < FM; ++i)
      #pragma unroll
      for (int j = 0; j < FN; ++j){
        acc[i][j] = __builtin_amdgcn_mfma_f32_16x16x32_bf16(af[i][0], bfv[j][0], acc[i][j], 0, 0, 0);
        acc[i][j] = __builtin_amdgcn_mfma_f32_16x16x32_bf16(af[i][1], bfv[j][1], acc[i][j], 0, 0, 0);
      }
  }

  // ---- V^T output path: LDS transpose bounce -> coalesced stores ----
  if constexpr (MODE == MODE_KV || MODE == MODE_QKV){
    const float* vb = nullptr; u16* vdst = nullptr; int n0e = 0; bool vpath = false;
    if constexpr (MODE == MODE_KV){
      const int ci = z >> 2, ll = (z >> 1) & 1, isv = z & 1;
      if (isv){ vpath = true; vb = bias1 + (long)(ll*5 + ci + 1) * DD; vdst = Cb0 + cbase; n0e = n0; }
    } else {
      if (n0 >= 2048){ vpath = true; vb = bias2; vdst = Cb2; n0e = n0 - 2048; }
    }
    if (vpath){
      static_assert(BN == 128, "vpath assumes BN=128");
      u16* S = Bs;                                   // scratch: BN*BM u16 <= 2*BSZ
      #pragma unroll
      for (int j = 0; j < FN; ++j){
        const int nl = wn + j*16 + fr;
        const float bvv = vb[n0e + nl];
        #pragma unroll
        for (int i = 0; i < FM; ++i)
          #pragma unroll
          for (int rr = 0; rr < 4; ++rr){
            const int ml = wm + i*16 + kg*4 + rr;
            S[(nl*BM + ml) ^ ((nl & 7) << 3)] = f2bf(acc[i][j][rr] + bvv);
          }
      }
      __syncthreads();
      constexpr int TPR = 256 / BN;                  // threads per row = 2
      constexpr int CPT = BM / (8 * TPR);            // 16B chunks per thread
      const int n = tid / TPR;
      const int mh = (tid % TPR) * (BM / TPR);
      const long rowoff = (((long)(m0 >> 9) * HH + ((n0e + n) >> 6)) * DHH
                           + ((n0e + n) & 63)) * TT + (m0 & 511) + mh;
      #pragma unroll
      for (int c = 0; c < CPT; ++c){
        int4 w4 = *(const int4*)&S[(n*BM + mh + c*8) ^ ((n & 7) << 3)];
        *(int4*)&vdst[rowoff + c*8] = w4;
      }
      return;
    }
  }

  // Epilogue. C/D frag layout: col = fr, row = kg*4 + rr.
  #pragma unroll
  for (int i = 0; i < FM; ++i){
    #pragma unroll
    for (int j = 0; j < FN; ++j){
      const int gn = n0 + wn + j*16 + fr;
      #pragma unroll
      for (int rr = 0; rr < 4; ++rr){
        const int gm = m0 + wm + i*16 + kg*4 + rr;
        float v = acc[i][j][rr];
        if constexpr (MODE == MODE_F32){
          v = (v + (bias0 ? bias0[gn] : 0.0f)) * alpha;
          if (relu) v = fmaxf(v, 0.0f);
          const long off = cbase + (long)gm * ldc + gn;
          if (bias2) v += bias2[off];             // fused residual
          Cf[off] = v;
        } else if constexpr (MODE == MODE_BF16){
          v = (v + (bias0 ? bias0[gn] : 0.0f)) * alpha;
          if (relu) v = fmaxf(v, 0.0f);
          Cb0[cbase + (long)gm * ldc + gn] = f2bf(v);
        } else if constexpr (MODE == MODE_QKV){
          const int sect = gn >> 10, nn = gn & (DD - 1);
          if (sect == 0)      Cb0[qk_off(gm, nn)] = f2bf((v + bias0[nn]) * alpha);
          else                Cb1[qk_off(gm, nn)] = f2bf(v + bias1[nn]);
        } else if constexpr (MODE == MODE_Q){
          Cb0[qk_off(gm, gn)] = f2bf((v + bias0[gn]) * alpha);
        } else {  // MODE_KV K-side
          const int ci = z >> 2, ll = (z >> 1) & 1;
          const float* bp = bias0 + (long)(ll*5 + ci + 1) * DD;
          Cb0[cbase + qk_off(gm, gn)] = f2bf(v + bp[gn]);
        }
      }
    }
  }
}

// ---------------------------------------------------------------------------
extern "C" void kernel_launch(void* const* d_in, const int* in_sizes, int n_in,
                              void* d_out, int out_size, void* d_ws, size_t ws_size,
                              hipStream_t stream)
{
  (void)in_sizes; (void)n_in; (void)out_size; (void)ws_size;
  const float* emb   = (const float*)d_in[0];
  const int*   pvec  = (const int*)d_in[1];
  const float* g_enc = (const float*)d_in[2];
  const float* g_con = (const float*)d_in[3];
  const float* g_db  = (const float*)d_in[4];
  const float* g_usr = (const float*)d_in[5];
  const int*   cmask = (const int*)d_in[6];
  const float* pose  = (const float*)d_in[7];
  const float* Wq = (const float*)d_in[8];
  const float* bq = (const float*)d_in[9];
  const float* Wk = (const float*)d_in[10];
  const float* bk = (const float*)d_in[11];
  const float* Wv = (const float*)d_in[12];
  const float* bv = (const float*)d_in[13];
  const float* Wo = (const float*)d_in[14];
  const float* bo = (const float*)d_in[15];
  const float* W1 = (const float*)d_in[16];
  const float* b1 = (const float*)d_in[17];
  const float* W2 = (const float*)d_in[18];
  const float* b2 = (const float*)d_in[19];
  float* out = (float*)d_out;

  const size_t NTOK = (size_t)BB * TT;   // 2048
  const long D2 = (long)DD * DD;

  char* wp = (char*)d_ws;
  auto alloc = [&](size_t bytes) -> char* {
    char* p = wp;
    wp += (bytes + 255) & ~(size_t)255;
    return p;
  };
  // NOTE: the first 6 arrays' order/offsets are hard-coded in transpose_all.
  u16*   WqkvS = (u16*)  alloc(sizeof(u16) * 2 * 3 * D2);
  u16*   WkvC  = (u16*)  alloc(sizeof(u16) * 2 * 4 * 2 * D2);
  u16*   WqC   = (u16*)  alloc(sizeof(u16) * 2 * 4 * D2);
  u16*   WoT   = (u16*)  alloc(sizeof(u16) * 10 * D2);
  u16*   W1T   = (u16*)  alloc(sizeof(u16) * 2 * DD * FF);
  u16*   W2T   = (u16*)  alloc(sizeof(u16) * 2 * DD * FF);
  // kvb0..3 MUST stay contiguous: MODE_KV indexes them as [4][NTOK][DD]
  u16*   kvb0  = (u16*)  alloc(sizeof(u16) * NTOK * DD);
  u16*   kvb1  = (u16*)  alloc(sizeof(u16) * NTOK * DD);
  u16*   kvb2  = (u16*)  alloc(sizeof(u16) * NTOK * DD);
  u16*   kvb3  = (u16*)  alloc(sizeof(u16) * NTOK * DD);
  u16*   KVc   = (u16*)  alloc(sizeof(u16) * 16 * NTOK * DD);
  float* xf    = (float*)alloc(sizeof(float) * NTOK * DD);
  u16*   xb    = (u16*)  alloc(sizeof(u16) * NTOK * DD);
  u16*   Qb    = (u16*)  alloc(sizeof(u16) * NTOK * DD);
  u16*   Kb    = (u16*)  alloc(sizeof(u16) * NTOK * DD);
  u16*   Vtb   = (u16*)  alloc(sizeof(u16) * NTOK * DD);
  u16*   attnb = (u16*)  alloc(sizeof(u16) * NTOK * DD);
  float* obuf  = (float*)alloc(sizeof(float) * NTOK * DD);
  u16*   hb    = (u16*)  alloc(sizeof(u16) * NTOK * FF);

  // ---- weight prep: ALL transposes in one launch ----
  transpose_all<<<57344, 256, 0, stream>>>(Wq, Wk, Wv, Wo, W1, W2, (u16*)d_ws);

  const int n4 = (int)(NTOK * DD / 4);
  f32_to_bf16_4<<<dim3(n4/256, 4, 1), 256, 0, stream>>>(
      g_db, g_con, g_usr, g_enc, kvb0, kvb1, kvb2, kvb3, n4);

  embed_ln_kernel<<<(int)NTOK, 256, 0, stream>>>(emb, pvec, pose, xf, xb);

  // ---- all cross-attention K/V in ONE 2048-block launch (16 z-batches) ----
  const long NB = (long)NTOK * DD;
  gemm_k<128,128,MODE_KV><<<dim3(8,16,16), 256, 0, stream>>>(
    kvb0, WkvC, bk, bv, nullptr,
    nullptr, KVc, nullptr, nullptr,
    DD, DD, DD, 0,
    0, 0, 0, 1, 0, 0, 1, 0,
    0, 1.0f);

  const int modeTab[5] = {-1, 2, 1, 3, 0};

  for (int l = 0; l < 2; ++l){
    for (int i = 0; i < 5; ++i){
      const u16 *Kp, *Vp;
      if (i == 0){
        gemm_k<64,128,MODE_QKV><<<dim3(24,32,1), 256, 0, stream>>>(
          xb, WqkvS + (long)l*3*D2,
          bq + (size_t)l*5*DD, bk + (size_t)l*5*DD, bv + (size_t)l*5*DD,
          nullptr, Qb, Kb, Vtb,
          DD, DD, DD, 0,
          0, 0, 0, 1, 0, 0, 1, 0,
          0, 0.125f);
        Kp = Kb; Vp = Vtb;
      } else {
        const int ci = i - 1;
        gemm_k<64,64,MODE_Q><<<dim3(16,32,1), 256, 0, stream>>>(
          xb, WqC + (long)(l*4 + ci)*D2,
          bq + (size_t)(l*5 + i)*DD, nullptr, nullptr,
          nullptr, Qb, nullptr, nullptr,
          DD, DD, DD, 0,
          0, 0, 0, 1, 0, 0, 1, 0,
          0, 0.125f);
        Kp = KVc + ((long)l*8 + ci*2)*NB;
        Vp = Kp + NB;
      }
      // fused attention (QK^T + masked softmax + PV)
      if (i == 0)
        flash_kernel<true><<<dim3(8,64), 256, 0, stream>>>(
            Qb, Kp, Vp, cmask, 0, attnb);
      else
        flash_kernel<false><<<dim3(8,64), 256, 0, stream>>>(
            Qb, Kp, Vp, cmask, modeTab[i], attnb);
      // O-projection + fused residual (f32 out)
      gemm_k<64,64,MODE_F32><<<dim3(16,32,1), 256, 0, stream>>>(
        attnb, WoT + (long)(l*5 + i)*D2,
        bo + (size_t)(l*5 + i)*DD, nullptr, xf,
        obuf, nullptr, nullptr, nullptr,
        DD, DD, DD, DD,
        0, 0, 0, 1, 0, 0, 1, 0,
        0, 1.0f);
      ln_kernel<<<(int)NTOK, 256, 0, stream>>>(obuf, nullptr, xf, xb);
    }
    // FFN
    gemm_k<64,128,MODE_BF16><<<dim3(32,32,1), 256, 0, stream>>>(
      xb, W1T + (size_t)l*DD*FF,
      b1 + (size_t)l*FF, nullptr, nullptr,
      nullptr, hb, nullptr, nullptr,
      DD, DD, DD, FF,
      0, 0, 0, 1, 0, 0, 1, 0,
      1, 1.0f);
    gemm_k<64,64,MODE_F32><<<dim3(16,32,1), 256, 0, stream>>>(
      hb, W2T + (size_t)l*DD*FF,
      b2 + (size_t)l*DD, nullptr, xf,
      obuf, nullptr, nullptr, nullptr,
      FF, FF, FF, DD,
      0, 0, 0, 1, 0, 0, 1, 0,
      0, 1.0f);
    float* yf = (l == 1) ? out : xf;
    ln_kernel<<<(int)NTOK, 256, 0, stream>>>(obuf, nullptr, yf, (l == 1) ? nullptr : xb);
  }
}

// Round 9
// 1001.366 us; speedup vs baseline: 1.1592x; 1.0033x over previous
//
#include <hip/hip_runtime.h>

// Problem constants (Bert4KGModel): B=4, T=S=512, D=1024, H=16, dh=64, F=4096, L=2
#define BB  4
#define TT  512
#define DD  1024
#define HH  16
#define DHH 64
#define FF  4096

typedef unsigned short u16;
typedef __attribute__((ext_vector_type(8))) short bfrag8;   // 8 bf16 (4 VGPRs)
typedef __attribute__((ext_vector_type(4))) float facc4;    // 4 f32 acc

__device__ __forceinline__ u16 f2bf(float f){
  unsigned u = __float_as_uint(f);
  unsigned r = u + 0x7fffu + ((u >> 16) & 1u);   // RNE
  return (u16)(r >> 16);
}
__device__ __forceinline__ float bf2f(u16 h){
  return __uint_as_float(((unsigned)h) << 16);
}

// async global->LDS, 16B per lane; LDS dest is wave-uniform base + lane*16
__device__ __forceinline__ void gload16(const u16* g, u16* l){
  __builtin_amdgcn_global_load_lds(
      (const __attribute__((address_space(1))) void*)g,
      (__attribute__((address_space(3))) void*)l, 16, 0, 0);
}

// counted vmcnt wait (literal immediates only)
template<int N> __device__ __forceinline__ void vwait(){
  static_assert(N==0 || N==4 || N==6 || N==8, "bad vmcnt literal");
  if constexpr (N==0)  asm volatile("s_waitcnt vmcnt(0)" ::: "memory");
  else if constexpr (N==4)  asm volatile("s_waitcnt vmcnt(4)" ::: "memory");
  else if constexpr (N==6)  asm volatile("s_waitcnt vmcnt(6)" ::: "memory");
  else if constexpr (N==8)  asm volatile("s_waitcnt vmcnt(8)" ::: "memory");
}

// ---------------------------------------------------------------------------
// ONE prep launch: all weight transposes (f32 [R][C] -> bf16 [C][R], 64x64
// tiles, 16B packed stores) + the 4 kv-input f32->bf16 converts.
// dst offsets match kernel_launch alloc order: WqkvS,WkvC,WqC,WoT,W1T,W2T.
// Blocks [0,14336): transpose tiles.  [14336,22528): converts.
// ---------------------------------------------------------------------------
__global__ __launch_bounds__(256) void prep_all(
    const float* __restrict__ Wq, const float* __restrict__ Wk,
    const float* __restrict__ Wv, const float* __restrict__ Wo,
    const float* __restrict__ W1, const float* __restrict__ W2,
    const float* __restrict__ g_db, const float* __restrict__ g_con,
    const float* __restrict__ g_usr, const float* __restrict__ g_enc,
    u16* __restrict__ dst0,
    u16* __restrict__ kvb0, u16* __restrict__ kvb1,
    u16* __restrict__ kvb2, u16* __restrict__ kvb3)
{
  const int bid = blockIdx.x;
  const int tid = threadIdx.x;
  if (bid >= 14336){                       // ---- kv convert ----
    const int r = bid - 14336;
    const float* s; u16* d;
    switch (r >> 11){
      case 0: s = g_db;  d = kvb0; break;
      case 1: s = g_con; d = kvb1; break;
      case 2: s = g_usr; d = kvb2; break;
      default: s = g_enc; d = kvb3; break;
    }
    const int i = (r & 2047) * 256 + tid;  // n4 = 2048*256 = NTOK*DD/4
    float4 v = ((const float4*)s)[i];
    ushort4 o;
    o.x = f2bf(v.x); o.y = f2bf(v.y); o.z = f2bf(v.z); o.w = f2bf(v.w);
    ((ushort4*)d)[i] = o;
    return;
  }
  constexpr long D2 = (long)DD * DD, DF = (long)DD * FF;
  constexpr long O_WqkvS = 0, O_WkvC = 6*D2, O_WqC = 22*D2, O_WoT = 30*D2,
                 O_W1T = 40*D2, O_W2T = 40*D2 + 2*DF;
  const float* src; long soff, doff; int R, C, rem;
  if (bid < 1536){                         // self Wq/Wk/Wv (j) x layer (l)
    const int j = bid / 512;
    src = (j==0) ? Wq : (j==1) ? Wk : Wv;
    const int l = (bid % 512) / 256; rem = bid & 255;
    soff = (long)l * 5 * D2;
    doff = O_WqkvS + (long)l * 3 * D2 + (long)j * D2;
    R = DD; C = DD;
  } else if (bid < 5632){                  // cross K/V: (l, ci, kv)
    const int idx = (bid - 1536) >> 8; rem = bid & 255;
    const int l = idx >> 3, ci = (idx >> 1) & 3, kv = idx & 1;
    src = kv ? Wv : Wk;
    soff = (long)(l*5 + 1 + ci) * D2;
    doff = O_WkvC + (long)(l*8 + ci*2 + kv) * D2;
    R = DD; C = DD;
  } else if (bid < 7680){                  // cross Q: (l, ci)
    const int idx = (bid - 5632) >> 8; rem = bid & 255;
    const int l = idx >> 2, ci = idx & 3;
    src = Wq;
    soff = (long)(l*5 + 1 + ci) * D2;
    doff = O_WqC + (long)(l*4 + ci) * D2;
    R = DD; C = DD;
  } else if (bid < 10240){                 // Wo (10 matrices, natural order)
    const int idx = (bid - 7680) >> 8; rem = bid & 255;
    src = Wo; soff = (long)idx * D2; doff = O_WoT + (long)idx * D2;
    R = DD; C = DD;
  } else if (bid < 12288){                 // W1 [DD][FF], z=2
    const int b5 = bid - 10240;
    const int z = b5 >> 10; rem = b5 & 1023;
    src = W1; soff = (long)z * DF; doff = O_W1T + (long)z * DF;
    R = DD; C = FF;
  } else {                                 // W2 [FF][DD], z=2
    const int b6 = bid - 12288;
    const int z = b6 >> 10; rem = b6 & 1023;
    src = W2; soff = (long)z * DF; doff = O_W2T + (long)z * DF;
    R = FF; C = DD;
  }
  const int ctiles = C >> 6;
  const int c0 = (rem % ctiles) << 6;
  const int r0 = (rem / ctiles) << 6;

  __shared__ u16 tile[64][66];             // stride 66: <=2-way banks both phases
  const int tr = tid >> 4, tc = tid & 15;
  #pragma unroll
  for (int i = 0; i < 4; ++i){
    const int row = tr + i*16;
    float4 v = ((const float4*)(src + soff + (long)(r0 + row)*C + c0))[tc];
    tile[row][tc*4+0] = f2bf(v.x);
    tile[row][tc*4+1] = f2bf(v.y);
    tile[row][tc*4+2] = f2bf(v.z);
    tile[row][tc*4+3] = f2bf(v.w);
  }
  __syncthreads();
  const int c = tid >> 2;                  // output row = source col
  #pragma unroll
  for (int s2 = 0; s2 < 2; ++s2){
    const int seg = ((tid & 3) << 1) + s2;
    union { int4 v; u16 u[8]; } P;
    #pragma unroll
    for (int j = 0; j < 8; ++j) P.u[j] = tile[seg*8 + j][c];
    *(int4*)&dst0[doff + (long)(c0 + c)*R + r0 + seg*8] = P.v;
  }
}

// ---------------------------------------------------------------------------
// Fused embedding gather + LayerNorm: one block per token row.
// ---------------------------------------------------------------------------
__global__ __launch_bounds__(256) void embed_ln_kernel(
    const float* __restrict__ emb, const int* __restrict__ pvec,
    const float* __restrict__ pos, float* __restrict__ yf, u16* __restrict__ yb)
{
  const int row = blockIdx.x;
  const int i = threadIdx.x;
  const int lane = i & 63, wid = i >> 6;
  const int idx = pvec[row];
  const int t = row & (TT - 1);
  float4 e = ((const float4*)(emb + (long)idx * DD))[i];
  float4 p = ((const float4*)(pos + (long)t * DD))[i];
  float4 x;
  x.x = e.x * 32.0f + p.x; x.y = e.y * 32.0f + p.y;
  x.z = e.z * 32.0f + p.z; x.w = e.w * 32.0f + p.w;
  float s = x.x + x.y + x.z + x.w;
  #pragma unroll
  for (int o = 32; o; o >>= 1) s += __shfl_xor(s, o);
  __shared__ float red[4];
  if (lane == 0) red[wid] = s;
  __syncthreads();
  const float mean = (red[0] + red[1] + red[2] + red[3]) * (1.0f / DD);
  __syncthreads();
  const float dx = x.x - mean, dy = x.y - mean, dz = x.z - mean, dw = x.w - mean;
  float q = dx*dx + dy*dy + dz*dz + dw*dw;
  #pragma unroll
  for (int o = 32; o; o >>= 1) q += __shfl_xor(q, o);
  if (lane == 0) red[wid] = q;
  __syncthreads();
  const float var = (red[0] + red[1] + red[2] + red[3]) * (1.0f / DD);
  const float rstd = rsqrtf(var + 1e-5f);
  float4 y; y.x = dx*rstd; y.y = dy*rstd; y.z = dz*rstd; y.w = dw*rstd;
  ((float4*)(yf + (long)row * DD))[i] = y;
  ushort4 o4; o4.x = f2bf(y.x); o4.y = f2bf(y.y); o4.z = f2bf(y.z); o4.w = f2bf(y.w);
  ((ushort4*)(yb + (long)row * DD))[i] = o4;
}

// ---------------------------------------------------------------------------
// LayerNorm(a [+ res]) -> yf (f32, optional) and yb (bf16, optional)
// ---------------------------------------------------------------------------
__global__ __launch_bounds__(256) void ln_kernel(
    const float* __restrict__ a, const float* __restrict__ res,
    float* __restrict__ yf, u16* __restrict__ yb)
{
  const int row = blockIdx.x;
  const int i = threadIdx.x;
  const int lane = i & 63, wid = i >> 6;
  float4 x = ((const float4*)(a + (long)row * DD))[i];
  if (res){
    float4 r4 = ((const float4*)(res + (long)row * DD))[i];
    x.x += r4.x; x.y += r4.y; x.z += r4.z; x.w += r4.w;
  }
  float s = x.x + x.y + x.z + x.w;
  #pragma unroll
  for (int o = 32; o; o >>= 1) s += __shfl_xor(s, o);
  __shared__ float red[4];
  if (lane == 0) red[wid] = s;
  __syncthreads();
  const float mean = (red[0] + red[1] + red[2] + red[3]) * (1.0f / DD);
  __syncthreads();
  const float dx = x.x - mean, dy = x.y - mean, dz = x.z - mean, dw = x.w - mean;
  float q = dx*dx + dy*dy + dz*dz + dw*dw;
  #pragma unroll
  for (int o = 32; o; o >>= 1) q += __shfl_xor(q, o);
  if (lane == 0) red[wid] = q;
  __syncthreads();
  const float var = (red[0] + red[1] + red[2] + red[3]) * (1.0f / DD);
  const float rstd = rsqrtf(var + 1e-5f);
  float4 y; y.x = dx*rstd; y.y = dy*rstd; y.z = dz*rstd; y.w = dw*rstd;
  if (yf) ((float4*)(yf + (long)row * DD))[i] = y;
  if (yb){
    ushort4 o4; o4.x = f2bf(y.x); o4.y = f2bf(y.y); o4.z = f2bf(y.z); o4.w = f2bf(y.w);
    ((ushort4*)(yb + (long)row * DD))[i] = o4;
  }
}

// ---------------------------------------------------------------------------
// Flash attention: one block per (q-tile 64, b*h). 4 waves x 16 q-rows.
// 2-deep counted-vmcnt K/V staging (41KB LDS); setprio on MFMA.
// ---------------------------------------------------------------------------
template<bool CAUSAL>
__global__ __launch_bounds__(256, 2) void flash_kernel(
    const u16* __restrict__ Q, const u16* __restrict__ Kt,
    const u16* __restrict__ Vt, const int* __restrict__ cmask, int mode,
    u16* __restrict__ O)
{
  __shared__ __align__(16) u16 Ks[2][64*64];
  __shared__ __align__(16) u16 Vs[2][64*64];
  __shared__ __align__(16) u16 Ps[4*16*64];
  __shared__ float biasS[512];

  // XCD swizzle: all 8 q-tiles of one head land on one XCD (K/V L2 reuse)
  const int fid = blockIdx.y * 8 + blockIdx.x;          // 0..511
  const int lid = (fid & 7) * 64 + (fid >> 3);
  const int qt = lid & 7;
  const int bh = lid >> 3;
  const int b = bh >> 4, h = bh & 15;

  const int tid = threadIdx.x, lane = tid & 63, wid = tid >> 6;
  const int fr = lane & 15, kg = lane >> 4;

  if (!CAUSAL){
    #pragma unroll
    for (int r = 0; r < 2; ++r){
      const int c = r * 256 + tid;
      biasS[c] = (cmask[b * 512 + c] != mode) ? 0.0f : -1e20f;
    }
  }

  const long base = (long)bh * (512 * 64);
  const u16* qrow = Q + base + (long)(qt*64 + wid*16 + fr) * 64;
  const bfrag8 aq0 = *(const bfrag8*)(qrow + kg*8);
  const bfrag8 aq1 = *(const bfrag8*)(qrow + 32 + kg*8);

  const int srow = tid >> 3;                         // 0..31
  const int gcol = ((tid & 7) ^ (srow & 7)) * 8;     // pre-swizzled source chunk

  auto stageKV = [&](int buf, int kt){
    u16* Kd = Ks[buf] + wid * 512;
    u16* Vd = Vs[buf] + wid * 512;
    #pragma unroll
    for (int p = 0; p < 2; ++p)
      gload16(Kt + base + (long)(kt*64 + p*32 + srow) * 64 + gcol, Kd + p*2048);
    #pragma unroll
    for (int p = 0; p < 2; ++p)
      gload16(Vt + base + (long)(p*32 + srow) * 512 + kt*64 + gcol, Vd + p*2048);
  };

  float mrow[4], lrow[4];
  #pragma unroll
  for (int r = 0; r < 4; ++r){ mrow[r] = -3e38f; lrow[r] = 0.0f; }
  facc4 accO[4] = {};
  const facc4 z4 = {0.0f, 0.0f, 0.0f, 0.0f};

  const int NT = CAUSAL ? (qt + 1) : 8;   // causal: skip fully-masked tiles
  stageKV(0, 0);
  if (NT > 1){ stageKV(1, 1); vwait<4>(); }
  else vwait<0>();
  __builtin_amdgcn_s_barrier();

  u16* Pw = Ps + wid * 1024;

  for (int kt = 0; kt < NT; ++kt){
    const int cur = kt & 1;
    bfrag8 bk[4][2], bv[4][2];
    #pragma unroll
    for (int j = 0; j < 4; ++j)
      #pragma unroll
      for (int c2 = 0; c2 < 2; ++c2){
        const int po = (((c2*4 + kg) ^ (fr & 7)) * 8);
        bk[j][c2] = *(const bfrag8*)&Ks[cur][(j*16 + fr)*64 + po];
        bv[j][c2] = *(const bfrag8*)&Vs[cur][(j*16 + fr)*64 + po];
      }
    __builtin_amdgcn_sched_barrier(0);
    __builtin_amdgcn_s_barrier();                 // all waves read buf[cur]
    if (kt + 2 < NT){ stageKV(cur, kt + 2); vwait<4>(); }
    else vwait<0>();                              // stage(kt+1) landed
    __builtin_amdgcn_s_barrier();                 // ...for every wave

    // QK^T (rows = q, cols = kpos)
    facc4 sc[4];
    __builtin_amdgcn_s_setprio(1);
    #pragma unroll
    for (int j = 0; j < 4; ++j){
      sc[j] = __builtin_amdgcn_mfma_f32_16x16x32_bf16(aq0, bk[j][0], z4, 0, 0, 0);
      sc[j] = __builtin_amdgcn_mfma_f32_16x16x32_bf16(aq1, bk[j][1], sc[j], 0, 0, 0);
    }
    __builtin_amdgcn_s_setprio(0);
    // mask
    if (CAUSAL){
      const int rowb = qt*64 + wid*16 + kg*4;
      #pragma unroll
      for (int j = 0; j < 4; ++j){
        const int col = kt*64 + j*16 + fr;
        #pragma unroll
        for (int r = 0; r < 4; ++r)
          if (col > rowb + r) sc[j][r] = -1e20f;
      }
    } else {
      #pragma unroll
      for (int j = 0; j < 4; ++j){
        const float bval = biasS[kt*64 + j*16 + fr];
        #pragma unroll
        for (int r = 0; r < 4; ++r) sc[j][r] += bval;
      }
    }
    // online softmax (per-lane rows kg*4+rr; reduce across fr lanes)
    float tmax[4];
    #pragma unroll
    for (int r = 0; r < 4; ++r)
      tmax[r] = fmaxf(fmaxf(sc[0][r], sc[1][r]), fmaxf(sc[2][r], sc[3][r]));
    #pragma unroll
    for (int o = 1; o < 16; o <<= 1)
      #pragma unroll
      for (int r = 0; r < 4; ++r)
        tmax[r] = fmaxf(tmax[r], __shfl_xor(tmax[r], o));
    float fac[4];
    #pragma unroll
    for (int r = 0; r < 4; ++r){
      const float mn = fmaxf(mrow[r], tmax[r]);
      fac[r] = __expf(mrow[r] - mn);
      mrow[r] = mn;
    }
    float tsum[4] = {0.0f, 0.0f, 0.0f, 0.0f};
    #pragma unroll
    for (int j = 0; j < 4; ++j)
      #pragma unroll
      for (int r = 0; r < 4; ++r){
        const float p = __expf(sc[j][r] - mrow[r]);
        sc[j][r] = p; tsum[r] += p;
      }
    #pragma unroll
    for (int o = 1; o < 16; o <<= 1)
      #pragma unroll
      for (int r = 0; r < 4; ++r) tsum[r] += __shfl_xor(tsum[r], o);
    #pragma unroll
    for (int r = 0; r < 4; ++r) lrow[r] = lrow[r]*fac[r] + tsum[r];
    #pragma unroll
    for (int f = 0; f < 4; ++f)
      #pragma unroll
      for (int r = 0; r < 4; ++r) accO[f][r] *= fac[r];

    // P -> wave-private LDS (chunk-swizzled), read back as A-frags
    #pragma unroll
    for (int j = 0; j < 4; ++j)
      #pragma unroll
      for (int r = 0; r < 4; ++r){
        const int row = kg*4 + r;
        const int col = j*16 + fr;
        Pw[row*64 + (((col >> 3) ^ (row & 7)) * 8) + (col & 7)] = f2bf(sc[j][r]);
      }
    bfrag8 ap[2];
    #pragma unroll
    for (int c2 = 0; c2 < 2; ++c2)
      ap[c2] = *(const bfrag8*)&Pw[fr*64 + (((c2*4 + kg) ^ (fr & 7)) * 8)];
    __builtin_amdgcn_s_setprio(1);
    #pragma unroll
    for (int f = 0; f < 4; ++f){
      accO[f] = __builtin_amdgcn_mfma_f32_16x16x32_bf16(ap[0], bv[f][0], accO[f], 0, 0, 0);
      accO[f] = __builtin_amdgcn_mfma_f32_16x16x32_bf16(ap[1], bv[f][1], accO[f], 0, 0, 0);
    }
    __builtin_amdgcn_s_setprio(0);
  }

  // epilogue: divide by row sum, write [b*512+t][1024] at col h*64
  #pragma unroll
  for (int f = 0; f < 4; ++f)
    #pragma unroll
    for (int r = 0; r < 4; ++r){
      const int row = qt*64 + wid*16 + kg*4 + r;
      const int col = h*64 + f*16 + fr;
      O[(long)(b*512 + row) * 1024 + col] = f2bf(accO[f][r] / lrow[r]);
    }
}

// ---------------------------------------------------------------------------
#define MODE_F32  0
#define MODE_BF16 1
#define MODE_QKV  3
#define MODE_KV   4
#define MODE_Q    5

__device__ __forceinline__ long qk_off(int gm, int gn){   // [b,h,t,d]
  return (((long)(gm >> 9) * HH + (gn >> 6)) * TT + (gm & (TT-1))) * DHH + (gn & (DHH-1));
}
__device__ __forceinline__ long vt_off(int gm, int gn){   // [b,h,d,s]
  return (((long)(gm >> 9) * HH + (gn >> 6)) * DHH + (gn & (DHH-1))) * TT + (gm & (TT-1));
}

// ---------------------------------------------------------------------------
// 256-thread bf16 MFMA GEMM, BK=64, counted-vmcnt pipeline, XCD swizzle.
// NBUF = 3 for 64x64 tiles (48KB LDS, grid-limited residency anyway ->
// free extra pipeline depth); 2 otherwise. V^T outputs go through an LDS
// transpose bounce -> coalesced 16B stores.
// ---------------------------------------------------------------------------
template<int BM, int BN, int MODE>
__global__ __launch_bounds__(256, 2) void gemm_k(
    const u16* __restrict__ A, const u16* __restrict__ B,
    const float* __restrict__ bias0, const float* __restrict__ bias1,
    const float* __restrict__ bias2,
    float* __restrict__ Cf, u16* __restrict__ Cb0,
    u16* __restrict__ Cb1, u16* __restrict__ Cb2,
    int K, int lda, int ldb, int ldc,
    long zsA, long zsB1, long zsB2, int zdivB,
    long czs1, long czs2, int zdivC, long bzs,
    int relu, float alpha)
{
  constexpr int BK = 64;
  constexpr int NBUF = (BM == 64 && BN == 64) ? 3 : 2;
  constexpr int ASZ = BM * BK, BSZ = BN * BK;
  __shared__ __align__(16) u16 As[NBUF * ASZ];
  __shared__ __align__(16) u16 Bs[NBUF * BSZ];

  // XCD-aware bijective block swizzle (all grids are %8 == 0)
  const int gx = gridDim.x, gy = gridDim.y;
  const int nwg = gx * gy * gridDim.z;
  const int fid = (blockIdx.z * gy + blockIdx.y) * gx + blockIdx.x;
  const int cpx = nwg >> 3;
  const int lid = (fid & 7) * cpx + (fid >> 3);
  const int bx = lid % gx;
  const int rem = lid / gx;
  const int by = rem % gy;
  const int z  = rem / gy;

  const u16* Ab;
  const u16* Bb;
  long cbase;
  constexpr long NBA = (long)2048 * 1024;      // one kv / KVc block (u16 elems)
  constexpr long D2C = (long)DD * DD;
  if constexpr (MODE == MODE_KV){
    const int ci = z >> 2, ll = (z >> 1) & 1, isv = z & 1;
    Ab = A + (long)ci * NBA;
    Bb = B + (long)(ll*8 + ci*2 + isv) * D2C;
    cbase = (long)(ll*8 + ci*2 + isv) * NBA;
  } else {
    Ab = A + (long)z * zsA;
    Bb = B + (long)(z / zdivB) * zsB1 + (long)(z % zdivB) * zsB2;
    cbase = (long)(z / zdivC) * czs1 + (long)(z % zdivC) * czs2;
  }
  const int tid = threadIdx.x, lane = tid & 63, wid = tid >> 6;
  const int m0 = by * BM, n0 = bx * BN;
  constexpr int TMW = BM / 2, TNW = BN / 2;           // 2x2 wave grid
  constexpr int FM = TMW / 16, FN = TNW / 16;
  const int wm = (wid >> 1) * TMW, wn = (wid & 1) * TNW;
  const int fr = lane & 15, kg = lane >> 4;
  facc4 acc[FM][FN] = {};

  // staging: pass = 32 rows (4KB); thread t -> row t>>3, phys chunk t&7;
  // global chunk pre-swizzled: LDS[r][c] = G[r][c^(r&7)]
  const int srow = tid >> 3;
  const int gcol = (((tid & 7) ^ (srow & 7)) * 8);
  constexpr int AP = BM / 32, BP = BN / 32;
  constexpr int LPS = AP + BP;

  auto stage = [&](int buf, int k0){
    u16* Ad = As + buf * ASZ + wid * 512;
    u16* Bd = Bs + buf * BSZ + wid * 512;
    #pragma unroll
    for (int p = 0; p < AP; ++p)
      gload16(Ab + (long)(m0 + p*32 + srow) * lda + (k0 + gcol), Ad + p*2048);
    #pragma unroll
    for (int p = 0; p < BP; ++p)
      gload16(Bb + (long)(n0 + p*32 + srow) * ldb + (k0 + gcol), Bd + p*2048);
  };

  const int nsteps = K / BK;
  stage(0, 0);
  if constexpr (NBUF == 3){
    if (nsteps > 1) stage(1, BK);
    if (nsteps > 2) stage(2, 2*BK);
    if (nsteps > 2) vwait<2*LPS>();
    else if (nsteps > 1) vwait<LPS>();
    else vwait<0>();
  } else {
    if (nsteps > 1){ stage(1, BK); vwait<LPS>(); }
    else vwait<0>();
  }
  __builtin_amdgcn_s_barrier();

  int cur = 0;
  for (int s = 0; s < nsteps; ++s){
    const u16* Ar = As + cur * ASZ;
    const u16* Br = Bs + cur * BSZ;
    bfrag8 af[FM][2], bfv[FN][2];
    #pragma unroll
    for (int i = 0; i < FM; ++i)
      #pragma unroll
      for (int c2 = 0; c2 < 2; ++c2)
        af[i][c2] = *(const bfrag8*)&Ar[(wm + i*16 + fr) * 64 + (((c2*4 + kg) ^ (fr & 7)) * 8)];
    #pragma unroll
    for (int j = 0; j < FN; ++j)
      #pragma unroll
      for (int c2 = 0; c2 < 2; ++c2)
        bfv[j][c2] = *(const bfrag8*)&Br[(wn + j*16 + fr) * 64 + (((c2*4 + kg) ^ (fr & 7)) * 8)];
    __builtin_amdgcn_sched_barrier(0);
    __builtin_amdgcn_s_barrier();                 // all waves done reading buf[cur]
    if constexpr (NBUF == 3){
      if (s + 3 < nsteps){ stage(cur, (s + 3) * BK); vwait<2*LPS>(); }
      else if (s + 2 < nsteps) vwait<LPS>();
      else if (s + 1 < nsteps) vwait<0>();
    } else {
      if (s + 2 < nsteps){ stage(cur, (s + 2) * BK); vwait<LPS>(); }
      else if (s + 1 < nsteps) vwait<0>();
    }
    __builtin_amdgcn_s_barrier();                 // buf[s+1] landed for every wave
    #pragma unroll
    for (int i = 0; i < FM; ++i)
      #pragma unroll
      for (int j = 0; j < FN; ++j){
        acc[i][j] = __builtin_amdgcn_mfma_f32_16x16x32_bf16(af[i][0], bfv[j][0], acc[i][j], 0, 0, 0);
        acc[i][j] = __builtin_amdgcn_mfma_f32_16x16x32_bf16(af[i][1], bfv[j][1], acc[i][j], 0, 0, 0);
      }
    cur = (cur == NBUF - 1) ? 0 : cur + 1;
  }

  // ---- V^T output path: LDS transpose bounce -> coalesced stores ----
  if constexpr (MODE == MODE_KV || MODE == MODE_QKV){
    const float* vb = nullptr; u16* vdst = nullptr; int n0e = 0; bool vpath = false;
    if constexpr (MODE == MODE_KV){
      const int ci = z >> 2, ll = (z >> 1) & 1, isv = z & 1;
      if (isv){ vpath = true; vb = bias1 + (long)(ll*5 + ci + 1) * DD; vdst = Cb0 + cbase; n0e = n0; }
    } else {
      if (n0 >= 2048){ vpath = true; vb = bias2; vdst = Cb2; n0e = n0 - 2048; }
    }
    if (vpath){
      static_assert(BN == 128 || (MODE == MODE_Q), "vpath assumes BN=128");
      u16* S = Bs;                                   // scratch: BN*BM u16 <= NBUF*BSZ
      #pragma unroll
      for (int j = 0; j < FN; ++j){
        const int nl = wn + j*16 + fr;
        const float bvv = vb[n0e + nl];
        #pragma unroll
        for (int i = 0; i < FM; ++i)
          #pragma unroll
          for (int rr = 0; rr < 4; ++rr){
            const int ml = wm + i*16 + kg*4 + rr;
            S[(nl*BM + ml) ^ ((nl & 7) << 3)] = f2bf(acc[i][j][rr] + bvv);
          }
      }
      __syncthreads();
      constexpr int TPR = 256 / BN;                  // threads per row = 2
      constexpr int CPT = BM / (8 * TPR);            // 16B chunks per thread
      const int n = tid / TPR;
      const int mh = (tid % TPR) * (BM / TPR);
      const long rowoff = (((long)(m0 >> 9) * HH + ((n0e + n) >> 6)) * DHH
                           + ((n0e + n) & 63)) * TT + (m0 & 511) + mh;
      #pragma unroll
      for (int c = 0; c < CPT; ++c){
        int4 w4 = *(const int4*)&S[(n*BM + mh + c*8) ^ ((n & 7) << 3)];
        *(int4*)&vdst[rowoff + c*8] = w4;
      }
      return;
    }
  }

  // Epilogue. C/D frag layout: col = fr, row = kg*4 + rr.
  #pragma unroll
  for (int i = 0; i < FM; ++i){
    #pragma unroll
    for (int j = 0; j < FN; ++j){
      const int gn = n0 + wn + j*16 + fr;
      #pragma unroll
      for (int rr = 0; rr < 4; ++rr){
        const int gm = m0 + wm + i*16 + kg*4 + rr;
        float v = acc[i][j][rr];
        if constexpr (MODE == MODE_F32){
          v = (v + (bias0 ? bias0[gn] : 0.0f)) * alpha;
          if (relu) v = fmaxf(v, 0.0f);
          const long off = cbase + (long)gm * ldc + gn;
          if (bias2) v += bias2[off];             // fused residual
          Cf[off] = v;
        } else if constexpr (MODE == MODE_BF16){
          v = (v + (bias0 ? bias0[gn] : 0.0f)) * alpha;
          if (relu) v = fmaxf(v, 0.0f);
          Cb0[cbase + (long)gm * ldc + gn] = f2bf(v);
        } else if constexpr (MODE == MODE_QKV){
          const int sect = gn >> 10, nn = gn & (DD - 1);
          if (sect == 0)      Cb0[qk_off(gm, nn)] = f2bf((v + bias0[nn]) * alpha);
          else                Cb1[qk_off(gm, nn)] = f2bf(v + bias1[nn]);
        } else if constexpr (MODE == MODE_Q){
          Cb0[qk_off(gm, gn)] = f2bf((v + bias0[gn]) * alpha);
        } else {  // MODE_KV K-side
          const int ci = z >> 2, ll = (z >> 1) & 1;
          const float* bp = bias0 + (long)(ll*5 + ci + 1) * DD;
          Cb0[cbase + qk_off(gm, gn)] = f2bf(v + bp[gn]);
        }
      }
    }
  }
}

// ---------------------------------------------------------------------------
extern "C" void kernel_launch(void* const* d_in, const int* in_sizes, int n_in,
                              void* d_out, int out_size, void* d_ws, size_t ws_size,
                              hipStream_t stream)
{
  (void)in_sizes; (void)n_in; (void)out_size; (void)ws_size;
  const float* emb   = (const float*)d_in[0];
  const int*   pvec  = (const int*)d_in[1];
  const float* g_enc = (const float*)d_in[2];
  const float* g_con = (const float*)d_in[3];
  const float* g_db  = (const float*)d_in[4];
  const float* g_usr = (const float*)d_in[5];
  const int*   cmask = (const int*)d_in[6];
  const float* pose  = (const float*)d_in[7];
  const float* Wq = (const float*)d_in[8];
  const float* bq = (const float*)d_in[9];
  const float* Wk = (const float*)d_in[10];
  const float* bk = (const float*)d_in[11];
  const float* Wv = (const float*)d_in[12];
  const float* bv = (const float*)d_in[13];
  const float* Wo = (const float*)d_in[14];
  const float* bo = (const float*)d_in[15];
  const float* W1 = (const float*)d_in[16];
  const float* b1 = (const float*)d_in[17];
  const float* W2 = (const float*)d_in[18];
  const float* b2 = (const float*)d_in[19];
  float* out = (float*)d_out;

  const size_t NTOK = (size_t)BB * TT;   // 2048
  const long D2 = (long)DD * DD;

  char* wp = (char*)d_ws;
  auto alloc = [&](size_t bytes) -> char* {
    char* p = wp;
    wp += (bytes + 255) & ~(size_t)255;
    return p;
  };
  // NOTE: the first 6 arrays' order/offsets are hard-coded in prep_all.
  u16*   WqkvS = (u16*)  alloc(sizeof(u16) * 2 * 3 * D2);
  u16*   WkvC  = (u16*)  alloc(sizeof(u16) * 2 * 4 * 2 * D2);
  u16*   WqC   = (u16*)  alloc(sizeof(u16) * 2 * 4 * D2);
  u16*   WoT   = (u16*)  alloc(sizeof(u16) * 10 * D2);
  u16*   W1T   = (u16*)  alloc(sizeof(u16) * 2 * DD * FF);
  u16*   W2T   = (u16*)  alloc(sizeof(u16) * 2 * DD * FF);
  // kvb0..3 MUST stay contiguous: MODE_KV indexes them as [4][NTOK][DD]
  u16*   kvb0  = (u16*)  alloc(sizeof(u16) * NTOK * DD);
  u16*   kvb1  = (u16*)  alloc(sizeof(u16) * NTOK * DD);
  u16*   kvb2  = (u16*)  alloc(sizeof(u16) * NTOK * DD);
  u16*   kvb3  = (u16*)  alloc(sizeof(u16) * NTOK * DD);
  u16*   KVc   = (u16*)  alloc(sizeof(u16) * 16 * NTOK * DD);
  float* xf    = (float*)alloc(sizeof(float) * NTOK * DD);
  u16*   xb    = (u16*)  alloc(sizeof(u16) * NTOK * DD);
  u16*   Qb    = (u16*)  alloc(sizeof(u16) * NTOK * DD);
  u16*   Kb    = (u16*)  alloc(sizeof(u16) * NTOK * DD);
  u16*   Vtb   = (u16*)  alloc(sizeof(u16) * NTOK * DD);
  u16*   attnb = (u16*)  alloc(sizeof(u16) * NTOK * DD);
  float* obuf  = (float*)alloc(sizeof(float) * NTOK * DD);
  u16*   hb    = (u16*)  alloc(sizeof(u16) * NTOK * FF);

  // ---- ONE prep launch: all transposes + kv converts ----
  prep_all<<<22528, 256, 0, stream>>>(
      Wq, Wk, Wv, Wo, W1, W2, g_db, g_con, g_usr, g_enc,
      (u16*)d_ws, kvb0, kvb1, kvb2, kvb3);

  embed_ln_kernel<<<(int)NTOK, 256, 0, stream>>>(emb, pvec, pose, xf, xb);

  // ---- all cross-attention K/V in ONE 2048-block launch (16 z-batches) ----
  const long NB = (long)NTOK * DD;
  gemm_k<128,128,MODE_KV><<<dim3(8,16,16), 256, 0, stream>>>(
    kvb0, WkvC, bk, bv, nullptr,
    nullptr, KVc, nullptr, nullptr,
    DD, DD, DD, 0,
    0, 0, 0, 1, 0, 0, 1, 0,
    0, 1.0f);

  const int modeTab[5] = {-1, 2, 1, 3, 0};

  for (int l = 0; l < 2; ++l){
    for (int i = 0; i < 5; ++i){
      const u16 *Kp, *Vp;
      if (i == 0){
        gemm_k<64,128,MODE_QKV><<<dim3(24,32,1), 256, 0, stream>>>(
          xb, WqkvS + (long)l*3*D2,
          bq + (size_t)l*5*DD, bk + (size_t)l*5*DD, bv + (size_t)l*5*DD,
          nullptr, Qb, Kb, Vtb,
          DD, DD, DD, 0,
          0, 0, 0, 1, 0, 0, 1, 0,
          0, 0.125f);
        Kp = Kb; Vp = Vtb;
      } else {
        const int ci = i - 1;
        gemm_k<64,64,MODE_Q><<<dim3(16,32,1), 256, 0, stream>>>(
          xb, WqC + (long)(l*4 + ci)*D2,
          bq + (size_t)(l*5 + i)*DD, nullptr, nullptr,
          nullptr, Qb, nullptr, nullptr,
          DD, DD, DD, 0,
          0, 0, 0, 1, 0, 0, 1, 0,
          0, 0.125f);
        Kp = KVc + ((long)l*8 + ci*2)*NB;
        Vp = Kp + NB;
      }
      // fused attention (QK^T + masked softmax + PV)
      if (i == 0)
        flash_kernel<true><<<dim3(8,64), 256, 0, stream>>>(
            Qb, Kp, Vp, cmask, 0, attnb);
      else
        flash_kernel<false><<<dim3(8,64), 256, 0, stream>>>(
            Qb, Kp, Vp, cmask, modeTab[i], attnb);
      // O-projection + fused residual (f32 out)
      gemm_k<64,64,MODE_F32><<<dim3(16,32,1), 256, 0, stream>>>(
        attnb, WoT + (long)(l*5 + i)*D2,
        bo + (size_t)(l*5 + i)*DD, nullptr, xf,
        obuf, nullptr, nullptr, nullptr,
        DD, DD, DD, DD,
        0, 0, 0, 1, 0, 0, 1, 0,
        0, 1.0f);
      ln_kernel<<<(int)NTOK, 256, 0, stream>>>(obuf, nullptr, xf, xb);
    }
    // FFN
    gemm_k<64,128,MODE_BF16><<<dim3(32,32,1), 256, 0, stream>>>(
      xb, W1T + (size_t)l*DD*FF,
      b1 + (size_t)l*FF, nullptr, nullptr,
      nullptr, hb, nullptr, nullptr,
      DD, DD, DD, FF,
      0, 0, 0, 1, 0, 0, 1, 0,
      1, 1.0f);
    gemm_k<64,64,MODE_F32><<<dim3(16,32,1), 256, 0, stream>>>(
      hb, W2T + (size_t)l*DD*FF,
      b2 + (size_t)l*DD, nullptr, xf,
      obuf, nullptr, nullptr, nullptr,
      FF, FF, FF, DD,
      0, 0, 0, 1, 0, 0, 1, 0,
      0, 1.0f);
    float* yf = (l == 1) ? out : xf;
    ln_kernel<<<(int)NTOK, 256, 0, stream>>>(obuf, nullptr, yf, (l == 1) ? nullptr : xb);
  }
}

// Round 10
// 971.547 us; speedup vs baseline: 1.1948x; 1.0307x over previous
//
#include <hip/hip_runtime.h>

// Problem constants (Bert4KGModel): B=4, T=S=512, D=1024, H=16, dh=64, F=4096, L=2
#define BB  4
#define TT  512
#define DD  1024
#define HH  16
#define DHH 64
#define FF  4096

typedef unsigned short u16;
typedef __attribute__((ext_vector_type(8))) short bfrag8;   // 8 bf16 (4 VGPRs)
typedef __attribute__((ext_vector_type(4))) float facc4;    // 4 f32 acc

__device__ __forceinline__ u16 f2bf(float f){
  unsigned u = __float_as_uint(f);
  unsigned r = u + 0x7fffu + ((u >> 16) & 1u);   // RNE
  return (u16)(r >> 16);
}
__device__ __forceinline__ float bf2f(u16 h){
  return __uint_as_float(((unsigned)h) << 16);
}

// async global->LDS, 16B per lane; LDS dest is wave-uniform base + lane*16
__device__ __forceinline__ void gload16(const u16* g, u16* l){
  __builtin_amdgcn_global_load_lds(
      (const __attribute__((address_space(1))) void*)g,
      (__attribute__((address_space(3))) void*)l, 16, 0, 0);
}

// counted vmcnt wait (literal immediates only)
template<int N> __device__ __forceinline__ void vwait(){
  static_assert(N==0 || N==4 || N==6 || N==8, "bad vmcnt literal");
  if constexpr (N==0)  asm volatile("s_waitcnt vmcnt(0)" ::: "memory");
  else if constexpr (N==4)  asm volatile("s_waitcnt vmcnt(4)" ::: "memory");
  else if constexpr (N==6)  asm volatile("s_waitcnt vmcnt(6)" ::: "memory");
  else if constexpr (N==8)  asm volatile("s_waitcnt vmcnt(8)" ::: "memory");
}

// ---------------------------------------------------------------------------
// ONE prep launch: all weight transposes (f32 [R][C] -> bf16 [C][R], 64x64
// tiles, 16B packed stores) + the 4 kv-input f32->bf16 converts.
// ---------------------------------------------------------------------------
__global__ __launch_bounds__(256) void prep_all(
    const float* __restrict__ Wq, const float* __restrict__ Wk,
    const float* __restrict__ Wv, const float* __restrict__ Wo,
    const float* __restrict__ W1, const float* __restrict__ W2,
    const float* __restrict__ g_db, const float* __restrict__ g_con,
    const float* __restrict__ g_usr, const float* __restrict__ g_enc,
    u16* __restrict__ dst0,
    u16* __restrict__ kvb0, u16* __restrict__ kvb1,
    u16* __restrict__ kvb2, u16* __restrict__ kvb3)
{
  const int bid = blockIdx.x;
  const int tid = threadIdx.x;
  if (bid >= 14336){                       // ---- kv convert ----
    const int r = bid - 14336;
    const float* s; u16* d;
    switch (r >> 11){
      case 0: s = g_db;  d = kvb0; break;
      case 1: s = g_con; d = kvb1; break;
      case 2: s = g_usr; d = kvb2; break;
      default: s = g_enc; d = kvb3; break;
    }
    const int i = (r & 2047) * 256 + tid;
    float4 v = ((const float4*)s)[i];
    ushort4 o;
    o.x = f2bf(v.x); o.y = f2bf(v.y); o.z = f2bf(v.z); o.w = f2bf(v.w);
    ((ushort4*)d)[i] = o;
    return;
  }
  constexpr long D2 = (long)DD * DD, DF = (long)DD * FF;
  constexpr long O_WqkvS = 0, O_WkvC = 6*D2, O_WqC = 22*D2, O_WoT = 30*D2,
                 O_W1T = 40*D2, O_W2T = 40*D2 + 2*DF;
  const float* src; long soff, doff; int R, C, rem;
  if (bid < 1536){                         // self Wq/Wk/Wv (j) x layer (l)
    const int j = bid / 512;
    src = (j==0) ? Wq : (j==1) ? Wk : Wv;
    const int l = (bid % 512) / 256; rem = bid & 255;
    soff = (long)l * 5 * D2;
    doff = O_WqkvS + (long)l * 3 * D2 + (long)j * D2;
    R = DD; C = DD;
  } else if (bid < 5632){                  // cross K/V: (l, ci, kv)
    const int idx = (bid - 1536) >> 8; rem = bid & 255;
    const int l = idx >> 3, ci = (idx >> 1) & 3, kv = idx & 1;
    src = kv ? Wv : Wk;
    soff = (long)(l*5 + 1 + ci) * D2;
    doff = O_WkvC + (long)(l*8 + ci*2 + kv) * D2;
    R = DD; C = DD;
  } else if (bid < 7680){                  // cross Q: (l, ci)
    const int idx = (bid - 5632) >> 8; rem = bid & 255;
    const int l = idx >> 2, ci = idx & 3;
    src = Wq;
    soff = (long)(l*5 + 1 + ci) * D2;
    doff = O_WqC + (long)(l*4 + ci) * D2;
    R = DD; C = DD;
  } else if (bid < 10240){                 // Wo (10 matrices)
    const int idx = (bid - 7680) >> 8; rem = bid & 255;
    src = Wo; soff = (long)idx * D2; doff = O_WoT + (long)idx * D2;
    R = DD; C = DD;
  } else if (bid < 12288){                 // W1 [DD][FF], z=2
    const int b5 = bid - 10240;
    const int z = b5 >> 10; rem = b5 & 1023;
    src = W1; soff = (long)z * DF; doff = O_W1T + (long)z * DF;
    R = DD; C = FF;
  } else {                                 // W2 [FF][DD], z=2
    const int b6 = bid - 12288;
    const int z = b6 >> 10; rem = b6 & 1023;
    src = W2; soff = (long)z * DF; doff = O_W2T + (long)z * DF;
    R = FF; C = DD;
  }
  const int ctiles = C >> 6;
  const int c0 = (rem % ctiles) << 6;
  const int r0 = (rem / ctiles) << 6;

  __shared__ u16 tile[64][66];
  const int tr = tid >> 4, tc = tid & 15;
  #pragma unroll
  for (int i = 0; i < 4; ++i){
    const int row = tr + i*16;
    float4 v = ((const float4*)(src + soff + (long)(r0 + row)*C + c0))[tc];
    tile[row][tc*4+0] = f2bf(v.x);
    tile[row][tc*4+1] = f2bf(v.y);
    tile[row][tc*4+2] = f2bf(v.z);
    tile[row][tc*4+3] = f2bf(v.w);
  }
  __syncthreads();
  const int c = tid >> 2;
  #pragma unroll
  for (int s2 = 0; s2 < 2; ++s2){
    const int seg = ((tid & 3) << 1) + s2;
    union { int4 v; u16 u[8]; } P;
    #pragma unroll
    for (int j = 0; j < 8; ++j) P.u[j] = tile[seg*8 + j][c];
    *(int4*)&dst0[doff + (long)(c0 + c)*R + r0 + seg*8] = P.v;
  }
}

// ---------------------------------------------------------------------------
// Fused embedding gather + LayerNorm
// ---------------------------------------------------------------------------
__global__ __launch_bounds__(256) void embed_ln_kernel(
    const float* __restrict__ emb, const int* __restrict__ pvec,
    const float* __restrict__ pos, float* __restrict__ yf, u16* __restrict__ yb)
{
  const int row = blockIdx.x;
  const int i = threadIdx.x;
  const int lane = i & 63, wid = i >> 6;
  const int idx = pvec[row];
  const int t = row & (TT - 1);
  float4 e = ((const float4*)(emb + (long)idx * DD))[i];
  float4 p = ((const float4*)(pos + (long)t * DD))[i];
  float4 x;
  x.x = e.x * 32.0f + p.x; x.y = e.y * 32.0f + p.y;
  x.z = e.z * 32.0f + p.z; x.w = e.w * 32.0f + p.w;
  float s = x.x + x.y + x.z + x.w;
  #pragma unroll
  for (int o = 32; o; o >>= 1) s += __shfl_xor(s, o);
  __shared__ float red[4];
  if (lane == 0) red[wid] = s;
  __syncthreads();
  const float mean = (red[0] + red[1] + red[2] + red[3]) * (1.0f / DD);
  __syncthreads();
  const float dx = x.x - mean, dy = x.y - mean, dz = x.z - mean, dw = x.w - mean;
  float q = dx*dx + dy*dy + dz*dz + dw*dw;
  #pragma unroll
  for (int o = 32; o; o >>= 1) q += __shfl_xor(q, o);
  if (lane == 0) red[wid] = q;
  __syncthreads();
  const float var = (red[0] + red[1] + red[2] + red[3]) * (1.0f / DD);
  const float rstd = rsqrtf(var + 1e-5f);
  float4 y; y.x = dx*rstd; y.y = dy*rstd; y.z = dz*rstd; y.w = dw*rstd;
  ((float4*)(yf + (long)row * DD))[i] = y;
  ushort4 o4; o4.x = f2bf(y.x); o4.y = f2bf(y.y); o4.z = f2bf(y.z); o4.w = f2bf(y.w);
  ((ushort4*)(yb + (long)row * DD))[i] = o4;
}

// ---------------------------------------------------------------------------
// LayerNorm(a [+ res]) -> yf (f32, optional) and yb (bf16, optional)
// ---------------------------------------------------------------------------
__global__ __launch_bounds__(256) void ln_kernel(
    const float* __restrict__ a, const float* __restrict__ res,
    float* __restrict__ yf, u16* __restrict__ yb)
{
  const int row = blockIdx.x;
  const int i = threadIdx.x;
  const int lane = i & 63, wid = i >> 6;
  float4 x = ((const float4*)(a + (long)row * DD))[i];
  if (res){
    float4 r4 = ((const float4*)(res + (long)row * DD))[i];
    x.x += r4.x; x.y += r4.y; x.z += r4.z; x.w += r4.w;
  }
  float s = x.x + x.y + x.z + x.w;
  #pragma unroll
  for (int o = 32; o; o >>= 1) s += __shfl_xor(s, o);
  __shared__ float red[4];
  if (lane == 0) red[wid] = s;
  __syncthreads();
  const float mean = (red[0] + red[1] + red[2] + red[3]) * (1.0f / DD);
  __syncthreads();
  const float dx = x.x - mean, dy = x.y - mean, dz = x.z - mean, dw = x.w - mean;
  float q = dx*dx + dy*dy + dz*dz + dw*dw;
  #pragma unroll
  for (int o = 32; o; o >>= 1) q += __shfl_xor(q, o);
  if (lane == 0) red[wid] = q;
  __syncthreads();
  const float var = (red[0] + red[1] + red[2] + red[3]) * (1.0f / DD);
  const float rstd = rsqrtf(var + 1e-5f);
  float4 y; y.x = dx*rstd; y.y = dy*rstd; y.z = dz*rstd; y.w = dw*rstd;
  if (yf) ((float4*)(yf + (long)row * DD))[i] = y;
  if (yb){
    ushort4 o4; o4.x = f2bf(y.x); o4.y = f2bf(y.y); o4.z = f2bf(y.z); o4.w = f2bf(y.w);
    ((ushort4*)(yb + (long)row * DD))[i] = o4;
  }
}

// ---------------------------------------------------------------------------
// Flash attention, optionally with the Q-projection fused in (FUSEQ):
// block (qt, bh) first computes its own 64x64 Q-tile = xb[qt rows] @ Wq^T[h
// panel] (K=1024, 2-deep counted-vmcnt loop reusing Ks/Vs), bounces it
// through the wave-private swizzled Pw buffer into A-frags, then runs the
// normal online-softmax K/V loop.
// ---------------------------------------------------------------------------
template<bool CAUSAL, bool FUSEQ>
__global__ __launch_bounds__(256, 2) void flash_kernel(
    const u16* __restrict__ Qsrc, const u16* __restrict__ Wq,
    const float* __restrict__ bqp,
    const u16* __restrict__ Kt, const u16* __restrict__ Vt,
    const int* __restrict__ cmask, int mode, u16* __restrict__ O)
{
  __shared__ __align__(16) u16 Ks[2][64*64];
  __shared__ __align__(16) u16 Vs[2][64*64];
  __shared__ __align__(16) u16 Ps[4*16*64];
  __shared__ float biasS[512];

  // XCD swizzle: all 8 q-tiles of one head land on one XCD (K/V + Wq reuse)
  const int fid = blockIdx.y * 8 + blockIdx.x;          // 0..511
  const int lid = (fid & 7) * 64 + (fid >> 3);
  const int qt = lid & 7;
  const int bh = lid >> 3;
  const int b = bh >> 4, h = bh & 15;

  const int tid = threadIdx.x, lane = tid & 63, wid = tid >> 6;
  const int fr = lane & 15, kg = lane >> 4;
  const int srow = tid >> 3;                         // 0..31
  const int gcol = ((tid & 7) ^ (srow & 7)) * 8;     // pre-swizzled source chunk
  u16* Pw = Ps + wid * 1024;
  const facc4 z4 = {0.0f, 0.0f, 0.0f, 0.0f};

  if (!CAUSAL){
    #pragma unroll
    for (int r = 0; r < 2; ++r){
      const int c = r * 256 + tid;
      biasS[c] = (cmask[b * 512 + c] != mode) ? 0.0f : -1e20f;
    }
  }

  const long base = (long)bh * (512 * 64);
  bfrag8 aq0, aq1;

  if constexpr (FUSEQ){
    // ---- Q-tile GEMM: rows b*512+qt*64..+64 of xb, cols h*64..+64 of Wq^T
    const u16* Ax = Qsrc + (long)(b*512 + qt*64) * DD;
    const u16* Bw = Wq + (long)(h*64) * DD;
    facc4 qacc[4] = {};
    auto stageQ = [&](int buf, int k0){
      u16* Xd = Ks[buf] + wid * 512;
      u16* Wd = Vs[buf] + wid * 512;
      #pragma unroll
      for (int p = 0; p < 2; ++p)
        gload16(Ax + (long)(p*32 + srow) * DD + k0 + gcol, Xd + p*2048);
      #pragma unroll
      for (int p = 0; p < 2; ++p)
        gload16(Bw + (long)(p*32 + srow) * DD + k0 + gcol, Wd + p*2048);
    };
    stageQ(0, 0);
    stageQ(1, 64);
    vwait<4>();
    __builtin_amdgcn_s_barrier();
    for (int s = 0; s < 16; ++s){
      const int cur = s & 1;
      bfrag8 ax[2], bw[4][2];
      #pragma unroll
      for (int c2 = 0; c2 < 2; ++c2)
        ax[c2] = *(const bfrag8*)&Ks[cur][(wid*16 + fr)*64 + (((c2*4 + kg) ^ (fr & 7))*8)];
      #pragma unroll
      for (int j = 0; j < 4; ++j)
        #pragma unroll
        for (int c2 = 0; c2 < 2; ++c2)
          bw[j][c2] = *(const bfrag8*)&Vs[cur][(j*16 + fr)*64 + (((c2*4 + kg) ^ (fr & 7))*8)];
      __builtin_amdgcn_sched_barrier(0);
      __builtin_amdgcn_s_barrier();
      if (s + 2 < 16){ stageQ(cur, (s + 2) * 64); vwait<4>(); }
      else if (s + 1 < 16) vwait<0>();
      __builtin_amdgcn_s_barrier();
      __builtin_amdgcn_s_setprio(1);
      #pragma unroll
      for (int j = 0; j < 4; ++j){
        qacc[j] = __builtin_amdgcn_mfma_f32_16x16x32_bf16(ax[0], bw[j][0], qacc[j], 0, 0, 0);
        qacc[j] = __builtin_amdgcn_mfma_f32_16x16x32_bf16(ax[1], bw[j][1], qacc[j], 0, 0, 0);
      }
      __builtin_amdgcn_s_setprio(0);
    }
    // write Q (+bias, x1/8) to wave-private Pw; re-read as A-frags
    #pragma unroll
    for (int j = 0; j < 4; ++j)
      #pragma unroll
      for (int rr = 0; rr < 4; ++rr){
        const int row = kg*4 + rr, col = j*16 + fr;
        Pw[row*64 + (((col >> 3) ^ (row & 7)) * 8) + (col & 7)] =
            f2bf((qacc[j][rr] + bqp[h*64 + col]) * 0.125f);
      }
    aq0 = *(const bfrag8*)&Pw[fr*64 + ((kg ^ (fr & 7)) * 8)];
    aq1 = *(const bfrag8*)&Pw[fr*64 + (((4 + kg) ^ (fr & 7)) * 8)];
  } else {
    const u16* qrow = Qsrc + base + (long)(qt*64 + wid*16 + fr) * 64;
    aq0 = *(const bfrag8*)(qrow + kg*8);
    aq1 = *(const bfrag8*)(qrow + 32 + kg*8);
  }

  auto stageKV = [&](int buf, int kt){
    u16* Kd = Ks[buf] + wid * 512;
    u16* Vd = Vs[buf] + wid * 512;
    #pragma unroll
    for (int p = 0; p < 2; ++p)
      gload16(Kt + base + (long)(kt*64 + p*32 + srow) * 64 + gcol, Kd + p*2048);
    #pragma unroll
    for (int p = 0; p < 2; ++p)
      gload16(Vt + base + (long)(p*32 + srow) * 512 + kt*64 + gcol, Vd + p*2048);
  };

  float mrow[4], lrow[4];
  #pragma unroll
  for (int r = 0; r < 4; ++r){ mrow[r] = -3e38f; lrow[r] = 0.0f; }
  facc4 accO[4] = {};

  const int NT = CAUSAL ? (qt + 1) : 8;   // causal: skip fully-masked tiles
  stageKV(0, 0);
  if (NT > 1){ stageKV(1, 1); vwait<4>(); }
  else vwait<0>();
  __builtin_amdgcn_s_barrier();

  for (int kt = 0; kt < NT; ++kt){
    const int cur = kt & 1;
    bfrag8 bk[4][2], bv[4][2];
    #pragma unroll
    for (int j = 0; j < 4; ++j)
      #pragma unroll
      for (int c2 = 0; c2 < 2; ++c2){
        const int po = (((c2*4 + kg) ^ (fr & 7)) * 8);
        bk[j][c2] = *(const bfrag8*)&Ks[cur][(j*16 + fr)*64 + po];
        bv[j][c2] = *(const bfrag8*)&Vs[cur][(j*16 + fr)*64 + po];
      }
    __builtin_amdgcn_sched_barrier(0);
    __builtin_amdgcn_s_barrier();                 // all waves read buf[cur]
    if (kt + 2 < NT){ stageKV(cur, kt + 2); vwait<4>(); }
    else vwait<0>();                              // stage(kt+1) landed
    __builtin_amdgcn_s_barrier();                 // ...for every wave

    // QK^T
    facc4 sc[4];
    __builtin_amdgcn_s_setprio(1);
    #pragma unroll
    for (int j = 0; j < 4; ++j){
      sc[j] = __builtin_amdgcn_mfma_f32_16x16x32_bf16(aq0, bk[j][0], z4, 0, 0, 0);
      sc[j] = __builtin_amdgcn_mfma_f32_16x16x32_bf16(aq1, bk[j][1], sc[j], 0, 0, 0);
    }
    __builtin_amdgcn_s_setprio(0);
    // mask
    if (CAUSAL){
      const int rowb = qt*64 + wid*16 + kg*4;
      #pragma unroll
      for (int j = 0; j < 4; ++j){
        const int col = kt*64 + j*16 + fr;
        #pragma unroll
        for (int r = 0; r < 4; ++r)
          if (col > rowb + r) sc[j][r] = -1e20f;
      }
    } else {
      #pragma unroll
      for (int j = 0; j < 4; ++j){
        const float bval = biasS[kt*64 + j*16 + fr];
        #pragma unroll
        for (int r = 0; r < 4; ++r) sc[j][r] += bval;
      }
    }
    // online softmax
    float tmax[4];
    #pragma unroll
    for (int r = 0; r < 4; ++r)
      tmax[r] = fmaxf(fmaxf(sc[0][r], sc[1][r]), fmaxf(sc[2][r], sc[3][r]));
    #pragma unroll
    for (int o = 1; o < 16; o <<= 1)
      #pragma unroll
      for (int r = 0; r < 4; ++r)
        tmax[r] = fmaxf(tmax[r], __shfl_xor(tmax[r], o));
    float fac[4];
    #pragma unroll
    for (int r = 0; r < 4; ++r){
      const float mn = fmaxf(mrow[r], tmax[r]);
      fac[r] = __expf(mrow[r] - mn);
      mrow[r] = mn;
    }
    float tsum[4] = {0.0f, 0.0f, 0.0f, 0.0f};
    #pragma unroll
    for (int j = 0; j < 4; ++j)
      #pragma unroll
      for (int r = 0; r < 4; ++r){
        const float p = __expf(sc[j][r] - mrow[r]);
        sc[j][r] = p; tsum[r] += p;
      }
    #pragma unroll
    for (int o = 1; o < 16; o <<= 1)
      #pragma unroll
      for (int r = 0; r < 4; ++r) tsum[r] += __shfl_xor(tsum[r], o);
    #pragma unroll
    for (int r = 0; r < 4; ++r) lrow[r] = lrow[r]*fac[r] + tsum[r];
    #pragma unroll
    for (int f = 0; f < 4; ++f)
      #pragma unroll
      for (int r = 0; r < 4; ++r) accO[f][r] *= fac[r];

    // P -> wave-private LDS (chunk-swizzled), read back as A-frags
    #pragma unroll
    for (int j = 0; j < 4; ++j)
      #pragma unroll
      for (int r = 0; r < 4; ++r){
        const int row = kg*4 + r;
        const int col = j*16 + fr;
        Pw[row*64 + (((col >> 3) ^ (row & 7)) * 8) + (col & 7)] = f2bf(sc[j][r]);
      }
    bfrag8 ap[2];
    #pragma unroll
    for (int c2 = 0; c2 < 2; ++c2)
      ap[c2] = *(const bfrag8*)&Pw[fr*64 + (((c2*4 + kg) ^ (fr & 7)) * 8)];
    __builtin_amdgcn_s_setprio(1);
    #pragma unroll
    for (int f = 0; f < 4; ++f){
      accO[f] = __builtin_amdgcn_mfma_f32_16x16x32_bf16(ap[0], bv[f][0], accO[f], 0, 0, 0);
      accO[f] = __builtin_amdgcn_mfma_f32_16x16x32_bf16(ap[1], bv[f][1], accO[f], 0, 0, 0);
    }
    __builtin_amdgcn_s_setprio(0);
  }

  // epilogue
  #pragma unroll
  for (int f = 0; f < 4; ++f)
    #pragma unroll
    for (int r = 0; r < 4; ++r){
      const int row = qt*64 + wid*16 + kg*4 + r;
      const int col = h*64 + f*16 + fr;
      O[(long)(b*512 + row) * 1024 + col] = f2bf(accO[f][r] / lrow[r]);
    }
}

// ---------------------------------------------------------------------------
#define MODE_F32  0
#define MODE_BF16 1
#define MODE_QKV  3
#define MODE_KV   4

__device__ __forceinline__ long qk_off(int gm, int gn){   // [b,h,t,d]
  return (((long)(gm >> 9) * HH + (gn >> 6)) * TT + (gm & (TT-1))) * DHH + (gn & (DHH-1));
}
__device__ __forceinline__ long vt_off(int gm, int gn){   // [b,h,d,s]
  return (((long)(gm >> 9) * HH + (gn >> 6)) * DHH + (gn & (DHH-1))) * TT + (gm & (TT-1));
}

// ---------------------------------------------------------------------------
// 256-thread bf16 MFMA GEMM, BK=64, counted-vmcnt pipeline, XCD swizzle.
// NBUF=3 for 64x64 tiles; V^T outputs via LDS transpose bounce.
// ---------------------------------------------------------------------------
template<int BM, int BN, int MODE>
__global__ __launch_bounds__(256, 2) void gemm_k(
    const u16* __restrict__ A, const u16* __restrict__ B,
    const float* __restrict__ bias0, const float* __restrict__ bias1,
    const float* __restrict__ bias2,
    float* __restrict__ Cf, u16* __restrict__ Cb0,
    u16* __restrict__ Cb1, u16* __restrict__ Cb2,
    int K, int lda, int ldb, int ldc,
    long zsA, long zsB1, long zsB2, int zdivB,
    long czs1, long czs2, int zdivC, long bzs,
    int relu, float alpha)
{
  constexpr int BK = 64;
  constexpr int NBUF = (BM == 64 && BN == 64) ? 3 : 2;
  constexpr int ASZ = BM * BK, BSZ = BN * BK;
  __shared__ __align__(16) u16 As[NBUF * ASZ];
  __shared__ __align__(16) u16 Bs[NBUF * BSZ];

  const int gx = gridDim.x, gy = gridDim.y;
  const int nwg = gx * gy * gridDim.z;
  const int fid = (blockIdx.z * gy + blockIdx.y) * gx + blockIdx.x;
  const int cpx = nwg >> 3;
  const int lid = (fid & 7) * cpx + (fid >> 3);
  const int bx = lid % gx;
  const int rem = lid / gx;
  const int by = rem % gy;
  const int z  = rem / gy;

  const u16* Ab;
  const u16* Bb;
  long cbase;
  constexpr long NBA = (long)2048 * 1024;
  constexpr long D2C = (long)DD * DD;
  if constexpr (MODE == MODE_KV){
    const int ci = z >> 2, ll = (z >> 1) & 1, isv = z & 1;
    Ab = A + (long)ci * NBA;
    Bb = B + (long)(ll*8 + ci*2 + isv) * D2C;
    cbase = (long)(ll*8 + ci*2 + isv) * NBA;
  } else {
    Ab = A + (long)z * zsA;
    Bb = B + (long)(z / zdivB) * zsB1 + (long)(z % zdivB) * zsB2;
    cbase = (long)(z / zdivC) * czs1 + (long)(z % zdivC) * czs2;
  }
  const int tid = threadIdx.x, lane = tid & 63, wid = tid >> 6;
  const int m0 = by * BM, n0 = bx * BN;
  constexpr int TMW = BM / 2, TNW = BN / 2;           // 2x2 wave grid
  constexpr int FM = TMW / 16, FN = TNW / 16;
  const int wm = (wid >> 1) * TMW, wn = (wid & 1) * TNW;
  const int fr = lane & 15, kg = lane >> 4;
  facc4 acc[FM][FN] = {};

  const int srow = tid >> 3;
  const int gcol = (((tid & 7) ^ (srow & 7)) * 8);
  constexpr int AP = BM / 32, BP = BN / 32;
  constexpr int LPS = AP + BP;

  auto stage = [&](int buf, int k0){
    u16* Ad = As + buf * ASZ + wid * 512;
    u16* Bd = Bs + buf * BSZ + wid * 512;
    #pragma unroll
    for (int p = 0; p < AP; ++p)
      gload16(Ab + (long)(m0 + p*32 + srow) * lda + (k0 + gcol), Ad + p*2048);
    #pragma unroll
    for (int p = 0; p < BP; ++p)
      gload16(Bb + (long)(n0 + p*32 + srow) * ldb + (k0 + gcol), Bd + p*2048);
  };

  const int nsteps = K / BK;
  stage(0, 0);
  if constexpr (NBUF == 3){
    if (nsteps > 1) stage(1, BK);
    if (nsteps > 2) stage(2, 2*BK);
    if (nsteps > 2) vwait<2*LPS>();
    else if (nsteps > 1) vwait<LPS>();
    else vwait<0>();
  } else {
    if (nsteps > 1){ stage(1, BK); vwait<LPS>(); }
    else vwait<0>();
  }
  __builtin_amdgcn_s_barrier();

  int cur = 0;
  for (int s = 0; s < nsteps; ++s){
    const u16* Ar = As + cur * ASZ;
    const u16* Br = Bs + cur * BSZ;
    bfrag8 af[FM][2], bfv[FN][2];
    #pragma unroll
    for (int i = 0; i < FM; ++i)
      #pragma unroll
      for (int c2 = 0; c2 < 2; ++c2)
        af[i][c2] = *(const bfrag8*)&Ar[(wm + i*16 + fr) * 64 + (((c2*4 + kg) ^ (fr & 7)) * 8)];
    #pragma unroll
    for (int j = 0; j < FN; ++j)
      #pragma unroll
      for (int c2 = 0; c2 < 2; ++c2)
        bfv[j][c2] = *(const bfrag8*)&Br[(wn + j*16 + fr) * 64 + (((c2*4 + kg) ^ (fr & 7)) * 8)];
    __builtin_amdgcn_sched_barrier(0);
    __builtin_amdgcn_s_barrier();
    if constexpr (NBUF == 3){
      if (s + 3 < nsteps){ stage(cur, (s + 3) * BK); vwait<2*LPS>(); }
      else if (s + 2 < nsteps) vwait<LPS>();
      else if (s + 1 < nsteps) vwait<0>();
    } else {
      if (s + 2 < nsteps){ stage(cur, (s + 2) * BK); vwait<LPS>(); }
      else if (s + 1 < nsteps) vwait<0>();
    }
    __builtin_amdgcn_s_barrier();
    #pragma unroll
    for (int i = 0; i < FM; ++i)
      #pragma unroll
      for (int j = 0; j < FN; ++j){
        acc[i][j] = __builtin_amdgcn_mfma_f32_16x16x32_bf16(af[i][0], bfv[j][0], acc[i][j], 0, 0, 0);
        acc[i][j] = __builtin_amdgcn_mfma_f32_16x16x32_bf16(af[i][1], bfv[j][1], acc[i][j], 0, 0, 0);
      }
    cur = (cur == NBUF - 1) ? 0 : cur + 1;
  }

  // ---- V^T output path: LDS transpose bounce -> coalesced stores ----
  if constexpr (MODE == MODE_KV || MODE == MODE_QKV){
    const float* vb = nullptr; u16* vdst = nullptr; int n0e = 0; bool vpath = false;
    if constexpr (MODE == MODE_KV){
      const int ci = z >> 2, ll = (z >> 1) & 1, isv = z & 1;
      if (isv){ vpath = true; vb = bias1 + (long)(ll*5 + ci + 1) * DD; vdst = Cb0 + cbase; n0e = n0; }
    } else {
      if (n0 >= 2048){ vpath = true; vb = bias2; vdst = Cb2; n0e = n0 - 2048; }
    }
    if (vpath){
      u16* S = Bs;
      #pragma unroll
      for (int j = 0; j < FN; ++j){
        const int nl = wn + j*16 + fr;
        const float bvv = vb[n0e + nl];
        #pragma unroll
        for (int i = 0; i < FM; ++i)
          #pragma unroll
          for (int rr = 0; rr < 4; ++rr){
            const int ml = wm + i*16 + kg*4 + rr;
            S[(nl*BM + ml) ^ ((nl & 7) << 3)] = f2bf(acc[i][j][rr] + bvv);
          }
      }
      __syncthreads();
      constexpr int TPR = 256 / BN;
      constexpr int CPT = BM / (8 * TPR);
      const int n = tid / TPR;
      const int mh = (tid % TPR) * (BM / TPR);
      const long rowoff = (((long)(m0 >> 9) * HH + ((n0e + n) >> 6)) * DHH
                           + ((n0e + n) & 63)) * TT + (m0 & 511) + mh;
      #pragma unroll
      for (int c = 0; c < CPT; ++c){
        int4 w4 = *(const int4*)&S[(n*BM + mh + c*8) ^ ((n & 7) << 3)];
        *(int4*)&vdst[rowoff + c*8] = w4;
      }
      return;
    }
  }

  // Epilogue. C/D frag layout: col = fr, row = kg*4 + rr.
  #pragma unroll
  for (int i = 0; i < FM; ++i){
    #pragma unroll
    for (int j = 0; j < FN; ++j){
      const int gn = n0 + wn + j*16 + fr;
      #pragma unroll
      for (int rr = 0; rr < 4; ++rr){
        const int gm = m0 + wm + i*16 + kg*4 + rr;
        float v = acc[i][j][rr];
        if constexpr (MODE == MODE_F32){
          v = (v + (bias0 ? bias0[gn] : 0.0f)) * alpha;
          if (relu) v = fmaxf(v, 0.0f);
          const long off = cbase + (long)gm * ldc + gn;
          if (bias2) v += bias2[off];             // fused residual
          Cf[off] = v;
        } else if constexpr (MODE == MODE_BF16){
          v = (v + (bias0 ? bias0[gn] : 0.0f)) * alpha;
          if (relu) v = fmaxf(v, 0.0f);
          Cb0[cbase + (long)gm * ldc + gn] = f2bf(v);
        } else if constexpr (MODE == MODE_QKV){
          const int sect = gn >> 10, nn = gn & (DD - 1);
          if (sect == 0)      Cb0[qk_off(gm, nn)] = f2bf((v + bias0[nn]) * alpha);
          else                Cb1[qk_off(gm, nn)] = f2bf(v + bias1[nn]);
        } else {  // MODE_KV K-side
          const int ci = z >> 2, ll = (z >> 1) & 1;
          const float* bp = bias0 + (long)(ll*5 + ci + 1) * DD;
          Cb0[cbase + qk_off(gm, gn)] = f2bf(v + bp[gn]);
        }
      }
    }
  }
}

// ---------------------------------------------------------------------------
extern "C" void kernel_launch(void* const* d_in, const int* in_sizes, int n_in,
                              void* d_out, int out_size, void* d_ws, size_t ws_size,
                              hipStream_t stream)
{
  (void)in_sizes; (void)n_in; (void)out_size; (void)ws_size;
  const float* emb   = (const float*)d_in[0];
  const int*   pvec  = (const int*)d_in[1];
  const float* g_enc = (const float*)d_in[2];
  const float* g_con = (const float*)d_in[3];
  const float* g_db  = (const float*)d_in[4];
  const float* g_usr = (const float*)d_in[5];
  const int*   cmask = (const int*)d_in[6];
  const float* pose  = (const float*)d_in[7];
  const float* Wq = (const float*)d_in[8];
  const float* bq = (const float*)d_in[9];
  const float* Wk = (const float*)d_in[10];
  const float* bk = (const float*)d_in[11];
  const float* Wv = (const float*)d_in[12];
  const float* bv = (const float*)d_in[13];
  const float* Wo = (const float*)d_in[14];
  const float* bo = (const float*)d_in[15];
  const float* W1 = (const float*)d_in[16];
  const float* b1 = (const float*)d_in[17];
  const float* W2 = (const float*)d_in[18];
  const float* b2 = (const float*)d_in[19];
  float* out = (float*)d_out;

  const size_t NTOK = (size_t)BB * TT;   // 2048
  const long D2 = (long)DD * DD;

  char* wp = (char*)d_ws;
  auto alloc = [&](size_t bytes) -> char* {
    char* p = wp;
    wp += (bytes + 255) & ~(size_t)255;
    return p;
  };
  // NOTE: the first 6 arrays' order/offsets are hard-coded in prep_all.
  u16*   WqkvS = (u16*)  alloc(sizeof(u16) * 2 * 3 * D2);
  u16*   WkvC  = (u16*)  alloc(sizeof(u16) * 2 * 4 * 2 * D2);
  u16*   WqC   = (u16*)  alloc(sizeof(u16) * 2 * 4 * D2);
  u16*   WoT   = (u16*)  alloc(sizeof(u16) * 10 * D2);
  u16*   W1T   = (u16*)  alloc(sizeof(u16) * 2 * DD * FF);
  u16*   W2T   = (u16*)  alloc(sizeof(u16) * 2 * DD * FF);
  // kvb0..3 MUST stay contiguous: MODE_KV indexes them as [4][NTOK][DD]
  u16*   kvb0  = (u16*)  alloc(sizeof(u16) * NTOK * DD);
  u16*   kvb1  = (u16*)  alloc(sizeof(u16) * NTOK * DD);
  u16*   kvb2  = (u16*)  alloc(sizeof(u16) * NTOK * DD);
  u16*   kvb3  = (u16*)  alloc(sizeof(u16) * NTOK * DD);
  u16*   KVc   = (u16*)  alloc(sizeof(u16) * 16 * NTOK * DD);
  float* xf    = (float*)alloc(sizeof(float) * NTOK * DD);
  u16*   xb    = (u16*)  alloc(sizeof(u16) * NTOK * DD);
  u16*   Qb    = (u16*)  alloc(sizeof(u16) * NTOK * DD);
  u16*   Kb    = (u16*)  alloc(sizeof(u16) * NTOK * DD);
  u16*   Vtb   = (u16*)  alloc(sizeof(u16) * NTOK * DD);
  u16*   attnb = (u16*)  alloc(sizeof(u16) * NTOK * DD);
  float* obuf  = (float*)alloc(sizeof(float) * NTOK * DD);
  u16*   hb    = (u16*)  alloc(sizeof(u16) * NTOK * FF);

  // ---- ONE prep launch: all transposes + kv converts ----
  prep_all<<<22528, 256, 0, stream>>>(
      Wq, Wk, Wv, Wo, W1, W2, g_db, g_con, g_usr, g_enc,
      (u16*)d_ws, kvb0, kvb1, kvb2, kvb3);

  embed_ln_kernel<<<(int)NTOK, 256, 0, stream>>>(emb, pvec, pose, xf, xb);

  // ---- all cross-attention K/V in ONE 2048-block launch (16 z-batches) ----
  const long NB = (long)NTOK * DD;
  gemm_k<128,128,MODE_KV><<<dim3(8,16,16), 256, 0, stream>>>(
    kvb0, WkvC, bk, bv, nullptr,
    nullptr, KVc, nullptr, nullptr,
    DD, DD, DD, 0,
    0, 0, 0, 1, 0, 0, 1, 0,
    0, 1.0f);

  const int modeTab[5] = {-1, 2, 1, 3, 0};

  for (int l = 0; l < 2; ++l){
    for (int i = 0; i < 5; ++i){
      if (i == 0){
        // fused self Q/K/V projection
        gemm_k<64,128,MODE_QKV><<<dim3(24,32,1), 256, 0, stream>>>(
          xb, WqkvS + (long)l*3*D2,
          bq + (size_t)l*5*DD, bk + (size_t)l*5*DD, bv + (size_t)l*5*DD,
          nullptr, Qb, Kb, Vtb,
          DD, DD, DD, 0,
          0, 0, 0, 1, 0, 0, 1, 0,
          0, 0.125f);
        flash_kernel<true,false><<<dim3(8,64), 256, 0, stream>>>(
            Qb, nullptr, nullptr, Kb, Vtb, cmask, 0, attnb);
      } else {
        const int ci = i - 1;
        const u16* Kp = KVc + ((long)l*8 + ci*2)*NB;
        const u16* Vp = Kp + NB;
        // flash with fused Q-projection (reads xb + WqC directly)
        flash_kernel<false,true><<<dim3(8,64), 256, 0, stream>>>(
            xb, WqC + (long)(l*4 + ci)*D2, bq + (size_t)(l*5 + i)*DD,
            Kp, Vp, cmask, modeTab[i], attnb);
      }
      // O-projection + fused residual (f32 out)
      gemm_k<64,64,MODE_F32><<<dim3(16,32,1), 256, 0, stream>>>(
        attnb, WoT + (long)(l*5 + i)*D2,
        bo + (size_t)(l*5 + i)*DD, nullptr, xf,
        obuf, nullptr, nullptr, nullptr,
        DD, DD, DD, DD,
        0, 0, 0, 1, 0, 0, 1, 0,
        0, 1.0f);
      ln_kernel<<<(int)NTOK, 256, 0, stream>>>(obuf, nullptr, xf, xb);
    }
    // FFN
    gemm_k<64,128,MODE_BF16><<<dim3(32,32,1), 256, 0, stream>>>(
      xb, W1T + (size_t)l*DD*FF,
      b1 + (size_t)l*FF, nullptr, nullptr,
      nullptr, hb, nullptr, nullptr,
      DD, DD, DD, FF,
      0, 0, 0, 1, 0, 0, 1, 0,
      1, 1.0f);
    gemm_k<64,64,MODE_F32><<<dim3(16,32,1), 256, 0, stream>>>(
      hb, W2T + (size_t)l*DD*FF,
      b2 + (size_t)l*DD, nullptr, xf,
      obuf, nullptr, nullptr, nullptr,
      FF, FF, FF, DD,
      0, 0, 0, 1, 0, 0, 1, 0,
      0, 1.0f);
    float* yf = (l == 1) ? out : xf;
    ln_kernel<<<(int)NTOK, 256, 0, stream>>>(obuf, nullptr, yf, (l == 1) ? nullptr : xb);
  }
}